// Round 2
// baseline (715.303 us; speedup 1.0000x reference)
//
#include <hip/hip_runtime.h>
#include <hip/hip_bf16.h>
#include <cstdint>

#define NM 20
#define NBIN 20
#define MAXB 65536

typedef __attribute__((ext_vector_type(8))) short bf16x8;
typedef __attribute__((ext_vector_type(4))) float f32x4;
typedef __attribute__((ext_vector_type(4))) unsigned int u32x4;

union FU { bf16x8 h; u32x4 u; };

#define MFMA(A, Bf, C) __builtin_amdgcn_mfma_f32_16x16x32_bf16((A), (Bf), (C), 0, 0, 0)

// A-fragment-packed, ROW-PERMUTED weights (bf16), built by prep each launch.
#define F_NE    0        // 4 frags  (4mb x 1kc, K=16 pad 32; col 16 = ne_b)
#define F_M1W1  2048     // 16       (4mb x 4kc, K=128)
#define F_M1W2  10240    // 8        (4mb x 2kc)
#define F_M2W1  14336    // 16
#define F_M2W2  22528    // 8
#define F_WIH   26624    // 36       (12mb x 3kc, K=72 pad 96)
#define F_WHH   45056    // 24       (12mb x 2kc)
#define F_PQ    57344    // 8        (identity rows)
#define F_PK    61440    // 8        (identity rows)
#define F_PACK  65536    // 4        (2mb x 2kc, rows = op|c1|c2 pad 32)
// bf16-packed bias/LN vectors (natural feature order, 64 each)
#define F_BNE   67584
#define F_B11   67648
#define F_B12   67712
#define F_G1    67776
#define F_L1    67840
#define F_B21   67904
#define F_B22   67968
#define F_G2    68032
#define F_L2    68096
#define F_TOTAL 68160

__device__ __align__(16) short g_fr[F_TOTAL];
// GRU gate biases, f32, float4-loadable: [0]=bih+bhh (r), [1]=bih+bhh (z),
// [2]=bih (n), [3]=bhh (n)
__device__ __align__(16) float g_grb[4][64];
__device__ int g_hist[NBIN];
__device__ int g_off[NBIN];
__device__ int g_done;
__device__ int g_perm[MAXB];

__device__ __forceinline__ short bf16rn(float x) {
  unsigned u = __float_as_uint(x);
  u += 0x7fffu + ((u >> 16) & 1u);
  return (short)(u >> 16);
}
__device__ __forceinline__ float bf2f(short s) {
  return __uint_as_float(((unsigned)(unsigned short)s) << 16);
}
__device__ __forceinline__ unsigned pk2(float lo, float hi) {
  __hip_bfloat162 t = __float22bfloat162_rn(float2{lo, hi});
  return *reinterpret_cast<unsigned*>(&t);
}
// slot permutation: C row r (=mb*16+qq*4+i) lands at slot s64(r); permuting weight
// rows by s64 makes the C-output the B-fragment of the next GEMM, register-locally.
__device__ __forceinline__ int s64(int r) {
  int mb = r >> 4, qq = (r >> 2) & 3, i = r & 3;
  return (mb >> 1) * 32 + qq * 8 + (mb & 1) * 4 + i;
}

#define LDF(off) (*(const bf16x8*)(g_fr + (off) + lane * 8))
#define LDB(off, c) (*(const bf16x8*)(g_fr + (off) + (c) * 32 + q * 8))

// ---------------- prep ----------------
#define BUILDA(OFS, MB, KC, ROWX, GET)                                 \
  for (int idx = t; idx < (MB) * (KC) * 512; idx += T) {               \
    int j = idx & 7, ln = (idx >> 3) & 63, f = idx >> 9;               \
    int mb = f / (KC), kc = f % (KC);                                  \
    int m = mb * 16 + (ln & 15);                                       \
    int k = kc * 32 + (ln >> 4) * 8 + j;                               \
    int row = (ROWX);                                                  \
    (void)row; (void)k; (void)m;                                       \
    g_fr[(OFS) + idx] = bf16rn(GET);                                   \
  }

__global__ void __launch_bounds__(256)
prep_frag(const float* __restrict__ ne_w,
          const float* __restrict__ m1w1, const float* __restrict__ m1w2,
          const float* __restrict__ m2w1, const float* __restrict__ m2w2,
          const float* __restrict__ wih,  const float* __restrict__ whh,
          const float* __restrict__ pqw,  const float* __restrict__ opw,
          const float* __restrict__ c1w,  const float* __restrict__ c2w,
          const float* __restrict__ pkw,
          const float* __restrict__ ne_b,
          const float* __restrict__ m1b1, const float* __restrict__ m1b2,
          const float* __restrict__ n1g,  const float* __restrict__ n1b,
          const float* __restrict__ m2b1, const float* __restrict__ m2b2,
          const float* __restrict__ n2g,  const float* __restrict__ n2b,
          const float* __restrict__ bih,  const float* __restrict__ bhh)
{
  const int t = blockIdx.x * blockDim.x + threadIdx.x;
  const int T = gridDim.x * blockDim.x;
  if (blockIdx.x == 0 && threadIdx.x < NBIN) g_hist[threadIdx.x] = 0;
  if (blockIdx.x == 0 && threadIdx.x == 0) g_done = 0;
  // ne_b folded into K-pad column 16 (B supplies constant 1.0 at k=16)
  BUILDA(F_NE,   4, 1, s64(m), (k < 16 ? ne_w[row * 16 + k] : (k == 16 ? ne_b[row] : 0.f)))
  BUILDA(F_M1W1, 4, 4, s64(m), m1w1[row * 128 + k])
  BUILDA(F_M1W2, 4, 2, s64(m), m1w2[row * 64 + k])
  BUILDA(F_M2W1, 4, 4, s64(m), m2w1[row * 128 + k])
  BUILDA(F_M2W2, 4, 2, s64(m), m2w2[row * 64 + k])
  BUILDA(F_WIH, 12, 3, (m & 0xC0) | s64(m & 63), (k < 72 ? wih[row * 72 + k] : 0.f))
  BUILDA(F_WHH, 12, 2, (m & 0xC0) | s64(m & 63), whh[row * 64 + k])
  BUILDA(F_PQ,   4, 2, m, pqw[row * 64 + k])
  BUILDA(F_PK,   4, 2, m, pkw[row * 64 + k])
  BUILDA(F_PACK, 2, 2, m, (row < 8 ? opw[row * 64 + k]
                           : row < 18 ? c1w[(row - 8) * 64 + k]
                           : row < 28 ? c2w[(row - 18) * 64 + k] : 0.f))
  for (int i = t; i < 64; i += T) {
    g_fr[F_BNE + i] = bf16rn(ne_b[i]);
    g_fr[F_B11 + i] = bf16rn(m1b1[i]);
    g_fr[F_B12 + i] = bf16rn(m1b2[i]);
    g_fr[F_G1  + i] = bf16rn(n1g[i]);
    g_fr[F_L1  + i] = bf16rn(n1b[i]);
    g_fr[F_B21 + i] = bf16rn(m2b1[i]);
    g_fr[F_B22 + i] = bf16rn(m2b2[i]);
    g_fr[F_G2  + i] = bf16rn(n2g[i]);
    g_fr[F_L2  + i] = bf16rn(n2b[i]);
    g_grb[0][i] = bih[i]       + bhh[i];
    g_grb[1][i] = bih[64 + i]  + bhh[64 + i];
    g_grb[2][i] = bih[128 + i];
    g_grb[3][i] = bhh[128 + i];
  }
}

// ---------------- counting sort by n_nodes: hist (+ last-block scan) ------------
__global__ void __launch_bounds__(256)
nn_hist(const int* __restrict__ nnp, int B)
{
  __shared__ int lh[NBIN];
  __shared__ int lastdone;
  const int t = threadIdx.x;
  if (t < NBIN) lh[t] = 0;
  __syncthreads();
  for (int i = blockIdx.x * blockDim.x + t; i < B; i += gridDim.x * blockDim.x)
    atomicAdd(&lh[nnp[i] - 1], 1);
  __syncthreads();
  if (t < NBIN && lh[t] > 0) atomicAdd(&g_hist[t], lh[t]);
  __threadfence();
  if (t == 0) lastdone = (atomicAdd(&g_done, 1) == (int)gridDim.x - 1);
  __syncthreads();
  if (t == 0 && lastdone) {
    int acc = 0;
    for (int i = 0; i < NBIN; i++) { g_off[i] = acc; acc += g_hist[i]; }
  }
}

__global__ void __launch_bounds__(256)
nn_scatter(const int* __restrict__ nnp, int B)
{
  __shared__ int lc[NBIN], lbase[NBIN];
  const int t = threadIdx.x;
  const int i = blockIdx.x * 256 + t;
  if (t < NBIN) lc[t] = 0;
  __syncthreads();
  int bin = 0, r = 0;
  const bool ok = (i < B);
  if (ok) { bin = nnp[i] - 1; r = atomicAdd(&lc[bin], 1); }
  __syncthreads();
  if (t < NBIN) lbase[t] = (lc[t] > 0) ? atomicAdd(&g_off[t], lc[t]) : 0;
  __syncthreads();
  if (ok) g_perm[lbase[bin] + r] = i;
}

__device__ __forceinline__ void pack8(FU& f, const float* v) {
  f.u[0] = pk2(v[0], v[1]); f.u[1] = pk2(v[2], v[3]);
  f.u[2] = pk2(v[4], v[5]); f.u[3] = pk2(v[6], v[7]);
}

// ---------------- MP stage: interleaved nodes n = wv + 4t, skip t >= nact --------
__device__ __forceinline__ void mp_stage(
    FU hA[][2], float* macc_out, const FU* msgf,
    int w1off, int w2off, int b1o, int b2o, int lgo, int lbo,
    int nnv, int wv, int nact, int lane, int q)
{
  if (nact == 0) return;
  const f32x4 zf4 = {0.f, 0.f, 0.f, 0.f};
  bf16x8 w1A[4][2], w2A[4][2];
  #pragma unroll
  for (int mb = 0; mb < 4; mb++) {
    w1A[mb][0] = LDF(w1off + (mb * 4 + 0) * 512);
    w1A[mb][1] = LDF(w1off + (mb * 4 + 1) * 512);
    w2A[mb][0] = LDF(w2off + (mb * 2 + 0) * 512);
    w2A[mb][1] = LDF(w2off + (mb * 2 + 1) * 512);
  }
  FU b1p[2], b2p[2], lgp[2], lbp[2];
  #pragma unroll
  for (int c = 0; c < 2; c++) {
    b1p[c].h = LDB(b1o, c); b2p[c].h = LDB(b2o, c);
    lgp[c].h = LDB(lgo, c); lbp[c].h = LDB(lbo, c);
  }
  f32x4 tmsg[4];
  #pragma unroll
  for (int mb = 0; mb < 4; mb++) {
    tmsg[mb] = MFMA(LDF(w1off + (mb * 4 + 2) * 512), msgf[0].h, zf4);
    tmsg[mb] = MFMA(LDF(w1off + (mb * 4 + 3) * 512), msgf[1].h, tmsg[mb]);
    // hoist b1 bias: added once per wave instead of once per node
    #pragma unroll
    for (int i = 0; i < 4; i++)
      tmsg[mb][i] += bf2f(b1p[mb >> 1].h[(mb & 1) * 4 + i]);
  }

  #pragma unroll
  for (int t = 0; t < 5; t++) {
    if (t < nact) {
      const int n = wv + 4 * t;
      f32x4 T[4];
      #pragma unroll
      for (int mb = 0; mb < 4; mb++) {
        T[mb] = MFMA(w1A[mb][0], hA[t][0].h, tmsg[mb]);
        T[mb] = MFMA(w1A[mb][1], hA[t][1].h, T[mb]);
      }
      FU tb[2];
      #pragma unroll
      for (int c = 0; c < 2; c++)
        #pragma unroll
        for (int w = 0; w < 4; w++) {
          int mb = 2 * c + (w >> 1), i0 = (w & 1) * 2;
          float lo = fmaxf(T[mb][i0],     0.f);
          float hi = fmaxf(T[mb][i0 + 1], 0.f);
          tb[c].u[w] = pk2(lo, hi);
        }
      f32x4 H[4];
      #pragma unroll
      for (int mb = 0; mb < 4; mb++) {
        H[mb] = MFMA(w2A[mb][0], tb[0].h, zf4);
        H[mb] = MFMA(w2A[mb][1], tb[1].h, H[mb]);
      }
      float y[16]; float s = 0.f, ss = 0.f;
      #pragma unroll
      for (int k = 0; k < 16; k++) {
        int c = k >> 3, j = k & 7;
        float v = H[2 * c + (j >> 2)][j & 3] + bf2f(b2p[c].h[j]) + bf2f(hA[t][c].h[j]);
        y[k] = v; s += v; ss += v * v;
      }
      s += __shfl_xor(s, 16, 64); ss += __shfl_xor(ss, 16, 64);
      s += __shfl_xor(s, 32, 64); ss += __shfl_xor(ss, 32, 64);
      float mu = s * 0.015625f;
      float rstd = rsqrtf(ss * 0.015625f - mu * mu + 1e-5f);
      float mfv = (n < nnv) ? 1.f : 0.f;
      #pragma unroll
      for (int k = 0; k < 16; k++) {
        int c = k >> 3, j = k & 7;
        float hv = ((y[k] - mu) * rstd * bf2f(lgp[c].h[j]) + bf2f(lbp[c].h[j])) * mfv;
        macc_out[k] += hv; y[k] = hv;
      }
      pack8(hA[t][0], y); pack8(hA[t][1], y + 8);
    }
  }
}

// ---------------- main: 16 sorted batch / block, interleaved node ownership ------
__global__ void __launch_bounds__(256, 4)
msp(const float* __restrict__ nf, const int* __restrict__ nnp,
    const float* __restrict__ rnn, const float* __restrict__ poh,
    const float* __restrict__ opb, const float* __restrict__ c1b,
    const float* __restrict__ c2b, const float* __restrict__ pqb,
    const float* __restrict__ pkb,
    float* __restrict__ out, int B)
{
  __shared__ __align__(16) float exch[2][4][64][17];   // 34816 B
  __shared__ __align__(16) unsigned nsx[64][8];        // 2048 B

  const int tid = threadIdx.x;
  const int wv = tid >> 6;
  const int lane = tid & 63;
  const int l15 = lane & 15, q = lane >> 4;
  const int b0 = blockIdx.x * 16;
  const int bb = g_perm[b0 + l15];

  const int nnv = nnp[bb];
  const float inv = 1.0f / (float)nnv;
  const f32x4 zf4 = {0.f, 0.f, 0.f, 0.f};

  // block-max nnv (same 16 samples for all waves): reduce within 16-lane groups
  int M = nnv;
  { int o;
    o = __shfl_xor(M, 1, 64); M = M > o ? M : o;
    o = __shfl_xor(M, 2, 64); M = M > o ? M : o;
    o = __shfl_xor(M, 4, 64); M = M > o ? M : o;
    o = __shfl_xor(M, 8, 64); M = M > o ? M : o; }
  // this wave owns nodes n = wv + 4t, t in [0, nact)
  int nact = (M - wv + 3) >> 2;
  nact = nact < 0 ? 0 : (nact > 5 ? 5 : nact);

  FU hA[5][2];
  float mac[16];
  #pragma unroll
  for (int k = 0; k < 16; k++) mac[k] = 0.f;

  // ================= E: h0^T = ne_w' · x^T (bias via k=16 pad column) ==========
  {
    bf16x8 neA[4];
    #pragma unroll
    for (int mb = 0; mb < 4; mb++) neA[mb] = LDF(F_NE + mb * 512);
    #pragma unroll
    for (int t = 0; t < 5; t++) {
      if (t < nact) {
        const int n = wv + 4 * t;
        FU bx;
        bx.u[0] = 0; bx.u[1] = 0; bx.u[2] = 0; bx.u[3] = 0;
        if (q < 2) {
          const float* p = nf + ((size_t)bb * NM + n) * 16 + q * 8;
          float4 x0 = *(const float4*)p, x1 = *(const float4*)(p + 4);
          bx.u[0] = pk2(x0.x, x0.y); bx.u[1] = pk2(x0.z, x0.w);
          bx.u[2] = pk2(x1.x, x1.y); bx.u[3] = pk2(x1.z, x1.w);
        } else if (q == 2) {
          bx.u[0] = pk2(1.f, 0.f);   // k=16 constant-1 -> ne_b column
        }
        f32x4 C[4];
        #pragma unroll
        for (int mb = 0; mb < 4; mb++) C[mb] = MFMA(neA[mb], bx.h, zf4);
        float hv[16];
        #pragma unroll
        for (int k = 0; k < 16; k++) {
          int c = k >> 3, j = k & 7;
          hv[k] = C[2 * c + (j >> 2)][j & 3];
          if (n < nnv) mac[k] += hv[k];
        }
        pack8(hA[t][0], hv); pack8(hA[t][1], hv + 8);
      }
    }
  }

  FU msgf[2];
  float tmp[16];
  #define EXCHANGE(REG)                                                        \
    _Pragma("unroll")                                                          \
    for (int k = 0; k < 16; k++) exch[REG][wv][lane][k] = mac[k];              \
    __syncthreads();                                                           \
    _Pragma("unroll")                                                          \
    for (int k = 0; k < 16; k++)                                               \
      tmp[k] = (exch[REG][0][lane][k] + exch[REG][1][lane][k] +                \
                exch[REG][2][lane][k] + exch[REG][3][lane][k]) * inv;

  EXCHANGE(0)   // msg1
  pack8(msgf[0], tmp); pack8(msgf[1], tmp + 8);
  #pragma unroll
  for (int k = 0; k < 16; k++) mac[k] = 0.f;
  mp_stage(hA, mac, msgf, F_M1W1, F_M1W2, F_B11, F_B12, F_G1, F_L1, nnv, wv, nact, lane, q);

  EXCHANGE(1)   // msg2
  pack8(msgf[0], tmp); pack8(msgf[1], tmp + 8);
  #pragma unroll
  for (int k = 0; k < 16; k++) mac[k] = 0.f;
  mp_stage(hA, mac, msgf, F_M2W1, F_M2W2, F_B21, F_B22, F_G2, F_L2, nnv, wv, nact, lane, q);

  EXCHANGE(0)   // graph_vec (region 0 safe to reuse: all reads done pre-stage2 barrier)

  // ================= GRU: wave wv owns gate tile tt = wv =================
  {
    FU gx[2]; pack8(gx[0], tmp); pack8(gx[1], tmp + 8);
    FU px;
    if (q == 0) {
      const float* pp = poh + (size_t)bb * 8;
      float4 p0 = *(const float4*)pp, p1 = *(const float4*)(pp + 4);
      px.u[0] = pk2(p0.x, p0.y); px.u[1] = pk2(p0.z, p0.w);
      px.u[2] = pk2(p1.x, p1.y); px.u[3] = pk2(p1.z, p1.w);
    } else { px.u[0] = 0; px.u[1] = 0; px.u[2] = 0; px.u[3] = 0; }
    const float* rr0 = rnn + (size_t)bb * 64;
    float rv[16];
    #pragma unroll
    for (int c = 0; c < 2; c++) {
      float4 a0 = *(const float4*)(rr0 + c * 32 + q * 8);
      float4 a1 = *(const float4*)(rr0 + c * 32 + q * 8 + 4);
      rv[c * 8 + 0] = a0.x; rv[c * 8 + 1] = a0.y; rv[c * 8 + 2] = a0.z; rv[c * 8 + 3] = a0.w;
      rv[c * 8 + 4] = a1.x; rv[c * 8 + 5] = a1.y; rv[c * 8 + 6] = a1.z; rv[c * 8 + 7] = a1.w;
    }
    FU ah[2]; pack8(ah[0], rv); pack8(ah[1], rv + 8);

    const int tt = wv;
    f32x4 R = MFMA(LDF(F_WIH + (tt * 3 + 0) * 512), gx[0].h, zf4);
    R = MFMA(LDF(F_WIH + (tt * 3 + 1) * 512), gx[1].h, R);
    R = MFMA(LDF(F_WIH + (tt * 3 + 2) * 512), px.h, R);
    R = MFMA(LDF(F_WHH + (tt * 2 + 0) * 512), ah[0].h, R);
    R = MFMA(LDF(F_WHH + (tt * 2 + 1) * 512), ah[1].h, R);
    f32x4 Z = MFMA(LDF(F_WIH + ((4 + tt) * 3 + 0) * 512), gx[0].h, zf4);
    Z = MFMA(LDF(F_WIH + ((4 + tt) * 3 + 1) * 512), gx[1].h, Z);
    Z = MFMA(LDF(F_WIH + ((4 + tt) * 3 + 2) * 512), px.h, Z);
    Z = MFMA(LDF(F_WHH + ((4 + tt) * 2 + 0) * 512), ah[0].h, Z);
    Z = MFMA(LDF(F_WHH + ((4 + tt) * 2 + 1) * 512), ah[1].h, Z);
    f32x4 Ni = MFMA(LDF(F_WIH + ((8 + tt) * 3 + 0) * 512), gx[0].h, zf4);
    Ni = MFMA(LDF(F_WIH + ((8 + tt) * 3 + 1) * 512), gx[1].h, Ni);
    Ni = MFMA(LDF(F_WIH + ((8 + tt) * 3 + 2) * 512), px.h, Ni);
    f32x4 Nh = MFMA(LDF(F_WHH + ((8 + tt) * 2 + 0) * 512), ah[0].h, zf4);
    Nh = MFMA(LDF(F_WHH + ((8 + tt) * 2 + 1) * 512), ah[1].h, Nh);

    const int dbase = q * 8 + (tt >> 1) * 32 + (tt & 1) * 4;
    f32x4 brv = *(const f32x4*)&g_grb[0][dbase];
    f32x4 bzv = *(const f32x4*)&g_grb[1][dbase];
    f32x4 bnv = *(const f32x4*)&g_grb[2][dbase];
    f32x4 bhv = *(const f32x4*)&g_grb[3][dbase];
    float nsv[4];
    #pragma unroll
    for (int i = 0; i < 4; i++) {
      const int K = (tt >> 1) * 32 + (tt & 1) * 4 + i;
      const int d = q * 8 + K;
      float rr = 1.f / (1.f + expf(-(R[i] + brv[i])));
      float zz = 1.f / (1.f + expf(-(Z[i] + bzv[i])));
      float ng = tanhf(Ni[i] + bnv[i] + rr * (Nh[i] + bhv[i]));
      float st = rv[(tt >> 1) * 8 + (tt & 1) * 4 + i];
      float v = (1.f - zz) * ng + zz * st;
      out[(size_t)B * 48 + (size_t)bb * 64 + d] = v;
      nsv[i] = v;
    }
    // ns quarter -> LDS: dwords (tt>>1)*4 + (tt&1)*2 + {0,1}
    const int dw = (tt >> 1) * 4 + (tt & 1) * 2;
    nsx[lane][dw]     = pk2(nsv[0], nsv[1]);
    nsx[lane][dw + 1] = pk2(nsv[2], nsv[3]);
  }
  __syncthreads();

  // ================= heads + pointer =================
  {
    FU an0, an1;
    an0.u = *(const u32x4*)&nsx[lane][0];
    an1.u = *(const u32x4*)&nsx[lane][4];
    float qv[16];
    #pragma unroll
    for (int mb = 0; mb < 4; mb++) {
      f32x4 Qc = MFMA(LDF(F_PQ + (mb * 2 + 0) * 512), an0.h, zf4);
      Qc = MFMA(LDF(F_PQ + (mb * 2 + 1) * 512), an1.h, Qc);
      f32x4 pq4 = *(const f32x4*)&pqb[mb * 16 + q * 4];
      #pragma unroll
      for (int i = 0; i < 4; i++) qv[mb * 4 + i] = Qc[i] + pq4[i];
    }
    float qb = 0.f;
    #pragma unroll
    for (int mb = 0; mb < 4; mb++) {
      f32x4 pk4 = *(const f32x4*)&pkb[mb * 16 + q * 4];
      #pragma unroll
      for (int i = 0; i < 4; i++) qb += qv[mb * 4 + i] * pk4[i];
    }
    qb += __shfl_xor(qb, 16, 64); qb += __shfl_xor(qb, 32, 64);

    if (wv < 2) {   // op/c1/c2 packed head: wave wv does mb2 = wv
      f32x4 L = MFMA(LDF(F_PACK + (wv * 2 + 0) * 512), an0.h, zf4);
      L = MFMA(LDF(F_PACK + (wv * 2 + 1) * 512), an1.h, L);
      #pragma unroll
      for (int i = 0; i < 4; i++) {
        int o = wv * 16 + q * 4 + i;
        if (o < 8)       out[(size_t)bb * 8 + o] = L[i] + opb[o];
        else if (o < 18) out[(size_t)B * 8 + (size_t)bb * 10 + (o - 8)] = L[i] + c1b[o - 8];
        else if (o < 28) out[(size_t)B * 18 + (size_t)bb * 10 + (o - 18)] = L[i] + c2b[o - 18];
      }
    }
    bf16x8 pkA[4][2];
    #pragma unroll
    for (int mb = 0; mb < 4; mb++) {
      pkA[mb][0] = LDF(F_PK + (mb * 2 + 0) * 512);
      pkA[mb][1] = LDF(F_PK + (mb * 2 + 1) * 512);
    }
    #pragma unroll
    for (int t = 0; t < 5; t++) {
      const int n = wv + 4 * t;
      if (t < nact) {
        float dt = 0.f;
        #pragma unroll
        for (int mb = 0; mb < 4; mb++) {
          f32x4 Kc = MFMA(pkA[mb][0], hA[t][0].h, zf4);
          Kc = MFMA(pkA[mb][1], hA[t][1].h, Kc);
          #pragma unroll
          for (int i = 0; i < 4; i++) dt += qv[mb * 4 + i] * Kc[i];
        }
        dt += __shfl_xor(dt, 16, 64); dt += __shfl_xor(dt, 32, 64);
        if (q == 0)
          out[(size_t)B * 28 + (size_t)bb * 20 + n] = (n < nnv) ? (dt + qb) : -1e9f;
      } else {
        if (q == 0)
          out[(size_t)B * 28 + (size_t)bb * 20 + n] = -1e9f;   // n >= M >= nnv
      }
    }
  }
}

extern "C" void kernel_launch(void* const* d_in, const int* in_sizes, int n_in,
                              void* d_out, int out_size, void* d_ws, size_t ws_size,
                              hipStream_t stream)
{
  (void)n_in; (void)out_size; (void)d_ws; (void)ws_size;
  const float* nf   = (const float*)d_in[0];
  const int*   nnp  = (const int*)  d_in[1];
  const float* rnn  = (const float*)d_in[2];
  const float* poh  = (const float*)d_in[3];
  const float* ne_w = (const float*)d_in[4];
  const float* ne_b = (const float*)d_in[5];
  const float* m1w1 = (const float*)d_in[6];
  const float* m1b1 = (const float*)d_in[7];
  const float* m1w2 = (const float*)d_in[8];
  const float* m1b2 = (const float*)d_in[9];
  const float* n1g  = (const float*)d_in[10];
  const float* n1b  = (const float*)d_in[11];
  const float* m2w1 = (const float*)d_in[12];
  const float* m2b1 = (const float*)d_in[13];
  const float* m2w2 = (const float*)d_in[14];
  const float* m2b2 = (const float*)d_in[15];
  const float* n2g  = (const float*)d_in[16];
  const float* n2b  = (const float*)d_in[17];
  const float* wih  = (const float*)d_in[18];
  const float* whh  = (const float*)d_in[19];
  const float* bih  = (const float*)d_in[20];
  const float* bhh  = (const float*)d_in[21];
  const float* opw  = (const float*)d_in[22];
  const float* opb  = (const float*)d_in[23];
  const float* c1w  = (const float*)d_in[24];
  const float* c1b  = (const float*)d_in[25];
  const float* c2w  = (const float*)d_in[26];
  const float* c2b  = (const float*)d_in[27];
  const float* pqw  = (const float*)d_in[28];
  const float* pqb  = (const float*)d_in[29];
  const float* pkw  = (const float*)d_in[30];
  const float* pkb  = (const float*)d_in[31];
  float* out = (float*)d_out;
  const int B = in_sizes[1];

  prep_frag<<<132, 256, 0, stream>>>(ne_w, m1w1, m1w2, m2w1, m2w2,
                                     wih, whh, pqw, opw, c1w, c2w, pkw,
                                     ne_b, m1b1, m1b2, n1g, n1b,
                                     m2b1, m2b2, n2g, n2b, bih, bhh);
  nn_hist<<<256, 256, 0, stream>>>(nnp, B);
  nn_scatter<<<(B + 255) / 256, 256, 0, stream>>>(nnp, B);
  msp<<<B / 16, 256, 0, stream>>>(nf, nnp, rnn, poh,
                                  opb, c1b, c2b,
                                  pqb, pkb, out, B);
}

// Round 3
// 419.076 us; speedup vs baseline: 1.7069x; 1.7069x over previous
//
#include <hip/hip_runtime.h>
#include <hip/hip_bf16.h>
#include <cstdint>

#define NM 20
#define NBIN 20
#define MAXB 65536

typedef __attribute__((ext_vector_type(8))) short bf16x8;
typedef __attribute__((ext_vector_type(4))) float f32x4;
typedef __attribute__((ext_vector_type(4))) unsigned int u32x4;

union FU { bf16x8 h; u32x4 u; };

#define MFMA(A, Bf, C) __builtin_amdgcn_mfma_f32_16x16x32_bf16((A), (Bf), (C), 0, 0, 0)

// A-fragment-packed, ROW-PERMUTED weights (bf16), built by prep each launch.
#define F_NE    0        // 4 frags  (4mb x 1kc, K=16 pad 32; col 16 = ne_b)
#define F_M1W1  2048     // 16       (4mb x 4kc, K=128)
#define F_M1W2  10240    // 8        (4mb x 2kc)
#define F_M2W1  14336    // 16
#define F_M2W2  22528    // 8
#define F_WIH   26624    // 36       (12mb x 3kc, K=72 pad 96)
#define F_WHH   45056    // 24       (12mb x 2kc)
#define F_PQ    57344    // 8        (identity rows)
#define F_PK    61440    // 8        (identity rows)
#define F_PACK  65536    // 4        (2mb x 2kc, rows = op|c1|c2 pad 32)
// bf16-packed bias/LN vectors (natural feature order, 64 each)
#define F_BNE   67584
#define F_B11   67648
#define F_B12   67712
#define F_G1    67776
#define F_L1    67840
#define F_B21   67904
#define F_B22   67968
#define F_G2    68032
#define F_L2    68096
#define F_TOTAL 68160

__device__ __align__(16) short g_fr[F_TOTAL];
// GRU gate biases, f32, float4-loadable: [0]=bih+bhh (r), [1]=bih+bhh (z),
// [2]=bih (n), [3]=bhh (n)
__device__ __align__(16) float g_grb[4][64];
__device__ int g_hist[NBIN];
__device__ int g_off[NBIN];
__device__ int g_done;
__device__ int g_perm[MAXB];

__device__ __forceinline__ short bf16rn(float x) {
  unsigned u = __float_as_uint(x);
  u += 0x7fffu + ((u >> 16) & 1u);
  return (short)(u >> 16);
}
__device__ __forceinline__ float bf2f(short s) {
  return __uint_as_float(((unsigned)(unsigned short)s) << 16);
}
__device__ __forceinline__ unsigned pk2(float lo, float hi) {
  __hip_bfloat162 t = __float22bfloat162_rn(float2{lo, hi});
  return *reinterpret_cast<unsigned*>(&t);
}
// slot permutation: C row r (=mb*16+qq*4+i) lands at slot s64(r); permuting weight
// rows by s64 makes the C-output the B-fragment of the next GEMM, register-locally.
__device__ __forceinline__ int s64(int r) {
  int mb = r >> 4, qq = (r >> 2) & 3, i = r & 3;
  return (mb >> 1) * 32 + qq * 8 + (mb & 1) * 4 + i;
}

#define LDF(off) (*(const bf16x8*)(g_fr + (off) + lane * 8))
#define LDB(off, c) (*(const bf16x8*)(g_fr + (off) + (c) * 32 + q * 8))
// z-variants: opaque 0 addend defeats LICM/scheduler hoisting (keeps live ranges short)
#define LDFz(off, z) (*(const bf16x8*)(g_fr + (off) + lane * 8 + (z)))
#define LDBz(off, c, z) (*(const bf16x8*)(g_fr + (off) + (c) * 32 + q * 8 + (z)))

// ---------------- prep ----------------
#define BUILDA(OFS, MB, KC, ROWX, GET)                                 \
  for (int idx = t; idx < (MB) * (KC) * 512; idx += T) {               \
    int j = idx & 7, ln = (idx >> 3) & 63, f = idx >> 9;               \
    int mb = f / (KC), kc = f % (KC);                                  \
    int m = mb * 16 + (ln & 15);                                       \
    int k = kc * 32 + (ln >> 4) * 8 + j;                               \
    int row = (ROWX);                                                  \
    (void)row; (void)k; (void)m;                                       \
    g_fr[(OFS) + idx] = bf16rn(GET);                                   \
  }

__global__ void __launch_bounds__(256)
prep_frag(const float* __restrict__ ne_w,
          const float* __restrict__ m1w1, const float* __restrict__ m1w2,
          const float* __restrict__ m2w1, const float* __restrict__ m2w2,
          const float* __restrict__ wih,  const float* __restrict__ whh,
          const float* __restrict__ pqw,  const float* __restrict__ opw,
          const float* __restrict__ c1w,  const float* __restrict__ c2w,
          const float* __restrict__ pkw,
          const float* __restrict__ ne_b,
          const float* __restrict__ m1b1, const float* __restrict__ m1b2,
          const float* __restrict__ n1g,  const float* __restrict__ n1b,
          const float* __restrict__ m2b1, const float* __restrict__ m2b2,
          const float* __restrict__ n2g,  const float* __restrict__ n2b,
          const float* __restrict__ bih,  const float* __restrict__ bhh)
{
  const int t = blockIdx.x * blockDim.x + threadIdx.x;
  const int T = gridDim.x * blockDim.x;
  if (blockIdx.x == 0 && threadIdx.x < NBIN) g_hist[threadIdx.x] = 0;
  if (blockIdx.x == 0 && threadIdx.x == 0) g_done = 0;
  // ne_b folded into K-pad column 16 (B supplies constant 1.0 at k=16)
  BUILDA(F_NE,   4, 1, s64(m), (k < 16 ? ne_w[row * 16 + k] : (k == 16 ? ne_b[row] : 0.f)))
  BUILDA(F_M1W1, 4, 4, s64(m), m1w1[row * 128 + k])
  BUILDA(F_M1W2, 4, 2, s64(m), m1w2[row * 64 + k])
  BUILDA(F_M2W1, 4, 4, s64(m), m2w1[row * 128 + k])
  BUILDA(F_M2W2, 4, 2, s64(m), m2w2[row * 64 + k])
  BUILDA(F_WIH, 12, 3, (m & 0xC0) | s64(m & 63), (k < 72 ? wih[row * 72 + k] : 0.f))
  BUILDA(F_WHH, 12, 2, (m & 0xC0) | s64(m & 63), whh[row * 64 + k])
  BUILDA(F_PQ,   4, 2, m, pqw[row * 64 + k])
  BUILDA(F_PK,   4, 2, m, pkw[row * 64 + k])
  BUILDA(F_PACK, 2, 2, m, (row < 8 ? opw[row * 64 + k]
                           : row < 18 ? c1w[(row - 8) * 64 + k]
                           : row < 28 ? c2w[(row - 18) * 64 + k] : 0.f))
  for (int i = t; i < 64; i += T) {
    g_fr[F_BNE + i] = bf16rn(ne_b[i]);
    g_fr[F_B11 + i] = bf16rn(m1b1[i]);
    g_fr[F_B12 + i] = bf16rn(m1b2[i]);
    g_fr[F_G1  + i] = bf16rn(n1g[i]);
    g_fr[F_L1  + i] = bf16rn(n1b[i]);
    g_fr[F_B21 + i] = bf16rn(m2b1[i]);
    g_fr[F_B22 + i] = bf16rn(m2b2[i]);
    g_fr[F_G2  + i] = bf16rn(n2g[i]);
    g_fr[F_L2  + i] = bf16rn(n2b[i]);
    g_grb[0][i] = bih[i]       + bhh[i];
    g_grb[1][i] = bih[64 + i]  + bhh[64 + i];
    g_grb[2][i] = bih[128 + i];
    g_grb[3][i] = bhh[128 + i];
  }
}

// ---------------- counting sort by n_nodes: hist (+ last-block scan) ------------
__global__ void __launch_bounds__(256)
nn_hist(const int* __restrict__ nnp, int B)
{
  __shared__ int lh[NBIN];
  __shared__ int lastdone;
  const int t = threadIdx.x;
  if (t < NBIN) lh[t] = 0;
  __syncthreads();
  for (int i = blockIdx.x * blockDim.x + t; i < B; i += gridDim.x * blockDim.x)
    atomicAdd(&lh[nnp[i] - 1], 1);
  __syncthreads();
  if (t < NBIN && lh[t] > 0) atomicAdd(&g_hist[t], lh[t]);
  __threadfence();
  if (t == 0) lastdone = (atomicAdd(&g_done, 1) == (int)gridDim.x - 1);
  __syncthreads();
  if (t == 0 && lastdone) {
    int acc = 0;
    for (int i = 0; i < NBIN; i++) { g_off[i] = acc; acc += g_hist[i]; }
  }
}

__global__ void __launch_bounds__(256)
nn_scatter(const int* __restrict__ nnp, int B)
{
  __shared__ int lc[NBIN], lbase[NBIN];
  const int t = threadIdx.x;
  const int i = blockIdx.x * 256 + t;
  if (t < NBIN) lc[t] = 0;
  __syncthreads();
  int bin = 0, r = 0;
  const bool ok = (i < B);
  if (ok) { bin = nnp[i] - 1; r = atomicAdd(&lc[bin], 1); }
  __syncthreads();
  if (t < NBIN) lbase[t] = (lc[t] > 0) ? atomicAdd(&g_off[t], lc[t]) : 0;
  __syncthreads();
  if (ok) g_perm[lbase[bin] + r] = i;
}

__device__ __forceinline__ void pack8(FU& f, const float* v) {
  f.u[0] = pk2(v[0], v[1]); f.u[1] = pk2(v[2], v[3]);
  f.u[2] = pk2(v[4], v[5]); f.u[3] = pk2(v[6], v[7]);
}

// ---------------- MP stage: interleaved nodes n = wv + 4t, skip t >= nact --------
// Weights re-loaded per node (L1/L2-hot) to keep register live ranges short.
__device__ __forceinline__ void mp_stage(
    FU hA[][2], const FU* msgf,
    int w1off, int w2off, int b1o, int b2o, int lgo, int lbo,
    int nnv, int wv, int nact, int lane, int q)
{
  if (nact == 0) return;
  const f32x4 zf4 = {0.f, 0.f, 0.f, 0.f};
  f32x4 tmsg[4];
  #pragma unroll
  for (int mb = 0; mb < 4; mb++) {
    tmsg[mb] = MFMA(LDF(w1off + (mb * 4 + 2) * 512), msgf[0].h, zf4);
    tmsg[mb] = MFMA(LDF(w1off + (mb * 4 + 3) * 512), msgf[1].h, tmsg[mb]);
  }
  {
    // hoist b1 bias: added once per wave instead of once per node
    FU b1p0, b1p1; b1p0.h = LDB(b1o, 0); b1p1.h = LDB(b1o, 1);
    #pragma unroll
    for (int mb = 0; mb < 4; mb++)
      #pragma unroll
      for (int i = 0; i < 4; i++)
        tmsg[mb][i] += bf2f(((mb >> 1) ? b1p1 : b1p0).h[(mb & 1) * 4 + i]);
  }

  #pragma unroll
  for (int t = 0; t < 5; t++) {
    if (t < nact) {
      int tz = 0;
      asm volatile("" : "+v"(tz));
      const int n = wv + 4 * t;
      f32x4 T[4];
      #pragma unroll
      for (int mb = 0; mb < 4; mb++) {
        T[mb] = MFMA(LDFz(w1off + (mb * 4 + 0) * 512, tz), hA[t][0].h, tmsg[mb]);
        T[mb] = MFMA(LDFz(w1off + (mb * 4 + 1) * 512, tz), hA[t][1].h, T[mb]);
      }
      FU tb[2];
      #pragma unroll
      for (int c = 0; c < 2; c++)
        #pragma unroll
        for (int w = 0; w < 4; w++) {
          int mb = 2 * c + (w >> 1), i0 = (w & 1) * 2;
          float lo = fmaxf(T[mb][i0],     0.f);
          float hi = fmaxf(T[mb][i0 + 1], 0.f);
          tb[c].u[w] = pk2(lo, hi);
        }
      f32x4 H[4];
      #pragma unroll
      for (int mb = 0; mb < 4; mb++) {
        H[mb] = MFMA(LDFz(w2off + (mb * 2 + 0) * 512, tz), tb[0].h, zf4);
        H[mb] = MFMA(LDFz(w2off + (mb * 2 + 1) * 512, tz), tb[1].h, H[mb]);
      }
      FU b2p0, b2p1;
      b2p0.h = LDBz(b2o, 0, tz); b2p1.h = LDBz(b2o, 1, tz);
      float y[16]; float s = 0.f, ss = 0.f;
      #pragma unroll
      for (int k = 0; k < 16; k++) {
        int c = k >> 3, j = k & 7;
        float v = H[2 * c + (j >> 2)][j & 3] + bf2f((c ? b2p1 : b2p0).h[j]) +
                  bf2f(hA[t][c].h[j]);
        y[k] = v; s += v; ss += v * v;
      }
      s += __shfl_xor(s, 16, 64); ss += __shfl_xor(ss, 16, 64);
      s += __shfl_xor(s, 32, 64); ss += __shfl_xor(ss, 32, 64);
      float mu = s * 0.015625f;
      float rstd = rsqrtf(ss * 0.015625f - mu * mu + 1e-5f);
      float mfv = (n < nnv) ? 1.f : 0.f;
      FU lgp0, lgp1, lbp0, lbp1;
      lgp0.h = LDBz(lgo, 0, tz); lgp1.h = LDBz(lgo, 1, tz);
      lbp0.h = LDBz(lbo, 0, tz); lbp1.h = LDBz(lbo, 1, tz);
      #pragma unroll
      for (int k = 0; k < 16; k++) {
        int c = k >> 3, j = k & 7;
        float hv = ((y[k] - mu) * rstd * bf2f((c ? lgp1 : lgp0).h[j]) +
                    bf2f((c ? lbp1 : lbp0).h[j])) * mfv;
        y[k] = hv;
      }
      pack8(hA[t][0], y); pack8(hA[t][1], y + 8);
    }
  }
}

// ---------------- main: 16 sorted batch / block, interleaved node ownership ------
__global__ void __launch_bounds__(256)
msp(const float* __restrict__ nf, const int* __restrict__ nnp,
    const float* __restrict__ rnn, const float* __restrict__ poh,
    const float* __restrict__ opb, const float* __restrict__ c1b,
    const float* __restrict__ c2b, const float* __restrict__ pqb,
    const float* __restrict__ pkb,
    float* __restrict__ out, int B)
{
  __shared__ __align__(16) float exch[2][4][64][17];   // 34816 B
  __shared__ __align__(16) unsigned nsx[64][8];        // 2048 B

  const int tid = threadIdx.x;
  const int wv = tid >> 6;
  const int lane = tid & 63;
  const int l15 = lane & 15, q = lane >> 4;
  const int b0 = blockIdx.x * 16;
  const int bb = g_perm[b0 + l15];

  const int nnv = nnp[bb];
  const float inv = 1.0f / (float)nnv;
  const f32x4 zf4 = {0.f, 0.f, 0.f, 0.f};

  // block-max nnv (same 16 samples for all waves): reduce within 16-lane groups
  int M = nnv;
  { int o;
    o = __shfl_xor(M, 1, 64); M = M > o ? M : o;
    o = __shfl_xor(M, 2, 64); M = M > o ? M : o;
    o = __shfl_xor(M, 4, 64); M = M > o ? M : o;
    o = __shfl_xor(M, 8, 64); M = M > o ? M : o; }
  // this wave owns nodes n = wv + 4t, t in [0, nact)
  int nact = (M - wv + 3) >> 2;
  nact = nact < 0 ? 0 : (nact > 5 ? 5 : nact);

  FU hA[5][2];
  #pragma unroll
  for (int t5 = 0; t5 < 5; t5++)
    #pragma unroll
    for (int c = 0; c < 2; c++) {
      hA[t5][c].u[0] = 0; hA[t5][c].u[1] = 0;
      hA[t5][c].u[2] = 0; hA[t5][c].u[3] = 0;
    }

  // ================= E: h0^T = ne_w' · x^T (bias via k=16 pad column) ==========
  {
    #pragma unroll
    for (int t = 0; t < 5; t++) {
      if (t < nact) {
        int tz = 0;
        asm volatile("" : "+v"(tz));
        const int n = wv + 4 * t;
        FU bx;
        bx.u[0] = 0; bx.u[1] = 0; bx.u[2] = 0; bx.u[3] = 0;
        if (q < 2) {
          const float* p = nf + ((size_t)bb * NM + n) * 16 + q * 8;
          float4 x0 = *(const float4*)p, x1 = *(const float4*)(p + 4);
          bx.u[0] = pk2(x0.x, x0.y); bx.u[1] = pk2(x0.z, x0.w);
          bx.u[2] = pk2(x1.x, x1.y); bx.u[3] = pk2(x1.z, x1.w);
        } else if (q == 2) {
          bx.u[0] = pk2(1.f, 0.f);   // k=16 constant-1 -> ne_b column
        }
        f32x4 C[4];
        #pragma unroll
        for (int mb = 0; mb < 4; mb++) C[mb] = MFMA(LDFz(F_NE + mb * 512, tz), bx.h, zf4);
        float hv[16];
        #pragma unroll
        for (int k = 0; k < 16; k++) {
          int c = k >> 3, j = k & 7;
          hv[k] = C[2 * c + (j >> 2)][j & 3];
        }
        pack8(hA[t][0], hv); pack8(hA[t][1], hv + 8);
      }
    }
  }

  FU msgf[2];
  // masked per-wave node-sum recomputed from hA (stage outputs are already
  // mask-zeroed; the n<nnv select also covers E's unmasked h0 and stale slots)
  #define EXCHANGE(REG)                                                        \
    {                                                                          \
      _Pragma("unroll")                                                        \
      for (int k = 0; k < 16; k++) {                                           \
        int c = k >> 3, j = k & 7;                                             \
        float sK = 0.f;                                                        \
        _Pragma("unroll")                                                      \
        for (int t5 = 0; t5 < 5; t5++) {                                       \
          float vv = bf2f(hA[t5][c].h[j]);                                     \
          sK += (wv + 4 * t5 < nnv) ? vv : 0.f;                                \
        }                                                                      \
        exch[REG][wv][lane][k] = sK;                                           \
      }                                                                        \
      __syncthreads();                                                         \
      _Pragma("unroll")                                                        \
      for (int w8 = 0; w8 < 8; w8++) {                                         \
        int k0 = 2 * w8, k1 = k0 + 1;                                          \
        float a = (exch[REG][0][lane][k0] + exch[REG][1][lane][k0] +           \
                   exch[REG][2][lane][k0] + exch[REG][3][lane][k0]) * inv;     \
        float b = (exch[REG][0][lane][k1] + exch[REG][1][lane][k1] +           \
                   exch[REG][2][lane][k1] + exch[REG][3][lane][k1]) * inv;     \
        FU* dp = (w8 < 4) ? &msgf[0] : &msgf[1];                               \
        dp->u[w8 & 3] = pk2(a, b);                                             \
      }                                                                        \
    }

  EXCHANGE(0)   // msg1
  mp_stage(hA, msgf, F_M1W1, F_M1W2, F_B11, F_B12, F_G1, F_L1, nnv, wv, nact, lane, q);

  EXCHANGE(1)   // msg2
  mp_stage(hA, msgf, F_M2W1, F_M2W2, F_B21, F_B22, F_G2, F_L2, nnv, wv, nact, lane, q);

  EXCHANGE(0)   // graph_vec -> msgf (region 0 safe: all reads done pre-stage2 barrier)

  // ================= GRU: wave wv owns gate tile tt = wv; gx == msgf ==========
  {
    FU px;
    if (q == 0) {
      const float* pp = poh + (size_t)bb * 8;
      float4 p0 = *(const float4*)pp, p1 = *(const float4*)(pp + 4);
      px.u[0] = pk2(p0.x, p0.y); px.u[1] = pk2(p0.z, p0.w);
      px.u[2] = pk2(p1.x, p1.y); px.u[3] = pk2(p1.z, p1.w);
    } else { px.u[0] = 0; px.u[1] = 0; px.u[2] = 0; px.u[3] = 0; }
    const float* rr0 = rnn + (size_t)bb * 64;
    float rv[16];
    #pragma unroll
    for (int c = 0; c < 2; c++) {
      float4 a0 = *(const float4*)(rr0 + c * 32 + q * 8);
      float4 a1 = *(const float4*)(rr0 + c * 32 + q * 8 + 4);
      rv[c * 8 + 0] = a0.x; rv[c * 8 + 1] = a0.y; rv[c * 8 + 2] = a0.z; rv[c * 8 + 3] = a0.w;
      rv[c * 8 + 4] = a1.x; rv[c * 8 + 5] = a1.y; rv[c * 8 + 6] = a1.z; rv[c * 8 + 7] = a1.w;
    }
    FU ah[2]; pack8(ah[0], rv); pack8(ah[1], rv + 8);

    const int tt = wv;
    f32x4 R = MFMA(LDF(F_WIH + (tt * 3 + 0) * 512), msgf[0].h, zf4);
    R = MFMA(LDF(F_WIH + (tt * 3 + 1) * 512), msgf[1].h, R);
    R = MFMA(LDF(F_WIH + (tt * 3 + 2) * 512), px.h, R);
    R = MFMA(LDF(F_WHH + (tt * 2 + 0) * 512), ah[0].h, R);
    R = MFMA(LDF(F_WHH + (tt * 2 + 1) * 512), ah[1].h, R);
    f32x4 Z = MFMA(LDF(F_WIH + ((4 + tt) * 3 + 0) * 512), msgf[0].h, zf4);
    Z = MFMA(LDF(F_WIH + ((4 + tt) * 3 + 1) * 512), msgf[1].h, Z);
    Z = MFMA(LDF(F_WIH + ((4 + tt) * 3 + 2) * 512), px.h, Z);
    Z = MFMA(LDF(F_WHH + ((4 + tt) * 2 + 0) * 512), ah[0].h, Z);
    Z = MFMA(LDF(F_WHH + ((4 + tt) * 2 + 1) * 512), ah[1].h, Z);
    f32x4 Ni = MFMA(LDF(F_WIH + ((8 + tt) * 3 + 0) * 512), msgf[0].h, zf4);
    Ni = MFMA(LDF(F_WIH + ((8 + tt) * 3 + 1) * 512), msgf[1].h, Ni);
    Ni = MFMA(LDF(F_WIH + ((8 + tt) * 3 + 2) * 512), px.h, Ni);
    f32x4 Nh = MFMA(LDF(F_WHH + ((8 + tt) * 2 + 0) * 512), ah[0].h, zf4);
    Nh = MFMA(LDF(F_WHH + ((8 + tt) * 2 + 1) * 512), ah[1].h, Nh);

    const int dbase = q * 8 + (tt >> 1) * 32 + (tt & 1) * 4;
    f32x4 brv = *(const f32x4*)&g_grb[0][dbase];
    f32x4 bzv = *(const f32x4*)&g_grb[1][dbase];
    f32x4 bnv = *(const f32x4*)&g_grb[2][dbase];
    f32x4 bhv = *(const f32x4*)&g_grb[3][dbase];
    float nsv[4];
    #pragma unroll
    for (int i = 0; i < 4; i++) {
      const int K = (tt >> 1) * 32 + (tt & 1) * 4 + i;
      const int d = q * 8 + K;
      float rr = 1.f / (1.f + expf(-(R[i] + brv[i])));
      float zz = 1.f / (1.f + expf(-(Z[i] + bzv[i])));
      float ng = tanhf(Ni[i] + bnv[i] + rr * (Nh[i] + bhv[i]));
      float st = rv[(tt >> 1) * 8 + (tt & 1) * 4 + i];
      float v = (1.f - zz) * ng + zz * st;
      out[(size_t)B * 48 + (size_t)bb * 64 + d] = v;
      nsv[i] = v;
    }
    // ns quarter -> LDS: dwords (tt>>1)*4 + (tt&1)*2 + {0,1}
    const int dw = (tt >> 1) * 4 + (tt & 1) * 2;
    nsx[lane][dw]     = pk2(nsv[0], nsv[1]);
    nsx[lane][dw + 1] = pk2(nsv[2], nsv[3]);
  }
  __syncthreads();

  // ================= heads + pointer =================
  {
    FU an0, an1;
    an0.u = *(const u32x4*)&nsx[lane][0];
    an1.u = *(const u32x4*)&nsx[lane][4];
    float qv[16];
    #pragma unroll
    for (int mb = 0; mb < 4; mb++) {
      f32x4 Qc = MFMA(LDF(F_PQ + (mb * 2 + 0) * 512), an0.h, zf4);
      Qc = MFMA(LDF(F_PQ + (mb * 2 + 1) * 512), an1.h, Qc);
      f32x4 pq4 = *(const f32x4*)&pqb[mb * 16 + q * 4];
      #pragma unroll
      for (int i = 0; i < 4; i++) qv[mb * 4 + i] = Qc[i] + pq4[i];
    }
    float qb = 0.f;
    #pragma unroll
    for (int mb = 0; mb < 4; mb++) {
      f32x4 pk4 = *(const f32x4*)&pkb[mb * 16 + q * 4];
      #pragma unroll
      for (int i = 0; i < 4; i++) qb += qv[mb * 4 + i] * pk4[i];
    }
    qb += __shfl_xor(qb, 16, 64); qb += __shfl_xor(qb, 32, 64);

    if (wv < 2) {   // op/c1/c2 packed head: wave wv does mb2 = wv
      f32x4 L = MFMA(LDF(F_PACK + (wv * 2 + 0) * 512), an0.h, zf4);
      L = MFMA(LDF(F_PACK + (wv * 2 + 1) * 512), an1.h, L);
      #pragma unroll
      for (int i = 0; i < 4; i++) {
        int o = wv * 16 + q * 4 + i;
        if (o < 8)       out[(size_t)bb * 8 + o] = L[i] + opb[o];
        else if (o < 18) out[(size_t)B * 8 + (size_t)bb * 10 + (o - 8)] = L[i] + c1b[o - 8];
        else if (o < 28) out[(size_t)B * 18 + (size_t)bb * 10 + (o - 18)] = L[i] + c2b[o - 18];
      }
    }
    #pragma unroll
    for (int t = 0; t < 5; t++) {
      const int n = wv + 4 * t;
      if (t < nact) {
        int tz = 0;
        asm volatile("" : "+v"(tz));
        float dt = 0.f;
        #pragma unroll
        for (int mb = 0; mb < 4; mb++) {
          f32x4 Kc = MFMA(LDFz(F_PK + (mb * 2 + 0) * 512, tz), hA[t][0].h, zf4);
          Kc = MFMA(LDFz(F_PK + (mb * 2 + 1) * 512, tz), hA[t][1].h, Kc);
          #pragma unroll
          for (int i = 0; i < 4; i++) dt += qv[mb * 4 + i] * Kc[i];
        }
        dt += __shfl_xor(dt, 16, 64); dt += __shfl_xor(dt, 32, 64);
        if (q == 0)
          out[(size_t)B * 28 + (size_t)bb * 20 + n] = (n < nnv) ? (dt + qb) : -1e9f;
      } else {
        if (q == 0)
          out[(size_t)B * 28 + (size_t)bb * 20 + n] = -1e9f;   // n >= M >= nnv
      }
    }
  }
}

extern "C" void kernel_launch(void* const* d_in, const int* in_sizes, int n_in,
                              void* d_out, int out_size, void* d_ws, size_t ws_size,
                              hipStream_t stream)
{
  (void)n_in; (void)out_size; (void)d_ws; (void)ws_size;
  const float* nf   = (const float*)d_in[0];
  const int*   nnp  = (const int*)  d_in[1];
  const float* rnn  = (const float*)d_in[2];
  const float* poh  = (const float*)d_in[3];
  const float* ne_w = (const float*)d_in[4];
  const float* ne_b = (const float*)d_in[5];
  const float* m1w1 = (const float*)d_in[6];
  const float* m1b1 = (const float*)d_in[7];
  const float* m1w2 = (const float*)d_in[8];
  const float* m1b2 = (const float*)d_in[9];
  const float* n1g  = (const float*)d_in[10];
  const float* n1b  = (const float*)d_in[11];
  const float* m2w1 = (const float*)d_in[12];
  const float* m2b1 = (const float*)d_in[13];
  const float* m2w2 = (const float*)d_in[14];
  const float* m2b2 = (const float*)d_in[15];
  const float* n2g  = (const float*)d_in[16];
  const float* n2b  = (const float*)d_in[17];
  const float* wih  = (const float*)d_in[18];
  const float* whh  = (const float*)d_in[19];
  const float* bih  = (const float*)d_in[20];
  const float* bhh  = (const float*)d_in[21];
  const float* opw  = (const float*)d_in[22];
  const float* opb  = (const float*)d_in[23];
  const float* c1w  = (const float*)d_in[24];
  const float* c1b  = (const float*)d_in[25];
  const float* c2w  = (const float*)d_in[26];
  const float* c2b  = (const float*)d_in[27];
  const float* pqw  = (const float*)d_in[28];
  const float* pqb  = (const float*)d_in[29];
  const float* pkw  = (const float*)d_in[30];
  const float* pkb  = (const float*)d_in[31];
  float* out = (float*)d_out;
  const int B = in_sizes[1];

  prep_frag<<<132, 256, 0, stream>>>(ne_w, m1w1, m1w2, m2w1, m2w2,
                                     wih, whh, pqw, opw, c1w, c2w, pkw,
                                     ne_b, m1b1, m1b2, n1g, n1b,
                                     m2b1, m2b2, n2g, n2b, bih, bhh);
  nn_hist<<<256, 256, 0, stream>>>(nnp, B);
  nn_scatter<<<(B + 255) / 256, 256, 0, stream>>>(nnp, B);
  msp<<<B / 16, 256, 0, stream>>>(nf, nnp, rnn, poh,
                                  opb, c1b, c2b,
                                  pqb, pkb, out, B);
}

// Round 4
// 401.839 us; speedup vs baseline: 1.7801x; 1.0429x over previous
//
#include <hip/hip_runtime.h>
#include <hip/hip_bf16.h>
#include <cstdint>

#define NM 20
#define NBIN 20
#define MAXB 65536

typedef __attribute__((ext_vector_type(8))) short bf16x8;
typedef __attribute__((ext_vector_type(4))) float f32x4;
typedef __attribute__((ext_vector_type(4))) unsigned int u32x4;

union FU { bf16x8 h; u32x4 u; };

#define MFMA(A, Bf, C) __builtin_amdgcn_mfma_f32_16x16x32_bf16((A), (Bf), (C), 0, 0, 0)

// A-fragment-packed, ROW-PERMUTED weights (bf16), built by prep each launch.
#define F_NE    0        // 4 frags  (4mb x 1kc, K=16 pad 32; col 16 = ne_b)
#define F_M1W1  2048     // 16       (4mb x 4kc, K=128)
#define F_M1W2  10240    // 8        (4mb x 2kc)
#define F_M2W1  14336    // 16
#define F_M2W2  22528    // 8
#define F_WIH   26624    // 36       (12mb x 3kc, K=72 pad 96)
#define F_WHH   45056    // 24       (12mb x 2kc)
#define F_PQ    57344    // 8        (identity rows)
#define F_PK    61440    // 8        (identity rows)
#define F_PACK  65536    // 4        (2mb x 2kc, rows = op|c1|c2 pad 32)
// bf16-packed bias/LN vectors (natural feature order, 64 each)
#define F_BNE   67584
#define F_B11   67648
#define F_B12   67712
#define F_G1    67776
#define F_L1    67840
#define F_B21   67904
#define F_B22   67968
#define F_G2    68032
#define F_L2    68096
#define F_TOTAL 68160

__device__ __align__(16) short g_fr[F_TOTAL];
// GRU gate biases, f32, float4-loadable: [0]=bih+bhh (r), [1]=bih+bhh (z),
// [2]=bih (n), [3]=bhh (n)
__device__ __align__(16) float g_grb[4][64];
__device__ int g_hist[NBIN];
__device__ int g_off[NBIN];
__device__ int g_done;
__device__ int g_perm[MAXB];

__device__ __forceinline__ short bf16rn(float x) {
  unsigned u = __float_as_uint(x);
  u += 0x7fffu + ((u >> 16) & 1u);
  return (short)(u >> 16);
}
__device__ __forceinline__ float bf2f(short s) {
  return __uint_as_float(((unsigned)(unsigned short)s) << 16);
}
__device__ __forceinline__ unsigned pk2(float lo, float hi) {
  __hip_bfloat162 t = __float22bfloat162_rn(float2{lo, hi});
  return *reinterpret_cast<unsigned*>(&t);
}
// fast GRU activations: v_exp_f32 + v_rcp_f32 (err ~1e-6, well within tolerance)
__device__ __forceinline__ float fsig(float x) {
  return __builtin_amdgcn_rcpf(1.f + __expf(-x));
}
__device__ __forceinline__ float ftanh(float x) {
  return 1.f - 2.f * __builtin_amdgcn_rcpf(1.f + __expf(2.f * x));
}
// slot permutation: C row r (=mb*16+qq*4+i) lands at slot s64(r); permuting weight
// rows by s64 makes the C-output the B-fragment of the next GEMM, register-locally.
__device__ __forceinline__ int s64(int r) {
  int mb = r >> 4, qq = (r >> 2) & 3, i = r & 3;
  return (mb >> 1) * 32 + qq * 8 + (mb & 1) * 4 + i;
}

#define LDF(off) (*(const bf16x8*)(g_fr + (off) + lane * 8))
#define LDB(off, c) (*(const bf16x8*)(g_fr + (off) + (c) * 32 + q * 8))
// node-local bases (gA/gB include an opaque 0 so loads can't be hoisted/LICM'd)
#define GAF(off) (*(const bf16x8*)(gA + (off)))
#define GBF(off, c) (*(const bf16x8*)(gB + (off) + (c) * 32))

// ---------------- prep ----------------
#define BUILDA(OFS, MB, KC, ROWX, GET)                                 \
  for (int idx = t; idx < (MB) * (KC) * 512; idx += T) {               \
    int j = idx & 7, ln = (idx >> 3) & 63, f = idx >> 9;               \
    int mb = f / (KC), kc = f % (KC);                                  \
    int m = mb * 16 + (ln & 15);                                       \
    int k = kc * 32 + (ln >> 4) * 8 + j;                               \
    int row = (ROWX);                                                  \
    (void)row; (void)k; (void)m;                                       \
    g_fr[(OFS) + idx] = bf16rn(GET);                                   \
  }

__global__ void __launch_bounds__(256)
prep_frag(const float* __restrict__ ne_w,
          const float* __restrict__ m1w1, const float* __restrict__ m1w2,
          const float* __restrict__ m2w1, const float* __restrict__ m2w2,
          const float* __restrict__ wih,  const float* __restrict__ whh,
          const float* __restrict__ pqw,  const float* __restrict__ opw,
          const float* __restrict__ c1w,  const float* __restrict__ c2w,
          const float* __restrict__ pkw,
          const float* __restrict__ ne_b,
          const float* __restrict__ m1b1, const float* __restrict__ m1b2,
          const float* __restrict__ n1g,  const float* __restrict__ n1b,
          const float* __restrict__ m2b1, const float* __restrict__ m2b2,
          const float* __restrict__ n2g,  const float* __restrict__ n2b,
          const float* __restrict__ bih,  const float* __restrict__ bhh)
{
  const int t = blockIdx.x * blockDim.x + threadIdx.x;
  const int T = gridDim.x * blockDim.x;
  if (blockIdx.x == 0 && threadIdx.x < NBIN) g_hist[threadIdx.x] = 0;
  if (blockIdx.x == 0 && threadIdx.x == 0) g_done = 0;
  // ne_b folded into K-pad column 16 (B supplies constant 1.0 at k=16)
  BUILDA(F_NE,   4, 1, s64(m), (k < 16 ? ne_w[row * 16 + k] : (k == 16 ? ne_b[row] : 0.f)))
  BUILDA(F_M1W1, 4, 4, s64(m), m1w1[row * 128 + k])
  BUILDA(F_M1W2, 4, 2, s64(m), m1w2[row * 64 + k])
  BUILDA(F_M2W1, 4, 4, s64(m), m2w1[row * 128 + k])
  BUILDA(F_M2W2, 4, 2, s64(m), m2w2[row * 64 + k])
  BUILDA(F_WIH, 12, 3, (m & 0xC0) | s64(m & 63), (k < 72 ? wih[row * 72 + k] : 0.f))
  BUILDA(F_WHH, 12, 2, (m & 0xC0) | s64(m & 63), whh[row * 64 + k])
  BUILDA(F_PQ,   4, 2, m, pqw[row * 64 + k])
  BUILDA(F_PK,   4, 2, m, pkw[row * 64 + k])
  BUILDA(F_PACK, 2, 2, m, (row < 8 ? opw[row * 64 + k]
                           : row < 18 ? c1w[(row - 8) * 64 + k]
                           : row < 28 ? c2w[(row - 18) * 64 + k] : 0.f))
  for (int i = t; i < 64; i += T) {
    g_fr[F_BNE + i] = bf16rn(ne_b[i]);
    g_fr[F_B11 + i] = bf16rn(m1b1[i]);
    g_fr[F_B12 + i] = bf16rn(m1b2[i]);
    g_fr[F_G1  + i] = bf16rn(n1g[i]);
    g_fr[F_L1  + i] = bf16rn(n1b[i]);
    g_fr[F_B21 + i] = bf16rn(m2b1[i]);
    g_fr[F_B22 + i] = bf16rn(m2b2[i]);
    g_fr[F_G2  + i] = bf16rn(n2g[i]);
    g_fr[F_L2  + i] = bf16rn(n2b[i]);
    g_grb[0][i] = bih[i]       + bhh[i];
    g_grb[1][i] = bih[64 + i]  + bhh[64 + i];
    g_grb[2][i] = bih[128 + i];
    g_grb[3][i] = bhh[128 + i];
  }
}

// ---------------- counting sort by n_nodes: hist (+ last-block DESCENDING scan) --
// Descending (LPT): heavy blocks (large nnv) dispatch first, light blocks backfill
// the drain tail.
__global__ void __launch_bounds__(256)
nn_hist(const int* __restrict__ nnp, int B)
{
  __shared__ int lh[NBIN];
  __shared__ int lastdone;
  const int t = threadIdx.x;
  if (t < NBIN) lh[t] = 0;
  __syncthreads();
  for (int i = blockIdx.x * blockDim.x + t; i < B; i += gridDim.x * blockDim.x)
    atomicAdd(&lh[nnp[i] - 1], 1);
  __syncthreads();
  if (t < NBIN && lh[t] > 0) atomicAdd(&g_hist[t], lh[t]);
  __threadfence();
  if (t == 0) lastdone = (atomicAdd(&g_done, 1) == (int)gridDim.x - 1);
  __syncthreads();
  if (t == 0 && lastdone) {
    int acc = 0;
    for (int i = NBIN - 1; i >= 0; i--) { g_off[i] = acc; acc += g_hist[i]; }
  }
}

__global__ void __launch_bounds__(256)
nn_scatter(const int* __restrict__ nnp, int B)
{
  __shared__ int lc[NBIN], lbase[NBIN];
  const int t = threadIdx.x;
  const int i = blockIdx.x * 256 + t;
  if (t < NBIN) lc[t] = 0;
  __syncthreads();
  int bin = 0, r = 0;
  const bool ok = (i < B);
  if (ok) { bin = nnp[i] - 1; r = atomicAdd(&lc[bin], 1); }
  __syncthreads();
  if (t < NBIN) lbase[t] = (lc[t] > 0) ? atomicAdd(&g_off[t], lc[t]) : 0;
  __syncthreads();
  if (ok) g_perm[lbase[bin] + r] = i;
}

__device__ __forceinline__ void pack8(FU& f, const float* v) {
  f.u[0] = pk2(v[0], v[1]); f.u[1] = pk2(v[2], v[3]);
  f.u[2] = pk2(v[4], v[5]); f.u[3] = pk2(v[6], v[7]);
}

// ---------------- MP stage: interleaved nodes n = wv + 4t, skip t >= nact --------
// Weights re-loaded per node (L1/L2-hot) to keep register live ranges short.
__device__ __forceinline__ void mp_stage(
    FU hA[][2], const FU* msgf,
    int w1off, int w2off, int b1o, int b2o, int lgo, int lbo,
    int nnv, int wv, int nact, int lane, int q)
{
  if (nact == 0) return;
  const f32x4 zf4 = {0.f, 0.f, 0.f, 0.f};
  f32x4 tmsg[4];
  #pragma unroll
  for (int mb = 0; mb < 4; mb++) {
    tmsg[mb] = MFMA(LDF(w1off + (mb * 4 + 2) * 512), msgf[0].h, zf4);
    tmsg[mb] = MFMA(LDF(w1off + (mb * 4 + 3) * 512), msgf[1].h, tmsg[mb]);
  }
  {
    // hoist b1 bias: added once per wave instead of once per node
    FU b1p0, b1p1; b1p0.h = LDB(b1o, 0); b1p1.h = LDB(b1o, 1);
    #pragma unroll
    for (int mb = 0; mb < 4; mb++)
      #pragma unroll
      for (int i = 0; i < 4; i++)
        tmsg[mb][i] += bf2f(((mb >> 1) ? b1p1 : b1p0).h[(mb & 1) * 4 + i]);
  }

  #pragma unroll
  for (int t = 0; t < 5; t++) {
    if (t < nact) {
      int tz = 0;
      asm volatile("" : "+v"(tz));
      const short* gA = g_fr + lane * 8 + tz;
      const short* gB = g_fr + q * 8 + tz;
      const int n = wv + 4 * t;
      f32x4 T[4];
      #pragma unroll
      for (int mb = 0; mb < 4; mb++) {
        T[mb] = MFMA(GAF(w1off + (mb * 4 + 0) * 512), hA[t][0].h, tmsg[mb]);
        T[mb] = MFMA(GAF(w1off + (mb * 4 + 1) * 512), hA[t][1].h, T[mb]);
      }
      FU tb[2];
      #pragma unroll
      for (int c = 0; c < 2; c++)
        #pragma unroll
        for (int w = 0; w < 4; w++) {
          int mb = 2 * c + (w >> 1), i0 = (w & 1) * 2;
          float lo = fmaxf(T[mb][i0],     0.f);
          float hi = fmaxf(T[mb][i0 + 1], 0.f);
          tb[c].u[w] = pk2(lo, hi);
        }
      f32x4 H[4];
      #pragma unroll
      for (int mb = 0; mb < 4; mb++) {
        H[mb] = MFMA(GAF(w2off + (mb * 2 + 0) * 512), tb[0].h, zf4);
        H[mb] = MFMA(GAF(w2off + (mb * 2 + 1) * 512), tb[1].h, H[mb]);
      }
      FU b2p0, b2p1;
      b2p0.h = GBF(b2o, 0); b2p1.h = GBF(b2o, 1);
      float y[16]; float s = 0.f, ss = 0.f;
      #pragma unroll
      for (int k = 0; k < 16; k++) {
        int c = k >> 3, j = k & 7;
        float v = H[2 * c + (j >> 2)][j & 3] + bf2f((c ? b2p1 : b2p0).h[j]) +
                  bf2f(hA[t][c].h[j]);
        y[k] = v; s += v; ss += v * v;
      }
      s += __shfl_xor(s, 16, 64); ss += __shfl_xor(ss, 16, 64);
      s += __shfl_xor(s, 32, 64); ss += __shfl_xor(ss, 32, 64);
      float mu = s * 0.015625f;
      float rstd = rsqrtf(ss * 0.015625f - mu * mu + 1e-5f);
      float mfv = (n < nnv) ? 1.f : 0.f;
      FU lgp0, lgp1, lbp0, lbp1;
      lgp0.h = GBF(lgo, 0); lgp1.h = GBF(lgo, 1);
      lbp0.h = GBF(lbo, 0); lbp1.h = GBF(lbo, 1);
      #pragma unroll
      for (int k = 0; k < 16; k++) {
        int c = k >> 3, j = k & 7;
        float hv = ((y[k] - mu) * rstd * bf2f((c ? lgp1 : lgp0).h[j]) +
                    bf2f((c ? lbp1 : lbp0).h[j])) * mfv;
        y[k] = hv;
      }
      pack8(hA[t][0], y); pack8(hA[t][1], y + 8);
    }
  }
}

// ---------------- main: 16 sorted batch / block, interleaved node ownership ------
__global__ void __launch_bounds__(256)
msp(const float* __restrict__ nf, const int* __restrict__ nnp,
    const float* __restrict__ rnn, const float* __restrict__ poh,
    const float* __restrict__ opb, const float* __restrict__ c1b,
    const float* __restrict__ c2b, const float* __restrict__ pqb,
    const float* __restrict__ pkb,
    float* __restrict__ out, int B)
{
  __shared__ __align__(16) float exch[2][4][64][17];   // 34816 B
  __shared__ __align__(16) unsigned nsx[64][8];        // 2048 B

  const int tid = threadIdx.x;
  const int wv = tid >> 6;
  const int lane = tid & 63;
  const int l15 = lane & 15, q = lane >> 4;
  const int b0 = blockIdx.x * 16;
  const int bb = g_perm[b0 + l15];

  const int nnv = nnp[bb];
  const float inv = 1.0f / (float)nnv;
  const f32x4 zf4 = {0.f, 0.f, 0.f, 0.f};

  // block-max nnv (same 16 samples for all waves): reduce within 16-lane groups
  int M = nnv;
  { int o;
    o = __shfl_xor(M, 1, 64); M = M > o ? M : o;
    o = __shfl_xor(M, 2, 64); M = M > o ? M : o;
    o = __shfl_xor(M, 4, 64); M = M > o ? M : o;
    o = __shfl_xor(M, 8, 64); M = M > o ? M : o; }
  // this wave owns nodes n = wv + 4t, t in [0, nact)
  int nact = (M - wv + 3) >> 2;
  nact = nact < 0 ? 0 : (nact > 5 ? 5 : nact);

  FU hA[5][2];

  // ================= E: h0^T = ne_w' · x^T (bias via k=16 pad column) ==========
  // h0 is masked AT SOURCE (hv *= mfv): all later exchanges are plain sums.
  {
    // load-phase: issue all node-feature loads before any consumer (one latency
    // exposure instead of five)
    float4 xa[5][2];
    #pragma unroll
    for (int t = 0; t < 5; t++) {
      if (t < nact && q < 2) {
        const float* p = nf + ((size_t)bb * NM + (wv + 4 * t)) * 16 + q * 8;
        xa[t][0] = *(const float4*)p;
        xa[t][1] = *(const float4*)(p + 4);
      }
    }
    #pragma unroll
    for (int t = 0; t < 5; t++) {
      if (t < nact) {
        int tz = 0;
        asm volatile("" : "+v"(tz));
        const short* gA = g_fr + lane * 8 + tz;
        const int n = wv + 4 * t;
        FU bx;
        bx.u[0] = 0; bx.u[1] = 0; bx.u[2] = 0; bx.u[3] = 0;
        if (q < 2) {
          bx.u[0] = pk2(xa[t][0].x, xa[t][0].y); bx.u[1] = pk2(xa[t][0].z, xa[t][0].w);
          bx.u[2] = pk2(xa[t][1].x, xa[t][1].y); bx.u[3] = pk2(xa[t][1].z, xa[t][1].w);
        } else if (q == 2) {
          bx.u[0] = pk2(1.f, 0.f);   // k=16 constant-1 -> ne_b column
        }
        f32x4 C[4];
        #pragma unroll
        for (int mb = 0; mb < 4; mb++) C[mb] = MFMA(GAF(F_NE + mb * 512), bx.h, zf4);
        const float mfv = (n < nnv) ? 1.f : 0.f;
        float hv[16];
        #pragma unroll
        for (int k = 0; k < 16; k++) {
          int c = k >> 3, j = k & 7;
          hv[k] = C[2 * c + (j >> 2)][j & 3] * mfv;
        }
        pack8(hA[t][0], hv); pack8(hA[t][1], hv + 8);
      }
    }
    // zero only the never-written slots (after E, to avoid long zero live-ranges)
    #pragma unroll
    for (int t = 0; t < 5; t++) {
      if (t >= nact) {
        #pragma unroll
        for (int c = 0; c < 2; c++) {
          hA[t][c].u[0] = 0; hA[t][c].u[1] = 0;
          hA[t][c].u[2] = 0; hA[t][c].u[3] = 0;
        }
      }
    }
  }

  FU msgf[2];
  // per-wave node-sum recomputed from hA (all values pre-masked -> plain sum)
  #define EXCHANGE(REG)                                                        \
    {                                                                          \
      _Pragma("unroll")                                                        \
      for (int k = 0; k < 16; k++) {                                           \
        int c = k >> 3, j = k & 7;                                             \
        float sK = bf2f(hA[0][c].h[j]) + bf2f(hA[1][c].h[j]) +                 \
                   bf2f(hA[2][c].h[j]) + bf2f(hA[3][c].h[j]) +                 \
                   bf2f(hA[4][c].h[j]);                                        \
        exch[REG][wv][lane][k] = sK;                                           \
      }                                                                        \
      __syncthreads();                                                         \
      _Pragma("unroll")                                                        \
      for (int w8 = 0; w8 < 8; w8++) {                                         \
        int k0 = 2 * w8, k1 = k0 + 1;                                          \
        float a = (exch[REG][0][lane][k0] + exch[REG][1][lane][k0] +           \
                   exch[REG][2][lane][k0] + exch[REG][3][lane][k0]) * inv;     \
        float b = (exch[REG][0][lane][k1] + exch[REG][1][lane][k1] +           \
                   exch[REG][2][lane][k1] + exch[REG][3][lane][k1]) * inv;     \
        FU* dp = (w8 < 4) ? &msgf[0] : &msgf[1];                               \
        dp->u[w8 & 3] = pk2(a, b);                                             \
      }                                                                        \
    }

  EXCHANGE(0)   // msg1
  mp_stage(hA, msgf, F_M1W1, F_M1W2, F_B11, F_B12, F_G1, F_L1, nnv, wv, nact, lane, q);

  EXCHANGE(1)   // msg2
  mp_stage(hA, msgf, F_M2W1, F_M2W2, F_B21, F_B22, F_G2, F_L2, nnv, wv, nact, lane, q);

  EXCHANGE(0)   // graph_vec -> msgf (region 0 safe: all reads done pre-stage2 barrier)

  // ================= GRU: wave wv owns gate tile tt = wv; gx == msgf ==========
  {
    FU px;
    if (q == 0) {
      const float* pp = poh + (size_t)bb * 8;
      float4 p0 = *(const float4*)pp, p1 = *(const float4*)(pp + 4);
      px.u[0] = pk2(p0.x, p0.y); px.u[1] = pk2(p0.z, p0.w);
      px.u[2] = pk2(p1.x, p1.y); px.u[3] = pk2(p1.z, p1.w);
    } else { px.u[0] = 0; px.u[1] = 0; px.u[2] = 0; px.u[3] = 0; }
    const float* rr0 = rnn + (size_t)bb * 64;
    float rv[16];
    #pragma unroll
    for (int c = 0; c < 2; c++) {
      float4 a0 = *(const float4*)(rr0 + c * 32 + q * 8);
      float4 a1 = *(const float4*)(rr0 + c * 32 + q * 8 + 4);
      rv[c * 8 + 0] = a0.x; rv[c * 8 + 1] = a0.y; rv[c * 8 + 2] = a0.z; rv[c * 8 + 3] = a0.w;
      rv[c * 8 + 4] = a1.x; rv[c * 8 + 5] = a1.y; rv[c * 8 + 6] = a1.z; rv[c * 8 + 7] = a1.w;
    }
    FU ah[2]; pack8(ah[0], rv); pack8(ah[1], rv + 8);

    const int tt = wv;
    f32x4 R = MFMA(LDF(F_WIH + (tt * 3 + 0) * 512), msgf[0].h, zf4);
    R = MFMA(LDF(F_WIH + (tt * 3 + 1) * 512), msgf[1].h, R);
    R = MFMA(LDF(F_WIH + (tt * 3 + 2) * 512), px.h, R);
    R = MFMA(LDF(F_WHH + (tt * 2 + 0) * 512), ah[0].h, R);
    R = MFMA(LDF(F_WHH + (tt * 2 + 1) * 512), ah[1].h, R);
    f32x4 Z = MFMA(LDF(F_WIH + ((4 + tt) * 3 + 0) * 512), msgf[0].h, zf4);
    Z = MFMA(LDF(F_WIH + ((4 + tt) * 3 + 1) * 512), msgf[1].h, Z);
    Z = MFMA(LDF(F_WIH + ((4 + tt) * 3 + 2) * 512), px.h, Z);
    Z = MFMA(LDF(F_WHH + ((4 + tt) * 2 + 0) * 512), ah[0].h, Z);
    Z = MFMA(LDF(F_WHH + ((4 + tt) * 2 + 1) * 512), ah[1].h, Z);
    f32x4 Ni = MFMA(LDF(F_WIH + ((8 + tt) * 3 + 0) * 512), msgf[0].h, zf4);
    Ni = MFMA(LDF(F_WIH + ((8 + tt) * 3 + 1) * 512), msgf[1].h, Ni);
    Ni = MFMA(LDF(F_WIH + ((8 + tt) * 3 + 2) * 512), px.h, Ni);
    f32x4 Nh = MFMA(LDF(F_WHH + ((8 + tt) * 2 + 0) * 512), ah[0].h, zf4);
    Nh = MFMA(LDF(F_WHH + ((8 + tt) * 2 + 1) * 512), ah[1].h, Nh);

    const int dbase = q * 8 + (tt >> 1) * 32 + (tt & 1) * 4;
    f32x4 brv = *(const f32x4*)&g_grb[0][dbase];
    f32x4 bzv = *(const f32x4*)&g_grb[1][dbase];
    f32x4 bnv = *(const f32x4*)&g_grb[2][dbase];
    f32x4 bhv = *(const f32x4*)&g_grb[3][dbase];
    float nsv[4];
    #pragma unroll
    for (int i = 0; i < 4; i++) {
      const int K = (tt >> 1) * 32 + (tt & 1) * 4 + i;
      const int d = q * 8 + K;
      float rr = fsig(R[i] + brv[i]);
      float zz = fsig(Z[i] + bzv[i]);
      float ng = ftanh(Ni[i] + bnv[i] + rr * (Nh[i] + bhv[i]));
      float st = rv[(tt >> 1) * 8 + (tt & 1) * 4 + i];
      float v = (1.f - zz) * ng + zz * st;
      out[(size_t)B * 48 + (size_t)bb * 64 + d] = v;
      nsv[i] = v;
    }
    // ns quarter -> LDS: dwords (tt>>1)*4 + (tt&1)*2 + {0,1}
    const int dw = (tt >> 1) * 4 + (tt & 1) * 2;
    nsx[lane][dw]     = pk2(nsv[0], nsv[1]);
    nsx[lane][dw + 1] = pk2(nsv[2], nsv[3]);
  }
  __syncthreads();

  // ================= heads + pointer =================
  {
    FU an0, an1;
    an0.u = *(const u32x4*)&nsx[lane][0];
    an1.u = *(const u32x4*)&nsx[lane][4];
    float qv[16];
    #pragma unroll
    for (int mb = 0; mb < 4; mb++) {
      f32x4 Qc = MFMA(LDF(F_PQ + (mb * 2 + 0) * 512), an0.h, zf4);
      Qc = MFMA(LDF(F_PQ + (mb * 2 + 1) * 512), an1.h, Qc);
      f32x4 pq4 = *(const f32x4*)&pqb[mb * 16 + q * 4];
      #pragma unroll
      for (int i = 0; i < 4; i++) qv[mb * 4 + i] = Qc[i] + pq4[i];
    }
    float qb = 0.f;
    #pragma unroll
    for (int mb = 0; mb < 4; mb++) {
      f32x4 pk4 = *(const f32x4*)&pkb[mb * 16 + q * 4];
      #pragma unroll
      for (int i = 0; i < 4; i++) qb += qv[mb * 4 + i] * pk4[i];
    }
    qb += __shfl_xor(qb, 16, 64); qb += __shfl_xor(qb, 32, 64);

    if (wv < 2) {   // op/c1/c2 packed head: wave wv does mb2 = wv
      f32x4 L = MFMA(LDF(F_PACK + (wv * 2 + 0) * 512), an0.h, zf4);
      L = MFMA(LDF(F_PACK + (wv * 2 + 1) * 512), an1.h, L);
      #pragma unroll
      for (int i = 0; i < 4; i++) {
        int o = wv * 16 + q * 4 + i;
        if (o < 8)       out[(size_t)bb * 8 + o] = L[i] + opb[o];
        else if (o < 18) out[(size_t)B * 8 + (size_t)bb * 10 + (o - 8)] = L[i] + c1b[o - 8];
        else if (o < 28) out[(size_t)B * 18 + (size_t)bb * 10 + (o - 18)] = L[i] + c2b[o - 18];
      }
    }
    #pragma unroll
    for (int t = 0; t < 5; t++) {
      const int n = wv + 4 * t;
      if (t < nact) {
        int tz = 0;
        asm volatile("" : "+v"(tz));
        const short* gA = g_fr + lane * 8 + tz;
        float dt = 0.f;
        #pragma unroll
        for (int mb = 0; mb < 4; mb++) {
          f32x4 Kc = MFMA(GAF(F_PK + (mb * 2 + 0) * 512), hA[t][0].h, zf4);
          Kc = MFMA(GAF(F_PK + (mb * 2 + 1) * 512), hA[t][1].h, Kc);
          #pragma unroll
          for (int i = 0; i < 4; i++) dt += qv[mb * 4 + i] * Kc[i];
        }
        dt += __shfl_xor(dt, 16, 64); dt += __shfl_xor(dt, 32, 64);
        if (q == 0)
          out[(size_t)B * 28 + (size_t)bb * 20 + n] = (n < nnv) ? (dt + qb) : -1e9f;
      } else {
        if (q == 0)
          out[(size_t)B * 28 + (size_t)bb * 20 + n] = -1e9f;   // n >= M >= nnv
      }
    }
  }
}

extern "C" void kernel_launch(void* const* d_in, const int* in_sizes, int n_in,
                              void* d_out, int out_size, void* d_ws, size_t ws_size,
                              hipStream_t stream)
{
  (void)n_in; (void)out_size; (void)d_ws; (void)ws_size;
  const float* nf   = (const float*)d_in[0];
  const int*   nnp  = (const int*)  d_in[1];
  const float* rnn  = (const float*)d_in[2];
  const float* poh  = (const float*)d_in[3];
  const float* ne_w = (const float*)d_in[4];
  const float* ne_b = (const float*)d_in[5];
  const float* m1w1 = (const float*)d_in[6];
  const float* m1b1 = (const float*)d_in[7];
  const float* m1w2 = (const float*)d_in[8];
  const float* m1b2 = (const float*)d_in[9];
  const float* n1g  = (const float*)d_in[10];
  const float* n1b  = (const float*)d_in[11];
  const float* m2w1 = (const float*)d_in[12];
  const float* m2b1 = (const float*)d_in[13];
  const float* m2w2 = (const float*)d_in[14];
  const float* m2b2 = (const float*)d_in[15];
  const float* n2g  = (const float*)d_in[16];
  const float* n2b  = (const float*)d_in[17];
  const float* wih  = (const float*)d_in[18];
  const float* whh  = (const float*)d_in[19];
  const float* bih  = (const float*)d_in[20];
  const float* bhh  = (const float*)d_in[21];
  const float* opw  = (const float*)d_in[22];
  const float* opb  = (const float*)d_in[23];
  const float* c1w  = (const float*)d_in[24];
  const float* c1b  = (const float*)d_in[25];
  const float* c2w  = (const float*)d_in[26];
  const float* c2b  = (const float*)d_in[27];
  const float* pqw  = (const float*)d_in[28];
  const float* pqb  = (const float*)d_in[29];
  const float* pkw  = (const float*)d_in[30];
  const float* pkb  = (const float*)d_in[31];
  float* out = (float*)d_out;
  const int B = in_sizes[1];

  prep_frag<<<132, 256, 0, stream>>>(ne_w, m1w1, m1w2, m2w1, m2w2,
                                     wih, whh, pqw, opw, c1w, c2w, pkw,
                                     ne_b, m1b1, m1b2, n1g, n1b,
                                     m2b1, m2b2, n2g, n2b, bih, bhh);
  nn_hist<<<256, 256, 0, stream>>>(nnp, B);
  nn_scatter<<<(B + 255) / 256, 256, 0, stream>>>(nnp, B);
  msp<<<B / 16, 256, 0, stream>>>(nf, nnp, rnn, poh,
                                  opb, c1b, c2b,
                                  pqb, pkb, out, B);
}

// Round 5
// 390.438 us; speedup vs baseline: 1.8321x; 1.0292x over previous
//
#include <hip/hip_runtime.h>
#include <hip/hip_bf16.h>
#include <cstdint>

#define NM 20
#define NBIN 20
#define MAXB 65536

typedef __attribute__((ext_vector_type(8))) short bf16x8;
typedef __attribute__((ext_vector_type(4))) float f32x4;
typedef __attribute__((ext_vector_type(4))) unsigned int u32x4;

union FU { bf16x8 h; u32x4 u; };

#define MFMA(A, Bf, C) __builtin_amdgcn_mfma_f32_16x16x32_bf16((A), (Bf), (C), 0, 0, 0)

// A-fragment-packed, ROW-PERMUTED weights (bf16), built by prep each launch.
#define F_NE    0        // 4 frags  (4mb x 1kc, K=16 pad 32; col 16 = ne_b)
#define F_M1W1  2048     // 16       (4mb x 4kc, K=128)
#define F_M1W2  10240    // 8        (4mb x 2kc)
#define F_M2W1  14336    // 16
#define F_M2W2  22528    // 8
#define F_WIH   26624    // 36       (12mb x 3kc, K=72 pad 96)
#define F_WHH   45056    // 24       (12mb x 2kc)
#define F_PQ    57344    // 8        (identity rows)
#define F_PK    61440    // 8        (identity rows)
#define F_PACK  65536    // 4        (2mb x 2kc, rows = op|c1|c2 pad 32)
// bf16-packed bias/LN vectors (natural feature order, 64 each)
#define F_BNE   67584
#define F_B11   67648
#define F_B12   67712
#define F_G1    67776
#define F_L1    67840
#define F_B21   67904
#define F_B22   67968
#define F_G2    68032
#define F_L2    68096
#define F_TOTAL 68160

__device__ __align__(16) short g_fr[F_TOTAL];
// GRU gate biases, f32, float4-loadable: [0]=bih+bhh (r), [1]=bih+bhh (z),
// [2]=bih (n), [3]=bhh (n)
__device__ __align__(16) float g_grb[4][64];
__device__ int g_hist[NBIN];   // invariant: zero at kernel entry (reset by last block)
__device__ int g_off[NBIN];
__device__ int g_done;         // invariant: zero at kernel entry
__device__ int g_perm[MAXB];

__device__ __forceinline__ short bf16rn(float x) {
  unsigned u = __float_as_uint(x);
  u += 0x7fffu + ((u >> 16) & 1u);
  return (short)(u >> 16);
}
__device__ __forceinline__ float bf2f(short s) {
  return __uint_as_float(((unsigned)(unsigned short)s) << 16);
}
__device__ __forceinline__ unsigned pk2(float lo, float hi) {
  __hip_bfloat162 t = __float22bfloat162_rn(float2{lo, hi});
  return *reinterpret_cast<unsigned*>(&t);
}
// fast GRU activations: v_exp_f32 + v_rcp_f32 (err ~1e-6, well within tolerance)
__device__ __forceinline__ float fsig(float x) {
  return __builtin_amdgcn_rcpf(1.f + __expf(-x));
}
__device__ __forceinline__ float ftanh(float x) {
  return 1.f - 2.f * __builtin_amdgcn_rcpf(1.f + __expf(2.f * x));
}
// slot permutation: C row r (=mb*16+qq*4+i) lands at slot s64(r); permuting weight
// rows by s64 makes the C-output the B-fragment of the next GEMM, register-locally.
__device__ __forceinline__ int s64(int r) {
  int mb = r >> 4, qq = (r >> 2) & 3, i = r & 3;
  return (mb >> 1) * 32 + qq * 8 + (mb & 1) * 4 + i;
}

#define LDF(off) (*(const bf16x8*)(g_fr + (off) + lane * 8))
#define LDB(off, c) (*(const bf16x8*)(g_fr + (off) + (c) * 32 + q * 8))
// node-local bases (gA/gB include an opaque 0 so loads can't be hoisted/LICM'd)
#define GAF(off) (*(const bf16x8*)(gA + (off)))
#define GBF(off, c) (*(const bf16x8*)(gB + (off) + (c) * 32))

// ---------------- prep (+ n_nodes histogram + DESCENDING scan, ticketed) --------
#define BUILDA(OFS, MB, KC, ROWX, GET)                                 \
  for (int idx = t; idx < (MB) * (KC) * 512; idx += T) {               \
    int j = idx & 7, ln = (idx >> 3) & 63, f = idx >> 9;               \
    int mb = f / (KC), kc = f % (KC);                                  \
    int m = mb * 16 + (ln & 15);                                       \
    int k = kc * 32 + (ln >> 4) * 8 + j;                               \
    int row = (ROWX);                                                  \
    (void)row; (void)k; (void)m;                                       \
    g_fr[(OFS) + idx] = bf16rn(GET);                                   \
  }

__global__ void __launch_bounds__(256)
prep_frag(const float* __restrict__ ne_w,
          const float* __restrict__ m1w1, const float* __restrict__ m1w2,
          const float* __restrict__ m2w1, const float* __restrict__ m2w2,
          const float* __restrict__ wih,  const float* __restrict__ whh,
          const float* __restrict__ pqw,  const float* __restrict__ opw,
          const float* __restrict__ c1w,  const float* __restrict__ c2w,
          const float* __restrict__ pkw,
          const float* __restrict__ ne_b,
          const float* __restrict__ m1b1, const float* __restrict__ m1b2,
          const float* __restrict__ n1g,  const float* __restrict__ n1b,
          const float* __restrict__ m2b1, const float* __restrict__ m2b2,
          const float* __restrict__ n2g,  const float* __restrict__ n2b,
          const float* __restrict__ bih,  const float* __restrict__ bhh,
          const int* __restrict__ nnp, int B)
{
  const int t = blockIdx.x * blockDim.x + threadIdx.x;
  const int T = gridDim.x * blockDim.x;
  // ne_b folded into K-pad column 16 (B supplies constant 1.0 at k=16)
  BUILDA(F_NE,   4, 1, s64(m), (k < 16 ? ne_w[row * 16 + k] : (k == 16 ? ne_b[row] : 0.f)))
  BUILDA(F_M1W1, 4, 4, s64(m), m1w1[row * 128 + k])
  BUILDA(F_M1W2, 4, 2, s64(m), m1w2[row * 64 + k])
  BUILDA(F_M2W1, 4, 4, s64(m), m2w1[row * 128 + k])
  BUILDA(F_M2W2, 4, 2, s64(m), m2w2[row * 64 + k])
  BUILDA(F_WIH, 12, 3, (m & 0xC0) | s64(m & 63), (k < 72 ? wih[row * 72 + k] : 0.f))
  BUILDA(F_WHH, 12, 2, (m & 0xC0) | s64(m & 63), whh[row * 64 + k])
  BUILDA(F_PQ,   4, 2, m, pqw[row * 64 + k])
  BUILDA(F_PK,   4, 2, m, pkw[row * 64 + k])
  BUILDA(F_PACK, 2, 2, m, (row < 8 ? opw[row * 64 + k]
                           : row < 18 ? c1w[(row - 8) * 64 + k]
                           : row < 28 ? c2w[(row - 18) * 64 + k] : 0.f))
  for (int i = t; i < 64; i += T) {
    g_fr[F_BNE + i] = bf16rn(ne_b[i]);
    g_fr[F_B11 + i] = bf16rn(m1b1[i]);
    g_fr[F_B12 + i] = bf16rn(m1b2[i]);
    g_fr[F_G1  + i] = bf16rn(n1g[i]);
    g_fr[F_L1  + i] = bf16rn(n1b[i]);
    g_fr[F_B21 + i] = bf16rn(m2b1[i]);
    g_fr[F_B22 + i] = bf16rn(m2b2[i]);
    g_fr[F_G2  + i] = bf16rn(n2g[i]);
    g_fr[F_L2  + i] = bf16rn(n2b[i]);
    g_grb[0][i] = bih[i]       + bhh[i];
    g_grb[1][i] = bih[64 + i]  + bhh[64 + i];
    g_grb[2][i] = bih[128 + i];
    g_grb[3][i] = bhh[128 + i];
  }

  // ---- histogram of n_nodes (g_hist zero at entry) ----
  __shared__ int lh[NBIN];
  __shared__ int lastdone;
  const int lt = threadIdx.x;
  if (lt < NBIN) lh[lt] = 0;
  __syncthreads();
  for (int i = t; i < B; i += T) atomicAdd(&lh[nnp[i] - 1], 1);
  __syncthreads();
  if (lt < NBIN && lh[lt] > 0) atomicAdd(&g_hist[lt], lh[lt]);
  __threadfence();
  if (lt == 0) lastdone = (atomicAdd(&g_done, 1) == (int)gridDim.x - 1);
  __syncthreads();
  // last block: DESCENDING scan (LPT: heavy blocks dispatch first), then restore
  // the zero-invariant for the next launch/replay.
  if (lastdone && lt == 0) {
    __threadfence();
    int acc = 0;
    for (int i = NBIN - 1; i >= 0; i--) {
      g_off[i] = acc; acc += g_hist[i]; g_hist[i] = 0;
    }
    g_done = 0;
  }
}

__global__ void __launch_bounds__(256)
nn_scatter(const int* __restrict__ nnp, int B)
{
  __shared__ int lc[NBIN], lbase[NBIN];
  const int t = threadIdx.x;
  const int i = blockIdx.x * 256 + t;
  if (t < NBIN) lc[t] = 0;
  __syncthreads();
  int bin = 0, r = 0;
  const bool ok = (i < B);
  if (ok) { bin = nnp[i] - 1; r = atomicAdd(&lc[bin], 1); }
  __syncthreads();
  if (t < NBIN) lbase[t] = (lc[t] > 0) ? atomicAdd(&g_off[t], lc[t]) : 0;
  __syncthreads();
  if (ok) g_perm[lbase[bin] + r] = i;
}

__device__ __forceinline__ void pack8(FU& f, const float* v) {
  f.u[0] = pk2(v[0], v[1]); f.u[1] = pk2(v[2], v[3]);
  f.u[2] = pk2(v[4], v[5]); f.u[3] = pk2(v[6], v[7]);
}

// ---------------- MP stage: interleaved nodes n = wv + 4t, skip t >= nact --------
// Weights re-loaded per node (L1/L2-hot) to keep register live ranges short.
// macc accumulates the masked node-sum for the next exchange (values pre-masked).
__device__ __forceinline__ void mp_stage(
    FU hA[][2], float* macc, const FU* msgf,
    int w1off, int w2off, int b1o, int b2o, int lgo, int lbo,
    int nnv, int wv, int nact, int lane, int q)
{
  if (nact == 0) return;
  const f32x4 zf4 = {0.f, 0.f, 0.f, 0.f};
  f32x4 tmsg[4];
  #pragma unroll
  for (int mb = 0; mb < 4; mb++) {
    tmsg[mb] = MFMA(LDF(w1off + (mb * 4 + 2) * 512), msgf[0].h, zf4);
    tmsg[mb] = MFMA(LDF(w1off + (mb * 4 + 3) * 512), msgf[1].h, tmsg[mb]);
  }
  {
    // hoist b1 bias: added once per wave instead of once per node
    FU b1p0, b1p1; b1p0.h = LDB(b1o, 0); b1p1.h = LDB(b1o, 1);
    #pragma unroll
    for (int mb = 0; mb < 4; mb++)
      #pragma unroll
      for (int i = 0; i < 4; i++)
        tmsg[mb][i] += bf2f(((mb >> 1) ? b1p1 : b1p0).h[(mb & 1) * 4 + i]);
  }

  #pragma unroll
  for (int t = 0; t < 5; t++) {
    if (t < nact) {
      int tz = 0;
      asm volatile("" : "+v"(tz));
      const short* gA = g_fr + lane * 8 + tz;
      const short* gB = g_fr + q * 8 + tz;
      const int n = wv + 4 * t;
      f32x4 T[4];
      #pragma unroll
      for (int mb = 0; mb < 4; mb++) {
        T[mb] = MFMA(GAF(w1off + (mb * 4 + 0) * 512), hA[t][0].h, tmsg[mb]);
        T[mb] = MFMA(GAF(w1off + (mb * 4 + 1) * 512), hA[t][1].h, T[mb]);
      }
      FU tb[2];
      #pragma unroll
      for (int c = 0; c < 2; c++)
        #pragma unroll
        for (int w = 0; w < 4; w++) {
          int mb = 2 * c + (w >> 1), i0 = (w & 1) * 2;
          float lo = fmaxf(T[mb][i0],     0.f);
          float hi = fmaxf(T[mb][i0 + 1], 0.f);
          tb[c].u[w] = pk2(lo, hi);
        }
      f32x4 H[4];
      #pragma unroll
      for (int mb = 0; mb < 4; mb++) {
        H[mb] = MFMA(GAF(w2off + (mb * 2 + 0) * 512), tb[0].h, zf4);
        H[mb] = MFMA(GAF(w2off + (mb * 2 + 1) * 512), tb[1].h, H[mb]);
      }
      FU b2p0, b2p1;
      b2p0.h = GBF(b2o, 0); b2p1.h = GBF(b2o, 1);
      float y[16]; float s = 0.f, ss = 0.f;
      #pragma unroll
      for (int k = 0; k < 16; k++) {
        int c = k >> 3, j = k & 7;
        float v = H[2 * c + (j >> 2)][j & 3] + bf2f((c ? b2p1 : b2p0).h[j]) +
                  bf2f(hA[t][c].h[j]);
        y[k] = v; s += v; ss += v * v;
      }
      s += __shfl_xor(s, 16, 64); ss += __shfl_xor(ss, 16, 64);
      s += __shfl_xor(s, 32, 64); ss += __shfl_xor(ss, 32, 64);
      float mu = s * 0.015625f;
      float rstd = rsqrtf(ss * 0.015625f - mu * mu + 1e-5f);
      float mfv = (n < nnv) ? 1.f : 0.f;
      FU lgp0, lgp1, lbp0, lbp1;
      lgp0.h = GBF(lgo, 0); lgp1.h = GBF(lgo, 1);
      lbp0.h = GBF(lbo, 0); lbp1.h = GBF(lbo, 1);
      #pragma unroll
      for (int k = 0; k < 16; k++) {
        int c = k >> 3, j = k & 7;
        float hv = ((y[k] - mu) * rstd * bf2f((c ? lgp1 : lgp0).h[j]) +
                    bf2f((c ? lbp1 : lbp0).h[j])) * mfv;
        macc[k] += hv; y[k] = hv;
      }
      pack8(hA[t][0], y); pack8(hA[t][1], y + 8);
    }
  }
}

// ---------------- main: 16 sorted batch / block, interleaved node ownership ------
__global__ void __launch_bounds__(256)
msp(const float* __restrict__ nf, const int* __restrict__ nnp,
    const float* __restrict__ rnn, const float* __restrict__ poh,
    const float* __restrict__ opb, const float* __restrict__ c1b,
    const float* __restrict__ c2b, const float* __restrict__ pqb,
    const float* __restrict__ pkb,
    float* __restrict__ out, int B)
{
  __shared__ __align__(16) float exch[2][4][64][17];   // 34816 B
  __shared__ __align__(16) unsigned nsx[64][8];        // 2048 B

  const int tid = threadIdx.x;
  const int wv = tid >> 6;
  const int lane = tid & 63;
  const int l15 = lane & 15, q = lane >> 4;
  const int b0 = blockIdx.x * 16;
  const int bb = g_perm[b0 + l15];

  const int nnv = nnp[bb];
  const float inv = 1.0f / (float)nnv;
  const f32x4 zf4 = {0.f, 0.f, 0.f, 0.f};

  // block-max nnv (same 16 samples for all waves): reduce within 16-lane groups
  int M = nnv;
  { int o;
    o = __shfl_xor(M, 1, 64); M = M > o ? M : o;
    o = __shfl_xor(M, 2, 64); M = M > o ? M : o;
    o = __shfl_xor(M, 4, 64); M = M > o ? M : o;
    o = __shfl_xor(M, 8, 64); M = M > o ? M : o; }
  // this wave owns nodes n = wv + 4t, t in [0, nact)
  int nact = (M - wv + 3) >> 2;
  nact = nact < 0 ? 0 : (nact > 5 ? 5 : nact);

  FU hA[5][2];
  float mac[16];
  #pragma unroll
  for (int k = 0; k < 16; k++) mac[k] = 0.f;

  // ================= E: h0^T = ne_w' · x^T (bias via k=16 pad column) ==========
  // h0 is masked AT SOURCE (hv *= mfv): exchanges are plain sums of mac.
  // xa prefetch depth 2 (ping-pong, compile-time-selected) to cap reg pressure.
  {
    float4 xaA[2], xaB[2];
    if (nact > 0 && q < 2) {
      const float* p = nf + ((size_t)bb * NM + wv) * 16 + q * 8;
      xaA[0] = *(const float4*)p; xaA[1] = *(const float4*)(p + 4);
    }
    #pragma unroll
    for (int t = 0; t < 5; t++) {
      if (t < nact) {
        float4 c0, c1;
        if ((t & 1) == 0) { c0 = xaA[0]; c1 = xaA[1]; }
        else              { c0 = xaB[0]; c1 = xaB[1]; }
        if (t + 1 < nact && q < 2) {
          const float* p = nf + ((size_t)bb * NM + (wv + 4 * (t + 1))) * 16 + q * 8;
          if ((t & 1) == 0) { xaB[0] = *(const float4*)p; xaB[1] = *(const float4*)(p + 4); }
          else              { xaA[0] = *(const float4*)p; xaA[1] = *(const float4*)(p + 4); }
        }
        int tz = 0;
        asm volatile("" : "+v"(tz));
        const short* gA = g_fr + lane * 8 + tz;
        const int n = wv + 4 * t;
        FU bx;
        bx.u[0] = 0; bx.u[1] = 0; bx.u[2] = 0; bx.u[3] = 0;
        if (q < 2) {
          bx.u[0] = pk2(c0.x, c0.y); bx.u[1] = pk2(c0.z, c0.w);
          bx.u[2] = pk2(c1.x, c1.y); bx.u[3] = pk2(c1.z, c1.w);
        } else if (q == 2) {
          bx.u[0] = pk2(1.f, 0.f);   // k=16 constant-1 -> ne_b column
        }
        f32x4 C[4];
        #pragma unroll
        for (int mb = 0; mb < 4; mb++) C[mb] = MFMA(GAF(F_NE + mb * 512), bx.h, zf4);
        const float mfv = (n < nnv) ? 1.f : 0.f;
        float hv[16];
        #pragma unroll
        for (int k = 0; k < 16; k++) {
          int c = k >> 3, j = k & 7;
          hv[k] = C[2 * c + (j >> 2)][j & 3] * mfv;
          mac[k] += hv[k];
        }
        pack8(hA[t][0], hv); pack8(hA[t][1], hv + 8);
      }
    }
  }

  FU msgf[2];
  // store per-wave masked sums, barrier, reduce 4 waves, pack bf16 msg, re-zero mac
  #define EXCHANGE(REG)                                                        \
    {                                                                          \
      _Pragma("unroll")                                                        \
      for (int k = 0; k < 16; k++) exch[REG][wv][lane][k] = mac[k];            \
      __syncthreads();                                                         \
      _Pragma("unroll")                                                        \
      for (int w8 = 0; w8 < 8; w8++) {                                         \
        int k0 = 2 * w8, k1 = k0 + 1;                                          \
        float a = (exch[REG][0][lane][k0] + exch[REG][1][lane][k0] +           \
                   exch[REG][2][lane][k0] + exch[REG][3][lane][k0]) * inv;     \
        float b = (exch[REG][0][lane][k1] + exch[REG][1][lane][k1] +           \
                   exch[REG][2][lane][k1] + exch[REG][3][lane][k1]) * inv;     \
        FU* dp = (w8 < 4) ? &msgf[0] : &msgf[1];                               \
        dp->u[w8 & 3] = pk2(a, b);                                             \
      }                                                                        \
      _Pragma("unroll")                                                        \
      for (int k = 0; k < 16; k++) mac[k] = 0.f;                               \
    }

  EXCHANGE(0)   // msg1
  mp_stage(hA, mac, msgf, F_M1W1, F_M1W2, F_B11, F_B12, F_G1, F_L1, nnv, wv, nact, lane, q);

  EXCHANGE(1)   // msg2
  mp_stage(hA, mac, msgf, F_M2W1, F_M2W2, F_B21, F_B22, F_G2, F_L2, nnv, wv, nact, lane, q);

  EXCHANGE(0)   // graph_vec -> msgf (region 0 safe: all reads done pre-stage2 barrier)

  // ================= GRU: wave wv owns gate tile tt = wv; gx == msgf ==========
  {
    FU px;
    if (q == 0) {
      const float* pp = poh + (size_t)bb * 8;
      float4 p0 = *(const float4*)pp, p1 = *(const float4*)(pp + 4);
      px.u[0] = pk2(p0.x, p0.y); px.u[1] = pk2(p0.z, p0.w);
      px.u[2] = pk2(p1.x, p1.y); px.u[3] = pk2(p1.z, p1.w);
    } else { px.u[0] = 0; px.u[1] = 0; px.u[2] = 0; px.u[3] = 0; }
    const float* rr0 = rnn + (size_t)bb * 64;
    float rv[16];
    #pragma unroll
    for (int c = 0; c < 2; c++) {
      float4 a0 = *(const float4*)(rr0 + c * 32 + q * 8);
      float4 a1 = *(const float4*)(rr0 + c * 32 + q * 8 + 4);
      rv[c * 8 + 0] = a0.x; rv[c * 8 + 1] = a0.y; rv[c * 8 + 2] = a0.z; rv[c * 8 + 3] = a0.w;
      rv[c * 8 + 4] = a1.x; rv[c * 8 + 5] = a1.y; rv[c * 8 + 6] = a1.z; rv[c * 8 + 7] = a1.w;
    }
    FU ah[2]; pack8(ah[0], rv); pack8(ah[1], rv + 8);

    const int tt = wv;
    f32x4 R = MFMA(LDF(F_WIH + (tt * 3 + 0) * 512), msgf[0].h, zf4);
    R = MFMA(LDF(F_WIH + (tt * 3 + 1) * 512), msgf[1].h, R);
    R = MFMA(LDF(F_WIH + (tt * 3 + 2) * 512), px.h, R);
    R = MFMA(LDF(F_WHH + (tt * 2 + 0) * 512), ah[0].h, R);
    R = MFMA(LDF(F_WHH + (tt * 2 + 1) * 512), ah[1].h, R);
    f32x4 Z = MFMA(LDF(F_WIH + ((4 + tt) * 3 + 0) * 512), msgf[0].h, zf4);
    Z = MFMA(LDF(F_WIH + ((4 + tt) * 3 + 1) * 512), msgf[1].h, Z);
    Z = MFMA(LDF(F_WIH + ((4 + tt) * 3 + 2) * 512), px.h, Z);
    Z = MFMA(LDF(F_WHH + ((4 + tt) * 2 + 0) * 512), ah[0].h, Z);
    Z = MFMA(LDF(F_WHH + ((4 + tt) * 2 + 1) * 512), ah[1].h, Z);
    f32x4 Ni = MFMA(LDF(F_WIH + ((8 + tt) * 3 + 0) * 512), msgf[0].h, zf4);
    Ni = MFMA(LDF(F_WIH + ((8 + tt) * 3 + 1) * 512), msgf[1].h, Ni);
    Ni = MFMA(LDF(F_WIH + ((8 + tt) * 3 + 2) * 512), px.h, Ni);
    f32x4 Nh = MFMA(LDF(F_WHH + ((8 + tt) * 2 + 0) * 512), ah[0].h, zf4);
    Nh = MFMA(LDF(F_WHH + ((8 + tt) * 2 + 1) * 512), ah[1].h, Nh);

    const int dbase = q * 8 + (tt >> 1) * 32 + (tt & 1) * 4;
    f32x4 brv = *(const f32x4*)&g_grb[0][dbase];
    f32x4 bzv = *(const f32x4*)&g_grb[1][dbase];
    f32x4 bnv = *(const f32x4*)&g_grb[2][dbase];
    f32x4 bhv = *(const f32x4*)&g_grb[3][dbase];
    float nsv[4];
    #pragma unroll
    for (int i = 0; i < 4; i++) {
      const int K = (tt >> 1) * 32 + (tt & 1) * 4 + i;
      const int d = q * 8 + K;
      float rr = fsig(R[i] + brv[i]);
      float zz = fsig(Z[i] + bzv[i]);
      float ng = ftanh(Ni[i] + bnv[i] + rr * (Nh[i] + bhv[i]));
      float st = rv[(tt >> 1) * 8 + (tt & 1) * 4 + i];
      float v = (1.f - zz) * ng + zz * st;
      out[(size_t)B * 48 + (size_t)bb * 64 + d] = v;
      nsv[i] = v;
    }
    // ns quarter -> LDS: dwords (tt>>1)*4 + (tt&1)*2 + {0,1}
    const int dw = (tt >> 1) * 4 + (tt & 1) * 2;
    nsx[lane][dw]     = pk2(nsv[0], nsv[1]);
    nsx[lane][dw + 1] = pk2(nsv[2], nsv[3]);
  }
  __syncthreads();

  // ================= heads + pointer =================
  {
    FU an0, an1;
    an0.u = *(const u32x4*)&nsx[lane][0];
    an1.u = *(const u32x4*)&nsx[lane][4];
    float qv[16];
    #pragma unroll
    for (int mb = 0; mb < 4; mb++) {
      f32x4 Qc = MFMA(LDF(F_PQ + (mb * 2 + 0) * 512), an0.h, zf4);
      Qc = MFMA(LDF(F_PQ + (mb * 2 + 1) * 512), an1.h, Qc);
      f32x4 pq4 = *(const f32x4*)&pqb[mb * 16 + q * 4];
      #pragma unroll
      for (int i = 0; i < 4; i++) qv[mb * 4 + i] = Qc[i] + pq4[i];
    }
    float qb = 0.f;
    #pragma unroll
    for (int mb = 0; mb < 4; mb++) {
      f32x4 pk4 = *(const f32x4*)&pkb[mb * 16 + q * 4];
      #pragma unroll
      for (int i = 0; i < 4; i++) qb += qv[mb * 4 + i] * pk4[i];
    }
    qb += __shfl_xor(qb, 16, 64); qb += __shfl_xor(qb, 32, 64);

    if (wv < 2) {   // op/c1/c2 packed head: wave wv does mb2 = wv
      f32x4 L = MFMA(LDF(F_PACK + (wv * 2 + 0) * 512), an0.h, zf4);
      L = MFMA(LDF(F_PACK + (wv * 2 + 1) * 512), an1.h, L);
      #pragma unroll
      for (int i = 0; i < 4; i++) {
        int o = wv * 16 + q * 4 + i;
        if (o < 8)       out[(size_t)bb * 8 + o] = L[i] + opb[o];
        else if (o < 18) out[(size_t)B * 8 + (size_t)bb * 10 + (o - 8)] = L[i] + c1b[o - 8];
        else if (o < 28) out[(size_t)B * 18 + (size_t)bb * 10 + (o - 18)] = L[i] + c2b[o - 18];
      }
    }
    // pointer K-GEMM: PK fragments hoisted (late-phase reg pressure is low)
    bf16x8 pkA[4][2];
    #pragma unroll
    for (int mb = 0; mb < 4; mb++) {
      pkA[mb][0] = LDF(F_PK + (mb * 2 + 0) * 512);
      pkA[mb][1] = LDF(F_PK + (mb * 2 + 1) * 512);
    }
    #pragma unroll
    for (int t = 0; t < 5; t++) {
      const int n = wv + 4 * t;
      if (t < nact) {
        float dt = 0.f;
        #pragma unroll
        for (int mb = 0; mb < 4; mb++) {
          f32x4 Kc = MFMA(pkA[mb][0], hA[t][0].h, zf4);
          Kc = MFMA(pkA[mb][1], hA[t][1].h, Kc);
          #pragma unroll
          for (int i = 0; i < 4; i++) dt += qv[mb * 4 + i] * Kc[i];
        }
        dt += __shfl_xor(dt, 16, 64); dt += __shfl_xor(dt, 32, 64);
        if (q == 0)
          out[(size_t)B * 28 + (size_t)bb * 20 + n] = (n < nnv) ? (dt + qb) : -1e9f;
      } else {
        if (q == 0)
          out[(size_t)B * 28 + (size_t)bb * 20 + n] = -1e9f;   // n >= M >= nnv
      }
    }
  }
}

extern "C" void kernel_launch(void* const* d_in, const int* in_sizes, int n_in,
                              void* d_out, int out_size, void* d_ws, size_t ws_size,
                              hipStream_t stream)
{
  (void)n_in; (void)out_size; (void)d_ws; (void)ws_size;
  const float* nf   = (const float*)d_in[0];
  const int*   nnp  = (const int*)  d_in[1];
  const float* rnn  = (const float*)d_in[2];
  const float* poh  = (const float*)d_in[3];
  const float* ne_w = (const float*)d_in[4];
  const float* ne_b = (const float*)d_in[5];
  const float* m1w1 = (const float*)d_in[6];
  const float* m1b1 = (const float*)d_in[7];
  const float* m1w2 = (const float*)d_in[8];
  const float* m1b2 = (const float*)d_in[9];
  const float* n1g  = (const float*)d_in[10];
  const float* n1b  = (const float*)d_in[11];
  const float* m2w1 = (const float*)d_in[12];
  const float* m2b1 = (const float*)d_in[13];
  const float* m2w2 = (const float*)d_in[14];
  const float* m2b2 = (const float*)d_in[15];
  const float* n2g  = (const float*)d_in[16];
  const float* n2b  = (const float*)d_in[17];
  const float* wih  = (const float*)d_in[18];
  const float* whh  = (const float*)d_in[19];
  const float* bih  = (const float*)d_in[20];
  const float* bhh  = (const float*)d_in[21];
  const float* opw  = (const float*)d_in[22];
  const float* opb  = (const float*)d_in[23];
  const float* c1w  = (const float*)d_in[24];
  const float* c1b  = (const float*)d_in[25];
  const float* c2w  = (const float*)d_in[26];
  const float* c2b  = (const float*)d_in[27];
  const float* pqw  = (const float*)d_in[28];
  const float* pqb  = (const float*)d_in[29];
  const float* pkw  = (const float*)d_in[30];
  const float* pkb  = (const float*)d_in[31];
  float* out = (float*)d_out;
  const int B = in_sizes[1];

  prep_frag<<<132, 256, 0, stream>>>(ne_w, m1w1, m1w2, m2w1, m2w2,
                                     wih, whh, pqw, opw, c1w, c2w, pkw,
                                     ne_b, m1b1, m1b2, n1g, n1b,
                                     m2b1, m2b2, n2g, n2b, bih, bhh,
                                     nnp, B);
  nn_scatter<<<(B + 255) / 256, 256, 0, stream>>>(nnp, B);
  msp<<<B / 16, 256, 0, stream>>>(nf, nnp, rnn, poh,
                                  opb, c1b, c2b,
                                  pqb, pkb, out, B);
}

// Round 6
// 387.241 us; speedup vs baseline: 1.8472x; 1.0083x over previous
//
#include <hip/hip_runtime.h>
#include <hip/hip_bf16.h>
#include <cstdint>

#define NM 20
#define NBIN 20
#define MAXB 65536

typedef __attribute__((ext_vector_type(8))) short bf16x8;
typedef __attribute__((ext_vector_type(4))) float f32x4;
typedef __attribute__((ext_vector_type(4))) unsigned int u32x4;

union FU { bf16x8 h; u32x4 u; };

#define MFMA(A, Bf, C) __builtin_amdgcn_mfma_f32_16x16x32_bf16((A), (Bf), (C), 0, 0, 0)

// A-fragment-packed, ROW-PERMUTED weights (bf16), built by prep each launch.
#define F_NE    0        // 4 frags  (4mb x 1kc, K=16 pad 32; col 16 = ne_b)
#define F_M1W1  2048     // 16       (4mb x 4kc, K=128)
#define F_M1W2  10240    // 8        (4mb x 2kc)
#define F_M2W1  14336    // 16
#define F_M2W2  22528    // 8
#define F_WIH   26624    // 36       (12mb x 3kc, K=72 pad 96)
#define F_WHH   45056    // 24       (12mb x 2kc)
#define F_PQ    57344    // 8        (identity rows)
#define F_PK    61440    // 8        (identity rows)
#define F_PACK  65536    // 4        (2mb x 2kc, rows = op|c1|c2 pad 32)
// bf16-packed bias/LN vectors (natural feature order, 64 each)
#define F_BNE   67584
#define F_B11   67648
#define F_B12   67712
#define F_G1    67776
#define F_L1    67840
#define F_B21   67904
#define F_B22   67968
#define F_G2    68032
#define F_L2    68096
#define F_TOTAL 68160

__device__ __align__(16) short g_fr[F_TOTAL];
// GRU gate biases, f32, float4-loadable: [0]=bih+bhh (r), [1]=bih+bhh (z),
// [2]=bih (n), [3]=bhh (n)
__device__ __align__(16) float g_grb[4][64];
__device__ int g_hist[NBIN];   // invariant: zero at kernel entry (reset by last block)
__device__ int g_off[NBIN];
__device__ int g_done;         // invariant: zero at kernel entry
__device__ int g_perm[MAXB];

__device__ __forceinline__ short bf16rn(float x) {
  unsigned u = __float_as_uint(x);
  u += 0x7fffu + ((u >> 16) & 1u);
  return (short)(u >> 16);
}
__device__ __forceinline__ float bf2f(short s) {
  return __uint_as_float(((unsigned)(unsigned short)s) << 16);
}
__device__ __forceinline__ unsigned pk2(float lo, float hi) {
  __hip_bfloat162 t = __float22bfloat162_rn(float2{lo, hi});
  return *reinterpret_cast<unsigned*>(&t);
}
// fast GRU activations: v_exp_f32 + v_rcp_f32 (err ~1e-6, well within tolerance)
__device__ __forceinline__ float fsig(float x) {
  return __builtin_amdgcn_rcpf(1.f + __expf(-x));
}
__device__ __forceinline__ float ftanh(float x) {
  return 1.f - 2.f * __builtin_amdgcn_rcpf(1.f + __expf(2.f * x));
}
// slot permutation: C row r (=mb*16+qq*4+i) lands at slot s64(r); permuting weight
// rows by s64 makes the C-output the B-fragment of the next GEMM, register-locally.
__device__ __forceinline__ int s64(int r) {
  int mb = r >> 4, qq = (r >> 2) & 3, i = r & 3;
  return (mb >> 1) * 32 + qq * 8 + (mb & 1) * 4 + i;
}

#define LDF(off) (*(const bf16x8*)(g_fr + (off) + lane * 8))
#define LDB(off, c) (*(const bf16x8*)(g_fr + (off) + (c) * 32 + q * 8))
// node-local bases (gA/gB include an opaque 0 so loads can't be hoisted/LICM'd)
#define GAF(off) (*(const bf16x8*)(gA + (off)))
#define GBF(off, c) (*(const bf16x8*)(gB + (off) + (c) * 32))

// ---------------- prep (+ n_nodes histogram + DESCENDING scan, ticketed) --------
#define BUILDA(OFS, MB, KC, ROWX, GET)                                 \
  for (int idx = t; idx < (MB) * (KC) * 512; idx += T) {               \
    int j = idx & 7, ln = (idx >> 3) & 63, f = idx >> 9;               \
    int mb = f / (KC), kc = f % (KC);                                  \
    int m = mb * 16 + (ln & 15);                                       \
    int k = kc * 32 + (ln >> 4) * 8 + j;                               \
    int row = (ROWX);                                                  \
    (void)row; (void)k; (void)m;                                       \
    g_fr[(OFS) + idx] = bf16rn(GET);                                   \
  }

__global__ void __launch_bounds__(256)
prep_frag(const float* __restrict__ ne_w,
          const float* __restrict__ m1w1, const float* __restrict__ m1w2,
          const float* __restrict__ m2w1, const float* __restrict__ m2w2,
          const float* __restrict__ wih,  const float* __restrict__ whh,
          const float* __restrict__ pqw,  const float* __restrict__ opw,
          const float* __restrict__ c1w,  const float* __restrict__ c2w,
          const float* __restrict__ pkw,
          const float* __restrict__ ne_b,
          const float* __restrict__ m1b1, const float* __restrict__ m1b2,
          const float* __restrict__ n1g,  const float* __restrict__ n1b,
          const float* __restrict__ m2b1, const float* __restrict__ m2b2,
          const float* __restrict__ n2g,  const float* __restrict__ n2b,
          const float* __restrict__ bih,  const float* __restrict__ bhh,
          const int* __restrict__ nnp, int B)
{
  const int t = blockIdx.x * blockDim.x + threadIdx.x;
  const int T = gridDim.x * blockDim.x;
  // ne_b folded into K-pad column 16 (B supplies constant 1.0 at k=16)
  BUILDA(F_NE,   4, 1, s64(m), (k < 16 ? ne_w[row * 16 + k] : (k == 16 ? ne_b[row] : 0.f)))
  BUILDA(F_M1W1, 4, 4, s64(m), m1w1[row * 128 + k])
  BUILDA(F_M1W2, 4, 2, s64(m), m1w2[row * 64 + k])
  BUILDA(F_M2W1, 4, 4, s64(m), m2w1[row * 128 + k])
  BUILDA(F_M2W2, 4, 2, s64(m), m2w2[row * 64 + k])
  BUILDA(F_WIH, 12, 3, (m & 0xC0) | s64(m & 63), (k < 72 ? wih[row * 72 + k] : 0.f))
  BUILDA(F_WHH, 12, 2, (m & 0xC0) | s64(m & 63), whh[row * 64 + k])
  BUILDA(F_PQ,   4, 2, m, pqw[row * 64 + k])
  BUILDA(F_PK,   4, 2, m, pkw[row * 64 + k])
  BUILDA(F_PACK, 2, 2, m, (row < 8 ? opw[row * 64 + k]
                           : row < 18 ? c1w[(row - 8) * 64 + k]
                           : row < 28 ? c2w[(row - 18) * 64 + k] : 0.f))
  for (int i = t; i < 64; i += T) {
    g_fr[F_BNE + i] = bf16rn(ne_b[i]);
    g_fr[F_B11 + i] = bf16rn(m1b1[i]);
    g_fr[F_B12 + i] = bf16rn(m1b2[i]);
    g_fr[F_G1  + i] = bf16rn(n1g[i]);
    g_fr[F_L1  + i] = bf16rn(n1b[i]);
    g_fr[F_B21 + i] = bf16rn(m2b1[i]);
    g_fr[F_B22 + i] = bf16rn(m2b2[i]);
    g_fr[F_G2  + i] = bf16rn(n2g[i]);
    g_fr[F_L2  + i] = bf16rn(n2b[i]);
    g_grb[0][i] = bih[i]       + bhh[i];
    g_grb[1][i] = bih[64 + i]  + bhh[64 + i];
    g_grb[2][i] = bih[128 + i];
    g_grb[3][i] = bhh[128 + i];
  }

  // ---- histogram of n_nodes (g_hist zero at entry) ----
  __shared__ int lh[NBIN];
  __shared__ int lastdone;
  const int lt = threadIdx.x;
  if (lt < NBIN) lh[lt] = 0;
  __syncthreads();
  for (int i = t; i < B; i += T) atomicAdd(&lh[nnp[i] - 1], 1);
  __syncthreads();
  if (lt < NBIN && lh[lt] > 0) atomicAdd(&g_hist[lt], lh[lt]);
  __threadfence();
  if (lt == 0) lastdone = (atomicAdd(&g_done, 1) == (int)gridDim.x - 1);
  __syncthreads();
  // last block: DESCENDING scan (LPT: heavy blocks dispatch first), then restore
  // the zero-invariant for the next launch/replay.
  if (lastdone && lt == 0) {
    __threadfence();
    int acc = 0;
    for (int i = NBIN - 1; i >= 0; i--) {
      g_off[i] = acc; acc += g_hist[i]; g_hist[i] = 0;
    }
    g_done = 0;
  }
}

__global__ void __launch_bounds__(256)
nn_scatter(const int* __restrict__ nnp, int B)
{
  __shared__ int lc[NBIN], lbase[NBIN];
  const int t = threadIdx.x;
  const int i = blockIdx.x * 256 + t;
  if (t < NBIN) lc[t] = 0;
  __syncthreads();
  int bin = 0, r = 0;
  const bool ok = (i < B);
  if (ok) { bin = nnp[i] - 1; r = atomicAdd(&lc[bin], 1); }
  __syncthreads();
  if (t < NBIN) lbase[t] = (lc[t] > 0) ? atomicAdd(&g_off[t], lc[t]) : 0;
  __syncthreads();
  if (ok) g_perm[lbase[bin] + r] = i;
}

__device__ __forceinline__ void pack8(FU& f, const float* v) {
  f.u[0] = pk2(v[0], v[1]); f.u[1] = pk2(v[2], v[3]);
  f.u[2] = pk2(v[4], v[5]); f.u[3] = pk2(v[6], v[7]);
}

// ---------------- MP stage: interleaved nodes n = wv + 4t, skip t >= nact --------
// Weights re-loaded per node (L1/L2-hot) to keep register live ranges short.
// macc accumulates the masked node-sum for the next exchange (values pre-masked).
__device__ __forceinline__ void mp_stage(
    FU hA[][2], float* macc, const FU* msgf,
    int w1off, int w2off, int b1o, int b2o, int lgo, int lbo,
    int nnv, int wv, int nact, int lane, int q)
{
  if (nact == 0) return;
  const f32x4 zf4 = {0.f, 0.f, 0.f, 0.f};
  f32x4 tmsg[4];
  #pragma unroll
  for (int mb = 0; mb < 4; mb++) {
    tmsg[mb] = MFMA(LDF(w1off + (mb * 4 + 2) * 512), msgf[0].h, zf4);
    tmsg[mb] = MFMA(LDF(w1off + (mb * 4 + 3) * 512), msgf[1].h, tmsg[mb]);
  }
  {
    // hoist b1 bias: added once per wave instead of once per node
    FU b1p0, b1p1; b1p0.h = LDB(b1o, 0); b1p1.h = LDB(b1o, 1);
    #pragma unroll
    for (int mb = 0; mb < 4; mb++)
      #pragma unroll
      for (int i = 0; i < 4; i++)
        tmsg[mb][i] += bf2f(((mb >> 1) ? b1p1 : b1p0).h[(mb & 1) * 4 + i]);
  }

  #pragma unroll
  for (int t = 0; t < 5; t++) {
    if (t < nact) {
      int tz = 0;
      asm volatile("" : "+v"(tz));
      const short* gA = g_fr + lane * 8 + tz;
      const short* gB = g_fr + q * 8 + tz;
      const int n = wv + 4 * t;
      f32x4 T[4];
      #pragma unroll
      for (int mb = 0; mb < 4; mb++) {
        T[mb] = MFMA(GAF(w1off + (mb * 4 + 0) * 512), hA[t][0].h, tmsg[mb]);
        T[mb] = MFMA(GAF(w1off + (mb * 4 + 1) * 512), hA[t][1].h, T[mb]);
      }
      FU tb[2];
      #pragma unroll
      for (int c = 0; c < 2; c++)
        #pragma unroll
        for (int w = 0; w < 4; w++) {
          int mb = 2 * c + (w >> 1), i0 = (w & 1) * 2;
          float lo = fmaxf(T[mb][i0],     0.f);
          float hi = fmaxf(T[mb][i0 + 1], 0.f);
          tb[c].u[w] = pk2(lo, hi);
        }
      f32x4 H[4];
      #pragma unroll
      for (int mb = 0; mb < 4; mb++) {
        H[mb] = MFMA(GAF(w2off + (mb * 2 + 0) * 512), tb[0].h, zf4);
        H[mb] = MFMA(GAF(w2off + (mb * 2 + 1) * 512), tb[1].h, H[mb]);
      }
      FU b2p0, b2p1;
      b2p0.h = GBF(b2o, 0); b2p1.h = GBF(b2o, 1);
      float y[16]; float s = 0.f, ss = 0.f;
      #pragma unroll
      for (int k = 0; k < 16; k++) {
        int c = k >> 3, j = k & 7;
        float v = H[2 * c + (j >> 2)][j & 3] + bf2f((c ? b2p1 : b2p0).h[j]) +
                  bf2f(hA[t][c].h[j]);
        y[k] = v; s += v; ss += v * v;
      }
      s += __shfl_xor(s, 16, 64); ss += __shfl_xor(ss, 16, 64);
      s += __shfl_xor(s, 32, 64); ss += __shfl_xor(ss, 32, 64);
      float mu = s * 0.015625f;
      float rstd = rsqrtf(ss * 0.015625f - mu * mu + 1e-5f);
      float mfv = (n < nnv) ? 1.f : 0.f;
      FU lgp0, lgp1, lbp0, lbp1;
      lgp0.h = GBF(lgo, 0); lgp1.h = GBF(lgo, 1);
      lbp0.h = GBF(lbo, 0); lbp1.h = GBF(lbo, 1);
      #pragma unroll
      for (int k = 0; k < 16; k++) {
        int c = k >> 3, j = k & 7;
        float hv = ((y[k] - mu) * rstd * bf2f((c ? lgp1 : lgp0).h[j]) +
                    bf2f((c ? lbp1 : lbp0).h[j])) * mfv;
        macc[k] += hv; y[k] = hv;
      }
      pack8(hA[t][0], y); pack8(hA[t][1], y + 8);
    }
  }
}

// ---------------- main: 16 sorted batch / block, interleaved node ownership ------
__global__ void __launch_bounds__(256)
msp(const float* __restrict__ nf, const int* __restrict__ nnp,
    const float* __restrict__ rnn, const float* __restrict__ poh,
    const float* __restrict__ opb, const float* __restrict__ c1b,
    const float* __restrict__ c2b, const float* __restrict__ pqb,
    const float* __restrict__ pkb,
    float* __restrict__ out, int B)
{
  // single exchange region (17408 B; +17 pad keeps b128 stores conflict-free) +
  // nsx (2048 B) = 19.5 KB -> 5 blocks/CU (limiter moves back to VGPR @92)
  __shared__ __align__(16) float exch[4][64][17];
  __shared__ __align__(16) unsigned nsx[64][8];

  const int tid = threadIdx.x;
  const int wv = tid >> 6;
  const int lane = tid & 63;
  const int l15 = lane & 15, q = lane >> 4;
  const int b0 = blockIdx.x * 16;
  const int bb = g_perm[b0 + l15];

  const int nnv = nnp[bb];
  const float inv = 1.0f / (float)nnv;
  const f32x4 zf4 = {0.f, 0.f, 0.f, 0.f};

  // block-max nnv (same 16 samples for all waves): reduce within 16-lane groups
  int M = nnv;
  { int o;
    o = __shfl_xor(M, 1, 64); M = M > o ? M : o;
    o = __shfl_xor(M, 2, 64); M = M > o ? M : o;
    o = __shfl_xor(M, 4, 64); M = M > o ? M : o;
    o = __shfl_xor(M, 8, 64); M = M > o ? M : o; }
  // this wave owns nodes n = wv + 4t, t in [0, nact)
  int nact = (M - wv + 3) >> 2;
  nact = nact < 0 ? 0 : (nact > 5 ? 5 : nact);

  FU hA[5][2];
  float mac[16];
  #pragma unroll
  for (int k = 0; k < 16; k++) mac[k] = 0.f;

  // ================= E: h0^T = ne_w' · x^T (bias via k=16 pad column) ==========
  // h0 is masked AT SOURCE (hv *= mfv): exchanges are plain sums of mac.
  // xa prefetch depth 2 (ping-pong, compile-time-selected) to cap reg pressure.
  {
    float4 xaA[2], xaB[2];
    if (nact > 0 && q < 2) {
      const float* p = nf + ((size_t)bb * NM + wv) * 16 + q * 8;
      xaA[0] = *(const float4*)p; xaA[1] = *(const float4*)(p + 4);
    }
    #pragma unroll
    for (int t = 0; t < 5; t++) {
      if (t < nact) {
        float4 c0, c1;
        if ((t & 1) == 0) { c0 = xaA[0]; c1 = xaA[1]; }
        else              { c0 = xaB[0]; c1 = xaB[1]; }
        if (t + 1 < nact && q < 2) {
          const float* p = nf + ((size_t)bb * NM + (wv + 4 * (t + 1))) * 16 + q * 8;
          if ((t & 1) == 0) { xaB[0] = *(const float4*)p; xaB[1] = *(const float4*)(p + 4); }
          else              { xaA[0] = *(const float4*)p; xaA[1] = *(const float4*)(p + 4); }
        }
        int tz = 0;
        asm volatile("" : "+v"(tz));
        const short* gA = g_fr + lane * 8 + tz;
        const int n = wv + 4 * t;
        FU bx;
        bx.u[0] = 0; bx.u[1] = 0; bx.u[2] = 0; bx.u[3] = 0;
        if (q < 2) {
          bx.u[0] = pk2(c0.x, c0.y); bx.u[1] = pk2(c0.z, c0.w);
          bx.u[2] = pk2(c1.x, c1.y); bx.u[3] = pk2(c1.z, c1.w);
        } else if (q == 2) {
          bx.u[0] = pk2(1.f, 0.f);   // k=16 constant-1 -> ne_b column
        }
        f32x4 C[4];
        #pragma unroll
        for (int mb = 0; mb < 4; mb++) C[mb] = MFMA(GAF(F_NE + mb * 512), bx.h, zf4);
        const float mfv = (n < nnv) ? 1.f : 0.f;
        float hv[16];
        #pragma unroll
        for (int k = 0; k < 16; k++) {
          int c = k >> 3, j = k & 7;
          hv[k] = C[2 * c + (j >> 2)][j & 3] * mfv;
          mac[k] += hv[k];
        }
        pack8(hA[t][0], hv); pack8(hA[t][1], hv + 8);
      }
    }
  }

  FU msgf[2];
  // single-region exchange: write, barrier, read, barrier (trailing barrier makes
  // region reuse safe: no wave may overwrite before all waves finished reading)
  #define EXCHANGE()                                                           \
    {                                                                          \
      _Pragma("unroll")                                                        \
      for (int k = 0; k < 16; k++) exch[wv][lane][k] = mac[k];                 \
      __syncthreads();                                                         \
      _Pragma("unroll")                                                        \
      for (int w8 = 0; w8 < 8; w8++) {                                         \
        int k0 = 2 * w8, k1 = k0 + 1;                                          \
        float a = (exch[0][lane][k0] + exch[1][lane][k0] +                     \
                   exch[2][lane][k0] + exch[3][lane][k0]) * inv;               \
        float b = (exch[0][lane][k1] + exch[1][lane][k1] +                     \
                   exch[2][lane][k1] + exch[3][lane][k1]) * inv;               \
        FU* dp = (w8 < 4) ? &msgf[0] : &msgf[1];                               \
        dp->u[w8 & 3] = pk2(a, b);                                             \
      }                                                                        \
      _Pragma("unroll")                                                        \
      for (int k = 0; k < 16; k++) mac[k] = 0.f;                               \
      __syncthreads();                                                         \
    }

  EXCHANGE()   // msg1
  mp_stage(hA, mac, msgf, F_M1W1, F_M1W2, F_B11, F_B12, F_G1, F_L1, nnv, wv, nact, lane, q);

  EXCHANGE()   // msg2
  mp_stage(hA, mac, msgf, F_M2W1, F_M2W2, F_B21, F_B22, F_G2, F_L2, nnv, wv, nact, lane, q);

  EXCHANGE()   // graph_vec -> msgf

  // ================= GRU: wave wv owns gate tile tt = wv; gx == msgf ==========
  {
    FU px;
    if (q == 0) {
      const float* pp = poh + (size_t)bb * 8;
      float4 p0 = *(const float4*)pp, p1 = *(const float4*)(pp + 4);
      px.u[0] = pk2(p0.x, p0.y); px.u[1] = pk2(p0.z, p0.w);
      px.u[2] = pk2(p1.x, p1.y); px.u[3] = pk2(p1.z, p1.w);
    } else { px.u[0] = 0; px.u[1] = 0; px.u[2] = 0; px.u[3] = 0; }
    const float* rr0 = rnn + (size_t)bb * 64;
    float rv[16];
    #pragma unroll
    for (int c = 0; c < 2; c++) {
      float4 a0 = *(const float4*)(rr0 + c * 32 + q * 8);
      float4 a1 = *(const float4*)(rr0 + c * 32 + q * 8 + 4);
      rv[c * 8 + 0] = a0.x; rv[c * 8 + 1] = a0.y; rv[c * 8 + 2] = a0.z; rv[c * 8 + 3] = a0.w;
      rv[c * 8 + 4] = a1.x; rv[c * 8 + 5] = a1.y; rv[c * 8 + 6] = a1.z; rv[c * 8 + 7] = a1.w;
    }
    FU ah[2]; pack8(ah[0], rv); pack8(ah[1], rv + 8);

    const int tt = wv;
    f32x4 R = MFMA(LDF(F_WIH + (tt * 3 + 0) * 512), msgf[0].h, zf4);
    R = MFMA(LDF(F_WIH + (tt * 3 + 1) * 512), msgf[1].h, R);
    R = MFMA(LDF(F_WIH + (tt * 3 + 2) * 512), px.h, R);
    R = MFMA(LDF(F_WHH + (tt * 2 + 0) * 512), ah[0].h, R);
    R = MFMA(LDF(F_WHH + (tt * 2 + 1) * 512), ah[1].h, R);
    f32x4 Z = MFMA(LDF(F_WIH + ((4 + tt) * 3 + 0) * 512), msgf[0].h, zf4);
    Z = MFMA(LDF(F_WIH + ((4 + tt) * 3 + 1) * 512), msgf[1].h, Z);
    Z = MFMA(LDF(F_WIH + ((4 + tt) * 3 + 2) * 512), px.h, Z);
    Z = MFMA(LDF(F_WHH + ((4 + tt) * 2 + 0) * 512), ah[0].h, Z);
    Z = MFMA(LDF(F_WHH + ((4 + tt) * 2 + 1) * 512), ah[1].h, Z);
    f32x4 Ni = MFMA(LDF(F_WIH + ((8 + tt) * 3 + 0) * 512), msgf[0].h, zf4);
    Ni = MFMA(LDF(F_WIH + ((8 + tt) * 3 + 1) * 512), msgf[1].h, Ni);
    Ni = MFMA(LDF(F_WIH + ((8 + tt) * 3 + 2) * 512), px.h, Ni);
    f32x4 Nh = MFMA(LDF(F_WHH + ((8 + tt) * 2 + 0) * 512), ah[0].h, zf4);
    Nh = MFMA(LDF(F_WHH + ((8 + tt) * 2 + 1) * 512), ah[1].h, Nh);

    const int dbase = q * 8 + (tt >> 1) * 32 + (tt & 1) * 4;
    f32x4 brv = *(const f32x4*)&g_grb[0][dbase];
    f32x4 bzv = *(const f32x4*)&g_grb[1][dbase];
    f32x4 bnv = *(const f32x4*)&g_grb[2][dbase];
    f32x4 bhv = *(const f32x4*)&g_grb[3][dbase];
    float nsv[4];
    #pragma unroll
    for (int i = 0; i < 4; i++) {
      const int K = (tt >> 1) * 32 + (tt & 1) * 4 + i;
      const int d = q * 8 + K;
      float rr = fsig(R[i] + brv[i]);
      float zz = fsig(Z[i] + bzv[i]);
      float ng = ftanh(Ni[i] + bnv[i] + rr * (Nh[i] + bhv[i]));
      float st = rv[(tt >> 1) * 8 + (tt & 1) * 4 + i];
      float v = (1.f - zz) * ng + zz * st;
      out[(size_t)B * 48 + (size_t)bb * 64 + d] = v;
      nsv[i] = v;
    }
    // ns quarter -> LDS: dwords (tt>>1)*4 + (tt&1)*2 + {0,1}
    const int dw = (tt >> 1) * 4 + (tt & 1) * 2;
    nsx[lane][dw]     = pk2(nsv[0], nsv[1]);
    nsx[lane][dw + 1] = pk2(nsv[2], nsv[3]);
  }
  __syncthreads();

  // ================= heads + pointer =================
  {
    FU an0, an1;
    an0.u = *(const u32x4*)&nsx[lane][0];
    an1.u = *(const u32x4*)&nsx[lane][4];
    float qv[16];
    #pragma unroll
    for (int mb = 0; mb < 4; mb++) {
      f32x4 Qc = MFMA(LDF(F_PQ + (mb * 2 + 0) * 512), an0.h, zf4);
      Qc = MFMA(LDF(F_PQ + (mb * 2 + 1) * 512), an1.h, Qc);
      f32x4 pq4 = *(const f32x4*)&pqb[mb * 16 + q * 4];
      #pragma unroll
      for (int i = 0; i < 4; i++) qv[mb * 4 + i] = Qc[i] + pq4[i];
    }
    float qb = 0.f;
    #pragma unroll
    for (int mb = 0; mb < 4; mb++) {
      f32x4 pk4 = *(const f32x4*)&pkb[mb * 16 + q * 4];
      #pragma unroll
      for (int i = 0; i < 4; i++) qb += qv[mb * 4 + i] * pk4[i];
    }
    qb += __shfl_xor(qb, 16, 64); qb += __shfl_xor(qb, 32, 64);

    if (wv < 2) {   // op/c1/c2 packed head: wave wv does mb2 = wv
      f32x4 L = MFMA(LDF(F_PACK + (wv * 2 + 0) * 512), an0.h, zf4);
      L = MFMA(LDF(F_PACK + (wv * 2 + 1) * 512), an1.h, L);
      #pragma unroll
      for (int i = 0; i < 4; i++) {
        int o = wv * 16 + q * 4 + i;
        if (o < 8)       out[(size_t)bb * 8 + o] = L[i] + opb[o];
        else if (o < 18) out[(size_t)B * 8 + (size_t)bb * 10 + (o - 8)] = L[i] + c1b[o - 8];
        else if (o < 28) out[(size_t)B * 18 + (size_t)bb * 10 + (o - 18)] = L[i] + c2b[o - 18];
      }
    }
    // pointer K-GEMM: PK fragments hoisted (late-phase reg pressure is low)
    bf16x8 pkA[4][2];
    #pragma unroll
    for (int mb = 0; mb < 4; mb++) {
      pkA[mb][0] = LDF(F_PK + (mb * 2 + 0) * 512);
      pkA[mb][1] = LDF(F_PK + (mb * 2 + 1) * 512);
    }
    #pragma unroll
    for (int t = 0; t < 5; t++) {
      const int n = wv + 4 * t;
      if (t < nact) {
        float dt = 0.f;
        #pragma unroll
        for (int mb = 0; mb < 4; mb++) {
          f32x4 Kc = MFMA(pkA[mb][0], hA[t][0].h, zf4);
          Kc = MFMA(pkA[mb][1], hA[t][1].h, Kc);
          #pragma unroll
          for (int i = 0; i < 4; i++) dt += qv[mb * 4 + i] * Kc[i];
        }
        dt += __shfl_xor(dt, 16, 64); dt += __shfl_xor(dt, 32, 64);
        if (q == 0)
          out[(size_t)B * 28 + (size_t)bb * 20 + n] = (n < nnv) ? (dt + qb) : -1e9f;
      } else {
        if (q == 0)
          out[(size_t)B * 28 + (size_t)bb * 20 + n] = -1e9f;   // n >= M >= nnv
      }
    }
  }
}

extern "C" void kernel_launch(void* const* d_in, const int* in_sizes, int n_in,
                              void* d_out, int out_size, void* d_ws, size_t ws_size,
                              hipStream_t stream)
{
  (void)n_in; (void)out_size; (void)d_ws; (void)ws_size;
  const float* nf   = (const float*)d_in[0];
  const int*   nnp  = (const int*)  d_in[1];
  const float* rnn  = (const float*)d_in[2];
  const float* poh  = (const float*)d_in[3];
  const float* ne_w = (const float*)d_in[4];
  const float* ne_b = (const float*)d_in[5];
  const float* m1w1 = (const float*)d_in[6];
  const float* m1b1 = (const float*)d_in[7];
  const float* m1w2 = (const float*)d_in[8];
  const float* m1b2 = (const float*)d_in[9];
  const float* n1g  = (const float*)d_in[10];
  const float* n1b  = (const float*)d_in[11];
  const float* m2w1 = (const float*)d_in[12];
  const float* m2b1 = (const float*)d_in[13];
  const float* m2w2 = (const float*)d_in[14];
  const float* m2b2 = (const float*)d_in[15];
  const float* n2g  = (const float*)d_in[16];
  const float* n2b  = (const float*)d_in[17];
  const float* wih  = (const float*)d_in[18];
  const float* whh  = (const float*)d_in[19];
  const float* bih  = (const float*)d_in[20];
  const float* bhh  = (const float*)d_in[21];
  const float* opw  = (const float*)d_in[22];
  const float* opb  = (const float*)d_in[23];
  const float* c1w  = (const float*)d_in[24];
  const float* c1b  = (const float*)d_in[25];
  const float* c2w  = (const float*)d_in[26];
  const float* c2b  = (const float*)d_in[27];
  const float* pqw  = (const float*)d_in[28];
  const float* pqb  = (const float*)d_in[29];
  const float* pkw  = (const float*)d_in[30];
  const float* pkb  = (const float*)d_in[31];
  float* out = (float*)d_out;
  const int B = in_sizes[1];

  prep_frag<<<132, 256, 0, stream>>>(ne_w, m1w1, m1w2, m2w1, m2w2,
                                     wih, whh, pqw, opw, c1w, c2w, pkw,
                                     ne_b, m1b1, m1b2, n1g, n1b,
                                     m2b1, m2b2, n2g, n2b, bih, bhh,
                                     nnp, B);
  nn_scatter<<<(B + 255) / 256, 256, 0, stream>>>(nnp, B);
  msp<<<B / 16, 256, 0, stream>>>(nf, nnp, rnn, poh,
                                  opb, c1b, c2b,
                                  pqb, pkb, out, B);
}

// Round 7
// 375.025 us; speedup vs baseline: 1.9073x; 1.0326x over previous
//
#include <hip/hip_runtime.h>
#include <hip/hip_bf16.h>
#include <cstdint>

#define NM 20
#define NBIN 20
#define MAXB 65536

typedef __attribute__((ext_vector_type(8))) short bf16x8;
typedef __attribute__((ext_vector_type(4))) float f32x4;
typedef __attribute__((ext_vector_type(4))) unsigned int u32x4;

union FU { bf16x8 h; u32x4 u; };

#define MFMA(A, Bf, C) __builtin_amdgcn_mfma_f32_16x16x32_bf16((A), (Bf), (C), 0, 0, 0)

// A-fragment-packed, ROW-PERMUTED weights (bf16), built by prep each launch.
#define F_NE    0        // 4 frags  (4mb x 1kc, K=16 pad 32; col 16 = ne_b)
#define F_M1W1  2048     // 16       (4mb x 4kc, K=128)
#define F_M1W2  10240    // 8        (4mb x 2kc)
#define F_M2W1  14336    // 16
#define F_M2W2  22528    // 8
#define F_WIH   26624    // 36       (12mb x 3kc, K=72 pad 96)
#define F_WHH   45056    // 24       (12mb x 2kc)
#define F_PQ    57344    // 8        (identity rows)
#define F_PK    61440    // 8        (identity rows)
#define F_PACK  65536    // 4        (2mb x 2kc, rows = op|c1|c2 pad 32)
// bf16-packed bias/LN vectors (natural feature order, 64 each)
#define F_BNE   67584
#define F_B11   67648
#define F_B12   67712
#define F_G1    67776
#define F_L1    67840
#define F_B21   67904
#define F_B22   67968
#define F_G2    68032
#define F_L2    68096
#define F_TOTAL 68160

__device__ __align__(16) short g_fr[F_TOTAL];
// GRU gate biases, f32, float4-loadable: [0]=bih+bhh (r), [1]=bih+bhh (z),
// [2]=bih (n), [3]=bhh (n)
__device__ __align__(16) float g_grb[4][64];
__device__ int g_hist[NBIN];   // invariant: zero at kernel entry (reset by last block)
__device__ int g_off[NBIN];
__device__ int g_done;         // invariant: zero at kernel entry
__device__ int g_perm[MAXB];

__device__ __forceinline__ short bf16rn(float x) {
  unsigned u = __float_as_uint(x);
  u += 0x7fffu + ((u >> 16) & 1u);
  return (short)(u >> 16);
}
__device__ __forceinline__ float bf2f(short s) {
  return __uint_as_float(((unsigned)(unsigned short)s) << 16);
}
__device__ __forceinline__ unsigned pk2(float lo, float hi) {
  __hip_bfloat162 t = __float22bfloat162_rn(float2{lo, hi});
  return *reinterpret_cast<unsigned*>(&t);
}
// fast GRU activations: v_exp_f32 + v_rcp_f32 (err ~1e-6, well within tolerance)
__device__ __forceinline__ float fsig(float x) {
  return __builtin_amdgcn_rcpf(1.f + __expf(-x));
}
__device__ __forceinline__ float ftanh(float x) {
  return 1.f - 2.f * __builtin_amdgcn_rcpf(1.f + __expf(2.f * x));
}
// slot permutation: C row r (=mb*16+qq*4+i) lands at slot s64(r); permuting weight
// rows by s64 makes the C-output the B-fragment of the next GEMM, register-locally.
__device__ __forceinline__ int s64(int r) {
  int mb = r >> 4, qq = (r >> 2) & 3, i = r & 3;
  return (mb >> 1) * 32 + qq * 8 + (mb & 1) * 4 + i;
}

#define LDF(off) (*(const bf16x8*)(g_fr + (off) + lane * 8))
#define LDB(off, c) (*(const bf16x8*)(g_fr + (off) + (c) * 32 + q * 8))
// node-local bases (gA/gB include an opaque 0 so loads can't be hoisted/LICM'd;
// protects the <=128-VGPR occupancy bin from over-aggressive LICM)
#define GAF(off) (*(const bf16x8*)(gA + (off)))
#define GBF(off, c) (*(const bf16x8*)(gB + (off) + (c) * 32))

// ---------------- prep (+ n_nodes histogram + DESCENDING scan, ticketed) --------
#define BUILDA(OFS, MB, KC, ROWX, GET)                                 \
  for (int idx = t; idx < (MB) * (KC) * 512; idx += T) {               \
    int j = idx & 7, ln = (idx >> 3) & 63, f = idx >> 9;               \
    int mb = f / (KC), kc = f % (KC);                                  \
    int m = mb * 16 + (ln & 15);                                       \
    int k = kc * 32 + (ln >> 4) * 8 + j;                               \
    int row = (ROWX);                                                  \
    (void)row; (void)k; (void)m;                                       \
    g_fr[(OFS) + idx] = bf16rn(GET);                                   \
  }

__global__ void __launch_bounds__(256)
prep_frag(const float* __restrict__ ne_w,
          const float* __restrict__ m1w1, const float* __restrict__ m1w2,
          const float* __restrict__ m2w1, const float* __restrict__ m2w2,
          const float* __restrict__ wih,  const float* __restrict__ whh,
          const float* __restrict__ pqw,  const float* __restrict__ opw,
          const float* __restrict__ c1w,  const float* __restrict__ c2w,
          const float* __restrict__ pkw,
          const float* __restrict__ ne_b,
          const float* __restrict__ m1b1, const float* __restrict__ m1b2,
          const float* __restrict__ n1g,  const float* __restrict__ n1b,
          const float* __restrict__ m2b1, const float* __restrict__ m2b2,
          const float* __restrict__ n2g,  const float* __restrict__ n2b,
          const float* __restrict__ bih,  const float* __restrict__ bhh,
          const int* __restrict__ nnp, int B)
{
  const int t = blockIdx.x * blockDim.x + threadIdx.x;
  const int T = gridDim.x * blockDim.x;
  // ne_b folded into K-pad column 16 (B supplies constant 1.0 at k=16)
  BUILDA(F_NE,   4, 1, s64(m), (k < 16 ? ne_w[row * 16 + k] : (k == 16 ? ne_b[row] : 0.f)))
  BUILDA(F_M1W1, 4, 4, s64(m), m1w1[row * 128 + k])
  BUILDA(F_M1W2, 4, 2, s64(m), m1w2[row * 64 + k])
  BUILDA(F_M2W1, 4, 4, s64(m), m2w1[row * 128 + k])
  BUILDA(F_M2W2, 4, 2, s64(m), m2w2[row * 64 + k])
  BUILDA(F_WIH, 12, 3, (m & 0xC0) | s64(m & 63), (k < 72 ? wih[row * 72 + k] : 0.f))
  BUILDA(F_WHH, 12, 2, (m & 0xC0) | s64(m & 63), whh[row * 64 + k])
  BUILDA(F_PQ,   4, 2, m, pqw[row * 64 + k])
  BUILDA(F_PK,   4, 2, m, pkw[row * 64 + k])
  BUILDA(F_PACK, 2, 2, m, (row < 8 ? opw[row * 64 + k]
                           : row < 18 ? c1w[(row - 8) * 64 + k]
                           : row < 28 ? c2w[(row - 18) * 64 + k] : 0.f))
  for (int i = t; i < 64; i += T) {
    g_fr[F_BNE + i] = bf16rn(ne_b[i]);
    g_fr[F_B11 + i] = bf16rn(m1b1[i]);
    g_fr[F_B12 + i] = bf16rn(m1b2[i]);
    g_fr[F_G1  + i] = bf16rn(n1g[i]);
    g_fr[F_L1  + i] = bf16rn(n1b[i]);
    g_fr[F_B21 + i] = bf16rn(m2b1[i]);
    g_fr[F_B22 + i] = bf16rn(m2b2[i]);
    g_fr[F_G2  + i] = bf16rn(n2g[i]);
    g_fr[F_L2  + i] = bf16rn(n2b[i]);
    g_grb[0][i] = bih[i]       + bhh[i];
    g_grb[1][i] = bih[64 + i]  + bhh[64 + i];
    g_grb[2][i] = bih[128 + i];
    g_grb[3][i] = bhh[128 + i];
  }

  // ---- histogram of n_nodes (g_hist zero at entry) ----
  __shared__ int lh[NBIN];
  __shared__ int lastdone;
  const int lt = threadIdx.x;
  if (lt < NBIN) lh[lt] = 0;
  __syncthreads();
  for (int i = t; i < B; i += T) atomicAdd(&lh[nnp[i] - 1], 1);
  __syncthreads();
  if (lt < NBIN && lh[lt] > 0) atomicAdd(&g_hist[lt], lh[lt]);
  __threadfence();
  if (lt == 0) lastdone = (atomicAdd(&g_done, 1) == (int)gridDim.x - 1);
  __syncthreads();
  // last block: DESCENDING scan (LPT: heavy blocks dispatch first), then restore
  // the zero-invariant for the next launch/replay.
  if (lastdone && lt == 0) {
    __threadfence();
    int acc = 0;
    for (int i = NBIN - 1; i >= 0; i--) {
      g_off[i] = acc; acc += g_hist[i]; g_hist[i] = 0;
    }
    g_done = 0;
  }
}

__global__ void __launch_bounds__(256)
nn_scatter(const int* __restrict__ nnp, int B)
{
  __shared__ int lc[NBIN], lbase[NBIN];
  const int t = threadIdx.x;
  const int i = blockIdx.x * 256 + t;
  if (t < NBIN) lc[t] = 0;
  __syncthreads();
  int bin = 0, r = 0;
  const bool ok = (i < B);
  if (ok) { bin = nnp[i] - 1; r = atomicAdd(&lc[bin], 1); }
  __syncthreads();
  if (t < NBIN) lbase[t] = (lc[t] > 0) ? atomicAdd(&g_off[t], lc[t]) : 0;
  __syncthreads();
  if (ok) g_perm[lbase[bin] + r] = i;
}

__device__ __forceinline__ void pack8(FU& f, const float* v) {
  f.u[0] = pk2(v[0], v[1]); f.u[1] = pk2(v[2], v[3]);
  f.u[2] = pk2(v[4], v[5]); f.u[3] = pk2(v[6], v[7]);
}

// ---------------- MP stage: interleaved nodes n = wv + 4t, skip t >= nact --------
// W1 fragments hoisted into registers (+32 VGPR; 65..128 bin has the headroom);
// W2/bias re-loaded per node (tz-pinned) to stay under the 128-VGPR bin edge.
__device__ __forceinline__ void mp_stage(
    FU hA[][2], float* macc, const FU* msgf,
    int w1off, int w2off, int b1o, int b2o, int lgo, int lbo,
    int nnv, int wv, int nact, int lane, int q)
{
  if (nact == 0) return;
  const f32x4 zf4 = {0.f, 0.f, 0.f, 0.f};
  f32x4 tmsg[4];
  #pragma unroll
  for (int mb = 0; mb < 4; mb++) {
    tmsg[mb] = MFMA(LDF(w1off + (mb * 4 + 2) * 512), msgf[0].h, zf4);
    tmsg[mb] = MFMA(LDF(w1off + (mb * 4 + 3) * 512), msgf[1].h, tmsg[mb]);
  }
  {
    // hoist b1 bias: added once per wave instead of once per node
    FU b1p0, b1p1; b1p0.h = LDB(b1o, 0); b1p1.h = LDB(b1o, 1);
    #pragma unroll
    for (int mb = 0; mb < 4; mb++)
      #pragma unroll
      for (int i = 0; i < 4; i++)
        tmsg[mb][i] += bf2f(((mb >> 1) ? b1p1 : b1p0).h[(mb & 1) * 4 + i]);
  }
  // hoist W1 A-fragments (8 frags = 32 VGPR): removes 8 dependent L1/L2 loads
  // from every node iteration's critical path
  bf16x8 w1A[4][2];
  #pragma unroll
  for (int mb = 0; mb < 4; mb++) {
    w1A[mb][0] = LDF(w1off + (mb * 4 + 0) * 512);
    w1A[mb][1] = LDF(w1off + (mb * 4 + 1) * 512);
  }

  #pragma unroll
  for (int t = 0; t < 5; t++) {
    if (t < nact) {
      int tz = 0;
      asm volatile("" : "+v"(tz));
      const short* gA = g_fr + lane * 8 + tz;
      const short* gB = g_fr + q * 8 + tz;
      const int n = wv + 4 * t;
      f32x4 T[4];
      #pragma unroll
      for (int mb = 0; mb < 4; mb++) {
        T[mb] = MFMA(w1A[mb][0], hA[t][0].h, tmsg[mb]);
        T[mb] = MFMA(w1A[mb][1], hA[t][1].h, T[mb]);
      }
      FU tb[2];
      #pragma unroll
      for (int c = 0; c < 2; c++)
        #pragma unroll
        for (int w = 0; w < 4; w++) {
          int mb = 2 * c + (w >> 1), i0 = (w & 1) * 2;
          float lo = fmaxf(T[mb][i0],     0.f);
          float hi = fmaxf(T[mb][i0 + 1], 0.f);
          tb[c].u[w] = pk2(lo, hi);
        }
      f32x4 H[4];
      #pragma unroll
      for (int mb = 0; mb < 4; mb++) {
        H[mb] = MFMA(GAF(w2off + (mb * 2 + 0) * 512), tb[0].h, zf4);
        H[mb] = MFMA(GAF(w2off + (mb * 2 + 1) * 512), tb[1].h, H[mb]);
      }
      FU b2p0, b2p1;
      b2p0.h = GBF(b2o, 0); b2p1.h = GBF(b2o, 1);
      float y[16]; float s = 0.f, ss = 0.f;
      #pragma unroll
      for (int k = 0; k < 16; k++) {
        int c = k >> 3, j = k & 7;
        float v = H[2 * c + (j >> 2)][j & 3] + bf2f((c ? b2p1 : b2p0).h[j]) +
                  bf2f(hA[t][c].h[j]);
        y[k] = v; s += v; ss += v * v;
      }
      s += __shfl_xor(s, 16, 64); ss += __shfl_xor(ss, 16, 64);
      s += __shfl_xor(s, 32, 64); ss += __shfl_xor(ss, 32, 64);
      float mu = s * 0.015625f;
      float rstd = rsqrtf(ss * 0.015625f - mu * mu + 1e-5f);
      float mfv = (n < nnv) ? 1.f : 0.f;
      FU lgp0, lgp1, lbp0, lbp1;
      lgp0.h = GBF(lgo, 0); lgp1.h = GBF(lgo, 1);
      lbp0.h = GBF(lbo, 0); lbp1.h = GBF(lbo, 1);
      #pragma unroll
      for (int k = 0; k < 16; k++) {
        int c = k >> 3, j = k & 7;
        float hv = ((y[k] - mu) * rstd * bf2f((c ? lgp1 : lgp0).h[j]) +
                    bf2f((c ? lbp1 : lbp0).h[j])) * mfv;
        macc[k] += hv; y[k] = hv;
      }
      pack8(hA[t][0], y); pack8(hA[t][1], y + 8);
    }
  }
}

// ---------------- main: 16 sorted batch / block, interleaved node ownership ------
__global__ void __launch_bounds__(256)
msp(const float* __restrict__ nf, const int* __restrict__ nnp,
    const float* __restrict__ rnn, const float* __restrict__ poh,
    const float* __restrict__ opb, const float* __restrict__ c1b,
    const float* __restrict__ c2b, const float* __restrict__ pqb,
    const float* __restrict__ pkb,
    float* __restrict__ out, int B)
{
  // double-buffered exchange (no trailing barriers needed); 36.9 KB LDS still
  // fits the 4-blocks/CU cap set by the 65..128 VGPR occupancy bin
  __shared__ __align__(16) float exch[2][4][64][17];
  __shared__ __align__(16) unsigned nsx[64][8];

  const int tid = threadIdx.x;
  const int wv = tid >> 6;
  const int lane = tid & 63;
  const int l15 = lane & 15, q = lane >> 4;
  const int b0 = blockIdx.x * 16;
  const int bb = g_perm[b0 + l15];

  const int nnv = nnp[bb];
  const float inv = 1.0f / (float)nnv;
  const f32x4 zf4 = {0.f, 0.f, 0.f, 0.f};

  // block-max nnv (same 16 samples for all waves): reduce within 16-lane groups
  int M = nnv;
  { int o;
    o = __shfl_xor(M, 1, 64); M = M > o ? M : o;
    o = __shfl_xor(M, 2, 64); M = M > o ? M : o;
    o = __shfl_xor(M, 4, 64); M = M > o ? M : o;
    o = __shfl_xor(M, 8, 64); M = M > o ? M : o; }
  // this wave owns nodes n = wv + 4t, t in [0, nact)
  int nact = (M - wv + 3) >> 2;
  nact = nact < 0 ? 0 : (nact > 5 ? 5 : nact);

  FU hA[5][2];
  float mac[16];
  #pragma unroll
  for (int k = 0; k < 16; k++) mac[k] = 0.f;

  // ================= E: h0^T = ne_w' · x^T (bias via k=16 pad column) ==========
  // h0 is masked AT SOURCE (hv *= mfv): exchanges are plain sums of mac.
  // xa prefetch depth 2 (ping-pong, compile-time-selected) to cap reg pressure.
  {
    bf16x8 neA[4];
    #pragma unroll
    for (int mb = 0; mb < 4; mb++) neA[mb] = LDF(F_NE + mb * 512);
    float4 xaA[2], xaB[2];
    if (nact > 0 && q < 2) {
      const float* p = nf + ((size_t)bb * NM + wv) * 16 + q * 8;
      xaA[0] = *(const float4*)p; xaA[1] = *(const float4*)(p + 4);
    }
    #pragma unroll
    for (int t = 0; t < 5; t++) {
      if (t < nact) {
        float4 c0, c1;
        if ((t & 1) == 0) { c0 = xaA[0]; c1 = xaA[1]; }
        else              { c0 = xaB[0]; c1 = xaB[1]; }
        if (t + 1 < nact && q < 2) {
          const float* p = nf + ((size_t)bb * NM + (wv + 4 * (t + 1))) * 16 + q * 8;
          if ((t & 1) == 0) { xaB[0] = *(const float4*)p; xaB[1] = *(const float4*)(p + 4); }
          else              { xaA[0] = *(const float4*)p; xaA[1] = *(const float4*)(p + 4); }
        }
        const int n = wv + 4 * t;
        FU bx;
        bx.u[0] = 0; bx.u[1] = 0; bx.u[2] = 0; bx.u[3] = 0;
        if (q < 2) {
          bx.u[0] = pk2(c0.x, c0.y); bx.u[1] = pk2(c0.z, c0.w);
          bx.u[2] = pk2(c1.x, c1.y); bx.u[3] = pk2(c1.z, c1.w);
        } else if (q == 2) {
          bx.u[0] = pk2(1.f, 0.f);   // k=16 constant-1 -> ne_b column
        }
        f32x4 C[4];
        #pragma unroll
        for (int mb = 0; mb < 4; mb++) C[mb] = MFMA(neA[mb], bx.h, zf4);
        const float mfv = (n < nnv) ? 1.f : 0.f;
        float hv[16];
        #pragma unroll
        for (int k = 0; k < 16; k++) {
          int c = k >> 3, j = k & 7;
          hv[k] = C[2 * c + (j >> 2)][j & 3] * mfv;
          mac[k] += hv[k];
        }
        pack8(hA[t][0], hv); pack8(hA[t][1], hv + 8);
      }
    }
  }

  FU msgf[2];
  // double-buffered exchange: write region, barrier, read region; buffer
  // alternation makes region reuse safe without a trailing barrier
  #define EXCHANGE(REG)                                                        \
    {                                                                          \
      _Pragma("unroll")                                                        \
      for (int k = 0; k < 16; k++) exch[REG][wv][lane][k] = mac[k];            \
      __syncthreads();                                                         \
      _Pragma("unroll")                                                        \
      for (int w8 = 0; w8 < 8; w8++) {                                         \
        int k0 = 2 * w8, k1 = k0 + 1;                                          \
        float a = (exch[REG][0][lane][k0] + exch[REG][1][lane][k0] +           \
                   exch[REG][2][lane][k0] + exch[REG][3][lane][k0]) * inv;     \
        float b = (exch[REG][0][lane][k1] + exch[REG][1][lane][k1] +           \
                   exch[REG][2][lane][k1] + exch[REG][3][lane][k1]) * inv;     \
        FU* dp = (w8 < 4) ? &msgf[0] : &msgf[1];                               \
        dp->u[w8 & 3] = pk2(a, b);                                             \
      }                                                                        \
      _Pragma("unroll")                                                        \
      for (int k = 0; k < 16; k++) mac[k] = 0.f;                               \
    }

  EXCHANGE(0)   // msg1
  mp_stage(hA, mac, msgf, F_M1W1, F_M1W2, F_B11, F_B12, F_G1, F_L1, nnv, wv, nact, lane, q);

  EXCHANGE(1)   // msg2
  mp_stage(hA, mac, msgf, F_M2W1, F_M2W2, F_B21, F_B22, F_G2, F_L2, nnv, wv, nact, lane, q);

  EXCHANGE(0)   // graph_vec (region 0 safe: all reads done pre-EXCHANGE(1) barrier)

  // ================= GRU: wave wv owns gate tile tt = wv; gx == msgf ==========
  {
    FU px;
    if (q == 0) {
      const float* pp = poh + (size_t)bb * 8;
      float4 p0 = *(const float4*)pp, p1 = *(const float4*)(pp + 4);
      px.u[0] = pk2(p0.x, p0.y); px.u[1] = pk2(p0.z, p0.w);
      px.u[2] = pk2(p1.x, p1.y); px.u[3] = pk2(p1.z, p1.w);
    } else { px.u[0] = 0; px.u[1] = 0; px.u[2] = 0; px.u[3] = 0; }
    const float* rr0 = rnn + (size_t)bb * 64;
    float rv[16];
    #pragma unroll
    for (int c = 0; c < 2; c++) {
      float4 a0 = *(const float4*)(rr0 + c * 32 + q * 8);
      float4 a1 = *(const float4*)(rr0 + c * 32 + q * 8 + 4);
      rv[c * 8 + 0] = a0.x; rv[c * 8 + 1] = a0.y; rv[c * 8 + 2] = a0.z; rv[c * 8 + 3] = a0.w;
      rv[c * 8 + 4] = a1.x; rv[c * 8 + 5] = a1.y; rv[c * 8 + 6] = a1.z; rv[c * 8 + 7] = a1.w;
    }
    FU ah[2]; pack8(ah[0], rv); pack8(ah[1], rv + 8);

    const int tt = wv;
    f32x4 R = MFMA(LDF(F_WIH + (tt * 3 + 0) * 512), msgf[0].h, zf4);
    R = MFMA(LDF(F_WIH + (tt * 3 + 1) * 512), msgf[1].h, R);
    R = MFMA(LDF(F_WIH + (tt * 3 + 2) * 512), px.h, R);
    R = MFMA(LDF(F_WHH + (tt * 2 + 0) * 512), ah[0].h, R);
    R = MFMA(LDF(F_WHH + (tt * 2 + 1) * 512), ah[1].h, R);
    f32x4 Z = MFMA(LDF(F_WIH + ((4 + tt) * 3 + 0) * 512), msgf[0].h, zf4);
    Z = MFMA(LDF(F_WIH + ((4 + tt) * 3 + 1) * 512), msgf[1].h, Z);
    Z = MFMA(LDF(F_WIH + ((4 + tt) * 3 + 2) * 512), px.h, Z);
    Z = MFMA(LDF(F_WHH + ((4 + tt) * 2 + 0) * 512), ah[0].h, Z);
    Z = MFMA(LDF(F_WHH + ((4 + tt) * 2 + 1) * 512), ah[1].h, Z);
    f32x4 Ni = MFMA(LDF(F_WIH + ((8 + tt) * 3 + 0) * 512), msgf[0].h, zf4);
    Ni = MFMA(LDF(F_WIH + ((8 + tt) * 3 + 1) * 512), msgf[1].h, Ni);
    Ni = MFMA(LDF(F_WIH + ((8 + tt) * 3 + 2) * 512), px.h, Ni);
    f32x4 Nh = MFMA(LDF(F_WHH + ((8 + tt) * 2 + 0) * 512), ah[0].h, zf4);
    Nh = MFMA(LDF(F_WHH + ((8 + tt) * 2 + 1) * 512), ah[1].h, Nh);

    const int dbase = q * 8 + (tt >> 1) * 32 + (tt & 1) * 4;
    f32x4 brv = *(const f32x4*)&g_grb[0][dbase];
    f32x4 bzv = *(const f32x4*)&g_grb[1][dbase];
    f32x4 bnv = *(const f32x4*)&g_grb[2][dbase];
    f32x4 bhv = *(const f32x4*)&g_grb[3][dbase];
    float nsv[4];
    #pragma unroll
    for (int i = 0; i < 4; i++) {
      const int K = (tt >> 1) * 32 + (tt & 1) * 4 + i;
      const int d = q * 8 + K;
      float rr = fsig(R[i] + brv[i]);
      float zz = fsig(Z[i] + bzv[i]);
      float ng = ftanh(Ni[i] + bnv[i] + rr * (Nh[i] + bhv[i]));
      float st = rv[(tt >> 1) * 8 + (tt & 1) * 4 + i];
      float v = (1.f - zz) * ng + zz * st;
      out[(size_t)B * 48 + (size_t)bb * 64 + d] = v;
      nsv[i] = v;
    }
    // ns quarter -> LDS: dwords (tt>>1)*4 + (tt&1)*2 + {0,1}
    const int dw = (tt >> 1) * 4 + (tt & 1) * 2;
    nsx[lane][dw]     = pk2(nsv[0], nsv[1]);
    nsx[lane][dw + 1] = pk2(nsv[2], nsv[3]);
  }
  __syncthreads();

  // ================= heads + pointer =================
  {
    FU an0, an1;
    an0.u = *(const u32x4*)&nsx[lane][0];
    an1.u = *(const u32x4*)&nsx[lane][4];
    float qv[16];
    #pragma unroll
    for (int mb = 0; mb < 4; mb++) {
      f32x4 Qc = MFMA(LDF(F_PQ + (mb * 2 + 0) * 512), an0.h, zf4);
      Qc = MFMA(LDF(F_PQ + (mb * 2 + 1) * 512), an1.h, Qc);
      f32x4 pq4 = *(const f32x4*)&pqb[mb * 16 + q * 4];
      #pragma unroll
      for (int i = 0; i < 4; i++) qv[mb * 4 + i] = Qc[i] + pq4[i];
    }
    float qb = 0.f;
    #pragma unroll
    for (int mb = 0; mb < 4; mb++) {
      f32x4 pk4 = *(const f32x4*)&pkb[mb * 16 + q * 4];
      #pragma unroll
      for (int i = 0; i < 4; i++) qb += qv[mb * 4 + i] * pk4[i];
    }
    qb += __shfl_xor(qb, 16, 64); qb += __shfl_xor(qb, 32, 64);

    if (wv < 2) {   // op/c1/c2 packed head: wave wv does mb2 = wv
      f32x4 L = MFMA(LDF(F_PACK + (wv * 2 + 0) * 512), an0.h, zf4);
      L = MFMA(LDF(F_PACK + (wv * 2 + 1) * 512), an1.h, L);
      #pragma unroll
      for (int i = 0; i < 4; i++) {
        int o = wv * 16 + q * 4 + i;
        if (o < 8)       out[(size_t)bb * 8 + o] = L[i] + opb[o];
        else if (o < 18) out[(size_t)B * 8 + (size_t)bb * 10 + (o - 8)] = L[i] + c1b[o - 8];
        else if (o < 28) out[(size_t)B * 18 + (size_t)bb * 10 + (o - 18)] = L[i] + c2b[o - 18];
      }
    }
    // pointer K-GEMM: PK fragments hoisted (late-phase reg pressure is low)
    bf16x8 pkA[4][2];
    #pragma unroll
    for (int mb = 0; mb < 4; mb++) {
      pkA[mb][0] = LDF(F_PK + (mb * 2 + 0) * 512);
      pkA[mb][1] = LDF(F_PK + (mb * 2 + 1) * 512);
    }
    #pragma unroll
    for (int t = 0; t < 5; t++) {
      const int n = wv + 4 * t;
      if (t < nact) {
        float dt = 0.f;
        #pragma unroll
        for (int mb = 0; mb < 4; mb++) {
          f32x4 Kc = MFMA(pkA[mb][0], hA[t][0].h, zf4);
          Kc = MFMA(pkA[mb][1], hA[t][1].h, Kc);
          #pragma unroll
          for (int i = 0; i < 4; i++) dt += qv[mb * 4 + i] * Kc[i];
        }
        dt += __shfl_xor(dt, 16, 64); dt += __shfl_xor(dt, 32, 64);
        if (q == 0)
          out[(size_t)B * 28 + (size_t)bb * 20 + n] = (n < nnv) ? (dt + qb) : -1e9f;
      } else {
        if (q == 0)
          out[(size_t)B * 28 + (size_t)bb * 20 + n] = -1e9f;   // n >= M >= nnv
      }
    }
  }
}

extern "C" void kernel_launch(void* const* d_in, const int* in_sizes, int n_in,
                              void* d_out, int out_size, void* d_ws, size_t ws_size,
                              hipStream_t stream)
{
  (void)n_in; (void)out_size; (void)d_ws; (void)ws_size;
  const float* nf   = (const float*)d_in[0];
  const int*   nnp  = (const int*)  d_in[1];
  const float* rnn  = (const float*)d_in[2];
  const float* poh  = (const float*)d_in[3];
  const float* ne_w = (const float*)d_in[4];
  const float* ne_b = (const float*)d_in[5];
  const float* m1w1 = (const float*)d_in[6];
  const float* m1b1 = (const float*)d_in[7];
  const float* m1w2 = (const float*)d_in[8];
  const float* m1b2 = (const float*)d_in[9];
  const float* n1g  = (const float*)d_in[10];
  const float* n1b  = (const float*)d_in[11];
  const float* m2w1 = (const float*)d_in[12];
  const float* m2b1 = (const float*)d_in[13];
  const float* m2w2 = (const float*)d_in[14];
  const float* m2b2 = (const float*)d_in[15];
  const float* n2g  = (const float*)d_in[16];
  const float* n2b  = (const float*)d_in[17];
  const float* wih  = (const float*)d_in[18];
  const float* whh  = (const float*)d_in[19];
  const float* bih  = (const float*)d_in[20];
  const float* bhh  = (const float*)d_in[21];
  const float* opw  = (const float*)d_in[22];
  const float* opb  = (const float*)d_in[23];
  const float* c1w  = (const float*)d_in[24];
  const float* c1b  = (const float*)d_in[25];
  const float* c2w  = (const float*)d_in[26];
  const float* c2b  = (const float*)d_in[27];
  const float* pqw  = (const float*)d_in[28];
  const float* pqb  = (const float*)d_in[29];
  const float* pkw  = (const float*)d_in[30];
  const float* pkb  = (const float*)d_in[31];
  float* out = (float*)d_out;
  const int B = in_sizes[1];

  prep_frag<<<132, 256, 0, stream>>>(ne_w, m1w1, m1w2, m2w1, m2w2,
                                     wih, whh, pqw, opw, c1w, c2w, pkw,
                                     ne_b, m1b1, m1b2, n1g, n1b,
                                     m2b1, m2b2, n2g, n2b, bih, bhh,
                                     nnp, B);
  nn_scatter<<<(B + 255) / 256, 256, 0, stream>>>(nnp, B);
  msp<<<B / 16, 256, 0, stream>>>(nf, nnp, rnn, poh,
                                  opb, c1b, c2b,
                                  pqb, pkb, out, B);
}

// Round 8
// 371.916 us; speedup vs baseline: 1.9233x; 1.0084x over previous
//
#include <hip/hip_runtime.h>
#include <hip/hip_bf16.h>
#include <cstdint>

#define NM 20
#define NBIN 20
#define MAXB 65536

typedef __attribute__((ext_vector_type(8))) short bf16x8;
typedef __attribute__((ext_vector_type(4))) float f32x4;
typedef __attribute__((ext_vector_type(4))) unsigned int u32x4;

union FU { bf16x8 h; u32x4 u; };

#define MFMA(A, Bf, C) __builtin_amdgcn_mfma_f32_16x16x32_bf16((A), (Bf), (C), 0, 0, 0)

// A-fragment-packed, ROW-PERMUTED weights (bf16), built by prep each launch.
#define F_NE    0        // 4 frags  (4mb x 1kc, K=16 pad 32; col 16 = ne_b)
#define F_M1W1  2048     // 16       (4mb x 4kc, K=128)
#define F_M1W2  10240    // 8        (4mb x 2kc)
#define F_M2W1  14336    // 16
#define F_M2W2  22528    // 8
#define F_WIH   26624    // 36       (12mb x 3kc, K=72 pad 96)
#define F_WHH   45056    // 24       (12mb x 2kc)
#define F_PQ    57344    // 8        (identity rows)
#define F_PK    61440    // 8        (identity rows)
#define F_PACK  65536    // 4        (2mb x 2kc, rows = op|c1|c2 pad 32)
// bf16-packed b1 vectors (natural feature order, 64 each) — used by tmsg fold
#define F_B11   67648
#define F_B21   67904
#define F_TOTAL 68160

__device__ __align__(16) short g_fr[F_TOTAL];
// GRU gate biases, f32, float4-loadable: [0]=bih+bhh (r), [1]=bih+bhh (z),
// [2]=bih (n), [3]=bhh (n)
__device__ __align__(16) float g_grb[4][64];
// per-stage LN/bias tables, f32 (kills 48 bf2f per node iteration):
// [stage][0]=b2, [1]=gamma, [2]=beta, natural feature order
__device__ __align__(16) float g_lnb[2][3][64];
__device__ int g_hist[NBIN];   // invariant: zero at kernel entry (reset by last block)
__device__ int g_off[NBIN];
__device__ int g_done;         // invariant: zero at kernel entry
__device__ int g_perm[MAXB];

__device__ __forceinline__ short bf16rn(float x) {
  unsigned u = __float_as_uint(x);
  u += 0x7fffu + ((u >> 16) & 1u);
  return (short)(u >> 16);
}
__device__ __forceinline__ float bf2f(short s) {
  return __uint_as_float(((unsigned)(unsigned short)s) << 16);
}
__device__ __forceinline__ unsigned pk2(float lo, float hi) {
  __hip_bfloat162 t = __float22bfloat162_rn(float2{lo, hi});
  return *reinterpret_cast<unsigned*>(&t);
}
// fast GRU activations: v_exp_f32 + v_rcp_f32 (err ~1e-6, well within tolerance)
__device__ __forceinline__ float fsig(float x) {
  return __builtin_amdgcn_rcpf(1.f + __expf(-x));
}
__device__ __forceinline__ float ftanh(float x) {
  return 1.f - 2.f * __builtin_amdgcn_rcpf(1.f + __expf(2.f * x));
}
// slot permutation: C row r (=mb*16+qq*4+i) lands at slot s64(r); permuting weight
// rows by s64 makes the C-output the B-fragment of the next GEMM, register-locally.
__device__ __forceinline__ int s64(int r) {
  int mb = r >> 4, qq = (r >> 2) & 3, i = r & 3;
  return (mb >> 1) * 32 + qq * 8 + (mb & 1) * 4 + i;
}

#define LDF(off) (*(const bf16x8*)(g_fr + (off) + lane * 8))
#define LDB(off, c) (*(const bf16x8*)(g_fr + (off) + (c) * 32 + q * 8))
// node-local bases (gA/gL include an opaque 0 so loads can't be hoisted/LICM'd;
// protects the <=128-VGPR occupancy bin from over-aggressive LICM)
#define GAF(off) (*(const bf16x8*)(gA + (off)))

// ---------------- prep (+ n_nodes histogram + DESCENDING scan, ticketed) --------
#define BUILDA(OFS, MB, KC, ROWX, GET)                                 \
  for (int idx = t; idx < (MB) * (KC) * 512; idx += T) {               \
    int j = idx & 7, ln = (idx >> 3) & 63, f = idx >> 9;               \
    int mb = f / (KC), kc = f % (KC);                                  \
    int m = mb * 16 + (ln & 15);                                       \
    int k = kc * 32 + (ln >> 4) * 8 + j;                               \
    int row = (ROWX);                                                  \
    (void)row; (void)k; (void)m;                                       \
    g_fr[(OFS) + idx] = bf16rn(GET);                                   \
  }

__global__ void __launch_bounds__(256)
prep_frag(const float* __restrict__ ne_w,
          const float* __restrict__ m1w1, const float* __restrict__ m1w2,
          const float* __restrict__ m2w1, const float* __restrict__ m2w2,
          const float* __restrict__ wih,  const float* __restrict__ whh,
          const float* __restrict__ pqw,  const float* __restrict__ opw,
          const float* __restrict__ c1w,  const float* __restrict__ c2w,
          const float* __restrict__ pkw,
          const float* __restrict__ ne_b,
          const float* __restrict__ m1b1, const float* __restrict__ m1b2,
          const float* __restrict__ n1g,  const float* __restrict__ n1b,
          const float* __restrict__ m2b1, const float* __restrict__ m2b2,
          const float* __restrict__ n2g,  const float* __restrict__ n2b,
          const float* __restrict__ bih,  const float* __restrict__ bhh,
          const int* __restrict__ nnp, int B)
{
  const int t = blockIdx.x * blockDim.x + threadIdx.x;
  const int T = gridDim.x * blockDim.x;
  // ne_b folded into K-pad column 16 (B supplies constant 1.0 at k=16)
  BUILDA(F_NE,   4, 1, s64(m), (k < 16 ? ne_w[row * 16 + k] : (k == 16 ? ne_b[row] : 0.f)))
  BUILDA(F_M1W1, 4, 4, s64(m), m1w1[row * 128 + k])
  BUILDA(F_M1W2, 4, 2, s64(m), m1w2[row * 64 + k])
  BUILDA(F_M2W1, 4, 4, s64(m), m2w1[row * 128 + k])
  BUILDA(F_M2W2, 4, 2, s64(m), m2w2[row * 64 + k])
  BUILDA(F_WIH, 12, 3, (m & 0xC0) | s64(m & 63), (k < 72 ? wih[row * 72 + k] : 0.f))
  BUILDA(F_WHH, 12, 2, (m & 0xC0) | s64(m & 63), whh[row * 64 + k])
  BUILDA(F_PQ,   4, 2, m, pqw[row * 64 + k])
  BUILDA(F_PK,   4, 2, m, pkw[row * 64 + k])
  BUILDA(F_PACK, 2, 2, m, (row < 8 ? opw[row * 64 + k]
                           : row < 18 ? c1w[(row - 8) * 64 + k]
                           : row < 28 ? c2w[(row - 18) * 64 + k] : 0.f))
  for (int i = t; i < 64; i += T) {
    g_fr[F_B11 + i] = bf16rn(m1b1[i]);
    g_fr[F_B21 + i] = bf16rn(m2b1[i]);
    g_lnb[0][0][i] = m1b2[i]; g_lnb[0][1][i] = n1g[i]; g_lnb[0][2][i] = n1b[i];
    g_lnb[1][0][i] = m2b2[i]; g_lnb[1][1][i] = n2g[i]; g_lnb[1][2][i] = n2b[i];
    g_grb[0][i] = bih[i]       + bhh[i];
    g_grb[1][i] = bih[64 + i]  + bhh[64 + i];
    g_grb[2][i] = bih[128 + i];
    g_grb[3][i] = bhh[128 + i];
  }

  // ---- histogram of n_nodes (g_hist zero at entry) ----
  __shared__ int lh[NBIN];
  __shared__ int lastdone;
  const int lt = threadIdx.x;
  if (lt < NBIN) lh[lt] = 0;
  __syncthreads();
  for (int i = t; i < B; i += T) atomicAdd(&lh[nnp[i] - 1], 1);
  __syncthreads();
  if (lt < NBIN && lh[lt] > 0) atomicAdd(&g_hist[lt], lh[lt]);
  __threadfence();
  if (lt == 0) lastdone = (atomicAdd(&g_done, 1) == (int)gridDim.x - 1);
  __syncthreads();
  // last block: DESCENDING scan (LPT: heavy blocks dispatch first), then restore
  // the zero-invariant for the next launch/replay.
  if (lastdone && lt == 0) {
    __threadfence();
    int acc = 0;
    for (int i = NBIN - 1; i >= 0; i--) {
      g_off[i] = acc; acc += g_hist[i]; g_hist[i] = 0;
    }
    g_done = 0;
  }
}

__global__ void __launch_bounds__(256)
nn_scatter(const int* __restrict__ nnp, int B)
{
  __shared__ int lc[NBIN], lbase[NBIN];
  const int t = threadIdx.x;
  const int i = blockIdx.x * 256 + t;
  if (t < NBIN) lc[t] = 0;
  __syncthreads();
  int bin = 0, r = 0;
  const bool ok = (i < B);
  if (ok) { bin = nnp[i] - 1; r = atomicAdd(&lc[bin], 1); }
  __syncthreads();
  if (t < NBIN) lbase[t] = (lc[t] > 0) ? atomicAdd(&g_off[t], lc[t]) : 0;
  __syncthreads();
  if (ok) g_perm[lbase[bin] + r] = i;
}

__device__ __forceinline__ void pack8(FU& f, const float* v) {
  f.u[0] = pk2(v[0], v[1]); f.u[1] = pk2(v[2], v[3]);
  f.u[2] = pk2(v[4], v[5]); f.u[3] = pk2(v[6], v[7]);
}

// ---------------- MP stage: interleaved nodes n = wv + 4t, skip t >= nact --------
// W1 fragments hoisted (+32 VGPR within the 65..128 bin); W2 re-loaded per node
// (tz-pinned). LN/bias vectors come from f32 tables (no bf2f), LN applied in
// fma-form with the mask folded into rstd.
__device__ __forceinline__ void mp_stage(
    FU hA[][2], float* macc, const FU* msgf, const float* lnb,
    int w1off, int w2off, int b1o,
    int nnv, int wv, int nact, int lane, int q)
{
  if (nact == 0) return;
  const f32x4 zf4 = {0.f, 0.f, 0.f, 0.f};
  f32x4 tmsg[4];
  #pragma unroll
  for (int mb = 0; mb < 4; mb++) {
    tmsg[mb] = MFMA(LDF(w1off + (mb * 4 + 2) * 512), msgf[0].h, zf4);
    tmsg[mb] = MFMA(LDF(w1off + (mb * 4 + 3) * 512), msgf[1].h, tmsg[mb]);
  }
  {
    // hoist b1 bias: added once per wave instead of once per node
    FU b1p0, b1p1; b1p0.h = LDB(b1o, 0); b1p1.h = LDB(b1o, 1);
    #pragma unroll
    for (int mb = 0; mb < 4; mb++)
      #pragma unroll
      for (int i = 0; i < 4; i++)
        tmsg[mb][i] += bf2f(((mb >> 1) ? b1p1 : b1p0).h[(mb & 1) * 4 + i]);
  }
  // hoist W1 A-fragments (8 frags = 32 VGPR): removes 8 dependent L1/L2 loads
  // from every node iteration's critical path
  bf16x8 w1A[4][2];
  #pragma unroll
  for (int mb = 0; mb < 4; mb++) {
    w1A[mb][0] = LDF(w1off + (mb * 4 + 0) * 512);
    w1A[mb][1] = LDF(w1off + (mb * 4 + 1) * 512);
  }

  #pragma unroll
  for (int t = 0; t < 5; t++) {
    if (t < nact) {
      int tz = 0;
      asm volatile("" : "+v"(tz));
      const short* gA = g_fr + lane * 8 + tz;
      const float* gL = lnb + q * 8 + tz;
      const int n = wv + 4 * t;
      f32x4 T[4];
      #pragma unroll
      for (int mb = 0; mb < 4; mb++) {
        T[mb] = MFMA(w1A[mb][0], hA[t][0].h, tmsg[mb]);
        T[mb] = MFMA(w1A[mb][1], hA[t][1].h, T[mb]);
      }
      FU tb[2];
      #pragma unroll
      for (int c = 0; c < 2; c++)
        #pragma unroll
        for (int w = 0; w < 4; w++) {
          int mb = 2 * c + (w >> 1), i0 = (w & 1) * 2;
          float lo = fmaxf(T[mb][i0],     0.f);
          float hi = fmaxf(T[mb][i0 + 1], 0.f);
          tb[c].u[w] = pk2(lo, hi);
        }
      f32x4 H[4];
      #pragma unroll
      for (int mb = 0; mb < 4; mb++) {
        H[mb] = MFMA(GAF(w2off + (mb * 2 + 0) * 512), tb[0].h, zf4);
        H[mb] = MFMA(GAF(w2off + (mb * 2 + 1) * 512), tb[1].h, H[mb]);
      }
      // residual + b2 (f32 table) + stats, per c-half (caps transient regs)
      float y[16]; float s = 0.f, ss = 0.f;
      #pragma unroll
      for (int c = 0; c < 2; c++) {
        f32x4 bq0 = *(const f32x4*)(gL + c * 32);
        f32x4 bq1 = *(const f32x4*)(gL + c * 32 + 4);
        #pragma unroll
        for (int j = 0; j < 8; j++) {
          float v = H[2 * c + (j >> 2)][j & 3] + ((j >> 2) ? bq1[j & 3] : bq0[j & 3]) +
                    bf2f(hA[t][c].h[j]);
          y[c * 8 + j] = v; s += v; ss += v * v;
        }
      }
      s += __shfl_xor(s, 16, 64); ss += __shfl_xor(ss, 16, 64);
      s += __shfl_xor(s, 32, 64); ss += __shfl_xor(ss, 32, 64);
      float mu = s * 0.015625f;
      float rstd = rsqrtf(ss * 0.015625f - mu * mu + 1e-5f);
      // hv = ((y-mu)*rstd*g + b)*mfv  ==  y*rm*g - mm*g + bm
      //   with rm = rstd*mfv, mm = mu*rm, bm = mfv ? b : 0
      const bool on = (n < nnv);
      float rm = on ? rstd : 0.f;
      float mm = mu * rm;
      #pragma unroll
      for (int c = 0; c < 2; c++) {
        f32x4 gq0 = *(const f32x4*)(gL + 64 + c * 32);
        f32x4 gq1 = *(const f32x4*)(gL + 64 + c * 32 + 4);
        f32x4 lq0 = *(const f32x4*)(gL + 128 + c * 32);
        f32x4 lq1 = *(const f32x4*)(gL + 128 + c * 32 + 4);
        #pragma unroll
        for (int j = 0; j < 8; j++) {
          int k = c * 8 + j;
          float gv = (j >> 2) ? gq1[j & 3] : gq0[j & 3];
          float lv = (j >> 2) ? lq1[j & 3] : lq0[j & 3];
          float bm = on ? lv : 0.f;
          float tv = y[k] * rm - mm;
          float hv = tv * gv + bm;
          macc[k] += hv; y[k] = hv;
        }
      }
      pack8(hA[t][0], y); pack8(hA[t][1], y + 8);
    }
  }
}

// ---------------- main: 16 sorted batch / block, interleaved node ownership ------
__global__ void __launch_bounds__(256)
msp(const float* __restrict__ nf, const int* __restrict__ nnp,
    const float* __restrict__ rnn, const float* __restrict__ poh,
    const float* __restrict__ opb, const float* __restrict__ c1b,
    const float* __restrict__ c2b, const float* __restrict__ pqb,
    const float* __restrict__ pkb,
    float* __restrict__ out, int B)
{
  // double-buffered exchange (no trailing barriers needed); 36.9 KB LDS still
  // fits the 4-blocks/CU cap set by the 65..128 VGPR occupancy bin
  __shared__ __align__(16) float exch[2][4][64][17];
  __shared__ __align__(16) unsigned nsx[64][8];

  const int tid = threadIdx.x;
  const int wv = tid >> 6;
  const int lane = tid & 63;
  const int l15 = lane & 15, q = lane >> 4;
  const int b0 = blockIdx.x * 16;
  const int bb = g_perm[b0 + l15];

  const int nnv = nnp[bb];
  const float inv = 1.0f / (float)nnv;
  const f32x4 zf4 = {0.f, 0.f, 0.f, 0.f};

  // block-max nnv (same 16 samples for all waves): reduce within 16-lane groups
  int M = nnv;
  { int o;
    o = __shfl_xor(M, 1, 64); M = M > o ? M : o;
    o = __shfl_xor(M, 2, 64); M = M > o ? M : o;
    o = __shfl_xor(M, 4, 64); M = M > o ? M : o;
    o = __shfl_xor(M, 8, 64); M = M > o ? M : o; }
  // this wave owns nodes n = wv + 4t, t in [0, nact)
  int nact = (M - wv + 3) >> 2;
  nact = nact < 0 ? 0 : (nact > 5 ? 5 : nact);

  FU hA[5][2];
  float mac[16];
  #pragma unroll
  for (int k = 0; k < 16; k++) mac[k] = 0.f;

  // ================= E: h0^T = ne_w' · x^T (bias via k=16 pad column) ==========
  // h0 is masked AT SOURCE (hv *= mfv): exchanges are plain sums of mac.
  // xa prefetch depth 2 (ping-pong, compile-time-selected) to cap reg pressure.
  {
    bf16x8 neA[4];
    #pragma unroll
    for (int mb = 0; mb < 4; mb++) neA[mb] = LDF(F_NE + mb * 512);
    float4 xaA[2], xaB[2];
    if (nact > 0 && q < 2) {
      const float* p = nf + ((size_t)bb * NM + wv) * 16 + q * 8;
      xaA[0] = *(const float4*)p; xaA[1] = *(const float4*)(p + 4);
    }
    #pragma unroll
    for (int t = 0; t < 5; t++) {
      if (t < nact) {
        float4 c0, c1;
        if ((t & 1) == 0) { c0 = xaA[0]; c1 = xaA[1]; }
        else              { c0 = xaB[0]; c1 = xaB[1]; }
        if (t + 1 < nact && q < 2) {
          const float* p = nf + ((size_t)bb * NM + (wv + 4 * (t + 1))) * 16 + q * 8;
          if ((t & 1) == 0) { xaB[0] = *(const float4*)p; xaB[1] = *(const float4*)(p + 4); }
          else              { xaA[0] = *(const float4*)p; xaA[1] = *(const float4*)(p + 4); }
        }
        const int n = wv + 4 * t;
        FU bx;
        bx.u[0] = 0; bx.u[1] = 0; bx.u[2] = 0; bx.u[3] = 0;
        if (q < 2) {
          bx.u[0] = pk2(c0.x, c0.y); bx.u[1] = pk2(c0.z, c0.w);
          bx.u[2] = pk2(c1.x, c1.y); bx.u[3] = pk2(c1.z, c1.w);
        } else if (q == 2) {
          bx.u[0] = pk2(1.f, 0.f);   // k=16 constant-1 -> ne_b column
        }
        f32x4 C[4];
        #pragma unroll
        for (int mb = 0; mb < 4; mb++) C[mb] = MFMA(neA[mb], bx.h, zf4);
        const float mfv = (n < nnv) ? 1.f : 0.f;
        float hv[16];
        #pragma unroll
        for (int k = 0; k < 16; k++) {
          int c = k >> 3, j = k & 7;
          hv[k] = C[2 * c + (j >> 2)][j & 3] * mfv;
          mac[k] += hv[k];
        }
        pack8(hA[t][0], hv); pack8(hA[t][1], hv + 8);
      }
    }
  }

  FU msgf[2];
  // double-buffered exchange: write region, barrier, read region; buffer
  // alternation makes region reuse safe without a trailing barrier
  #define EXCHANGE(REG)                                                        \
    {                                                                          \
      _Pragma("unroll")                                                        \
      for (int k = 0; k < 16; k++) exch[REG][wv][lane][k] = mac[k];            \
      __syncthreads();                                                         \
      _Pragma("unroll")                                                        \
      for (int w8 = 0; w8 < 8; w8++) {                                         \
        int k0 = 2 * w8, k1 = k0 + 1;                                          \
        float a = (exch[REG][0][lane][k0] + exch[REG][1][lane][k0] +           \
                   exch[REG][2][lane][k0] + exch[REG][3][lane][k0]) * inv;     \
        float b = (exch[REG][0][lane][k1] + exch[REG][1][lane][k1] +           \
                   exch[REG][2][lane][k1] + exch[REG][3][lane][k1]) * inv;     \
        FU* dp = (w8 < 4) ? &msgf[0] : &msgf[1];                               \
        dp->u[w8 & 3] = pk2(a, b);                                             \
      }                                                                        \
      _Pragma("unroll")                                                        \
      for (int k = 0; k < 16; k++) mac[k] = 0.f;                               \
    }

  EXCHANGE(0)   // msg1
  mp_stage(hA, mac, msgf, &g_lnb[0][0][0], F_M1W1, F_M1W2, F_B11,
           nnv, wv, nact, lane, q);

  EXCHANGE(1)   // msg2
  mp_stage(hA, mac, msgf, &g_lnb[1][0][0], F_M2W1, F_M2W2, F_B21,
           nnv, wv, nact, lane, q);

  EXCHANGE(0)   // graph_vec (region 0 safe: all reads done pre-EXCHANGE(1) barrier)

  // ================= GRU: wave wv owns gate tile tt = wv; gx == msgf ==========
  {
    FU px;
    if (q == 0) {
      const float* pp = poh + (size_t)bb * 8;
      float4 p0 = *(const float4*)pp, p1 = *(const float4*)(pp + 4);
      px.u[0] = pk2(p0.x, p0.y); px.u[1] = pk2(p0.z, p0.w);
      px.u[2] = pk2(p1.x, p1.y); px.u[3] = pk2(p1.z, p1.w);
    } else { px.u[0] = 0; px.u[1] = 0; px.u[2] = 0; px.u[3] = 0; }
    const float* rr0 = rnn + (size_t)bb * 64;
    float rv[16];
    #pragma unroll
    for (int c = 0; c < 2; c++) {
      float4 a0 = *(const float4*)(rr0 + c * 32 + q * 8);
      float4 a1 = *(const float4*)(rr0 + c * 32 + q * 8 + 4);
      rv[c * 8 + 0] = a0.x; rv[c * 8 + 1] = a0.y; rv[c * 8 + 2] = a0.z; rv[c * 8 + 3] = a0.w;
      rv[c * 8 + 4] = a1.x; rv[c * 8 + 5] = a1.y; rv[c * 8 + 6] = a1.z; rv[c * 8 + 7] = a1.w;
    }
    FU ah[2]; pack8(ah[0], rv); pack8(ah[1], rv + 8);

    const int tt = wv;
    f32x4 R = MFMA(LDF(F_WIH + (tt * 3 + 0) * 512), msgf[0].h, zf4);
    R = MFMA(LDF(F_WIH + (tt * 3 + 1) * 512), msgf[1].h, R);
    R = MFMA(LDF(F_WIH + (tt * 3 + 2) * 512), px.h, R);
    R = MFMA(LDF(F_WHH + (tt * 2 + 0) * 512), ah[0].h, R);
    R = MFMA(LDF(F_WHH + (tt * 2 + 1) * 512), ah[1].h, R);
    f32x4 Z = MFMA(LDF(F_WIH + ((4 + tt) * 3 + 0) * 512), msgf[0].h, zf4);
    Z = MFMA(LDF(F_WIH + ((4 + tt) * 3 + 1) * 512), msgf[1].h, Z);
    Z = MFMA(LDF(F_WIH + ((4 + tt) * 3 + 2) * 512), px.h, Z);
    Z = MFMA(LDF(F_WHH + ((4 + tt) * 2 + 0) * 512), ah[0].h, Z);
    Z = MFMA(LDF(F_WHH + ((4 + tt) * 2 + 1) * 512), ah[1].h, Z);
    f32x4 Ni = MFMA(LDF(F_WIH + ((8 + tt) * 3 + 0) * 512), msgf[0].h, zf4);
    Ni = MFMA(LDF(F_WIH + ((8 + tt) * 3 + 1) * 512), msgf[1].h, Ni);
    Ni = MFMA(LDF(F_WIH + ((8 + tt) * 3 + 2) * 512), px.h, Ni);
    f32x4 Nh = MFMA(LDF(F_WHH + ((8 + tt) * 2 + 0) * 512), ah[0].h, zf4);
    Nh = MFMA(LDF(F_WHH + ((8 + tt) * 2 + 1) * 512), ah[1].h, Nh);

    const int dbase = q * 8 + (tt >> 1) * 32 + (tt & 1) * 4;
    f32x4 brv = *(const f32x4*)&g_grb[0][dbase];
    f32x4 bzv = *(const f32x4*)&g_grb[1][dbase];
    f32x4 bnv = *(const f32x4*)&g_grb[2][dbase];
    f32x4 bhv = *(const f32x4*)&g_grb[3][dbase];
    float nsv[4];
    #pragma unroll
    for (int i = 0; i < 4; i++) {
      const int K = (tt >> 1) * 32 + (tt & 1) * 4 + i;
      const int d = q * 8 + K;
      float rr = fsig(R[i] + brv[i]);
      float zz = fsig(Z[i] + bzv[i]);
      float ng = ftanh(Ni[i] + bnv[i] + rr * (Nh[i] + bhv[i]));
      float st = rv[(tt >> 1) * 8 + (tt & 1) * 4 + i];
      float v = (1.f - zz) * ng + zz * st;
      out[(size_t)B * 48 + (size_t)bb * 64 + d] = v;
      nsv[i] = v;
    }
    // ns quarter -> LDS: dwords (tt>>1)*4 + (tt&1)*2 + {0,1}
    const int dw = (tt >> 1) * 4 + (tt & 1) * 2;
    nsx[lane][dw]     = pk2(nsv[0], nsv[1]);
    nsx[lane][dw + 1] = pk2(nsv[2], nsv[3]);
  }
  __syncthreads();

  // ================= heads + pointer =================
  {
    FU an0, an1;
    an0.u = *(const u32x4*)&nsx[lane][0];
    an1.u = *(const u32x4*)&nsx[lane][4];
    float qv[16];
    #pragma unroll
    for (int mb = 0; mb < 4; mb++) {
      f32x4 Qc = MFMA(LDF(F_PQ + (mb * 2 + 0) * 512), an0.h, zf4);
      Qc = MFMA(LDF(F_PQ + (mb * 2 + 1) * 512), an1.h, Qc);
      f32x4 pq4 = *(const f32x4*)&pqb[mb * 16 + q * 4];
      #pragma unroll
      for (int i = 0; i < 4; i++) qv[mb * 4 + i] = Qc[i] + pq4[i];
    }
    float qb = 0.f;
    #pragma unroll
    for (int mb = 0; mb < 4; mb++) {
      f32x4 pk4 = *(const f32x4*)&pkb[mb * 16 + q * 4];
      #pragma unroll
      for (int i = 0; i < 4; i++) qb += qv[mb * 4 + i] * pk4[i];
    }
    qb += __shfl_xor(qb, 16, 64); qb += __shfl_xor(qb, 32, 64);

    if (wv < 2) {   // op/c1/c2 packed head: wave wv does mb2 = wv
      f32x4 L = MFMA(LDF(F_PACK + (wv * 2 + 0) * 512), an0.h, zf4);
      L = MFMA(LDF(F_PACK + (wv * 2 + 1) * 512), an1.h, L);
      #pragma unroll
      for (int i = 0; i < 4; i++) {
        int o = wv * 16 + q * 4 + i;
        if (o < 8)       out[(size_t)bb * 8 + o] = L[i] + opb[o];
        else if (o < 18) out[(size_t)B * 8 + (size_t)bb * 10 + (o - 8)] = L[i] + c1b[o - 8];
        else if (o < 28) out[(size_t)B * 18 + (size_t)bb * 10 + (o - 18)] = L[i] + c2b[o - 18];
      }
    }
    // pointer K-GEMM: PK fragments hoisted (late-phase reg pressure is low)
    bf16x8 pkA[4][2];
    #pragma unroll
    for (int mb = 0; mb < 4; mb++) {
      pkA[mb][0] = LDF(F_PK + (mb * 2 + 0) * 512);
      pkA[mb][1] = LDF(F_PK + (mb * 2 + 1) * 512);
    }
    #pragma unroll
    for (int t = 0; t < 5; t++) {
      const int n = wv + 4 * t;
      if (t < nact) {
        float dt = 0.f;
        #pragma unroll
        for (int mb = 0; mb < 4; mb++) {
          f32x4 Kc = MFMA(pkA[mb][0], hA[t][0].h, zf4);
          Kc = MFMA(pkA[mb][1], hA[t][1].h, Kc);
          #pragma unroll
          for (int i = 0; i < 4; i++) dt += qv[mb * 4 + i] * Kc[i];
        }
        dt += __shfl_xor(dt, 16, 64); dt += __shfl_xor(dt, 32, 64);
        if (q == 0)
          out[(size_t)B * 28 + (size_t)bb * 20 + n] = (n < nnv) ? (dt + qb) : -1e9f;
      } else {
        if (q == 0)
          out[(size_t)B * 28 + (size_t)bb * 20 + n] = -1e9f;   // n >= M >= nnv
      }
    }
  }
}

extern "C" void kernel_launch(void* const* d_in, const int* in_sizes, int n_in,
                              void* d_out, int out_size, void* d_ws, size_t ws_size,
                              hipStream_t stream)
{
  (void)n_in; (void)out_size; (void)d_ws; (void)ws_size;
  const float* nf   = (const float*)d_in[0];
  const int*   nnp  = (const int*)  d_in[1];
  const float* rnn  = (const float*)d_in[2];
  const float* poh  = (const float*)d_in[3];
  const float* ne_w = (const float*)d_in[4];
  const float* ne_b = (const float*)d_in[5];
  const float* m1w1 = (const float*)d_in[6];
  const float* m1b1 = (const float*)d_in[7];
  const float* m1w2 = (const float*)d_in[8];
  const float* m1b2 = (const float*)d_in[9];
  const float* n1g  = (const float*)d_in[10];
  const float* n1b  = (const float*)d_in[11];
  const float* m2w1 = (const float*)d_in[12];
  const float* m2b1 = (const float*)d_in[13];
  const float* m2w2 = (const float*)d_in[14];
  const float* m2b2 = (const float*)d_in[15];
  const float* n2g  = (const float*)d_in[16];
  const float* n2b  = (const float*)d_in[17];
  const float* wih  = (const float*)d_in[18];
  const float* whh  = (const float*)d_in[19];
  const float* bih  = (const float*)d_in[20];
  const float* bhh  = (const float*)d_in[21];
  const float* opw  = (const float*)d_in[22];
  const float* opb  = (const float*)d_in[23];
  const float* c1w  = (const float*)d_in[24];
  const float* c1b  = (const float*)d_in[25];
  const float* c2w  = (const float*)d_in[26];
  const float* c2b  = (const float*)d_in[27];
  const float* pqw  = (const float*)d_in[28];
  const float* pqb  = (const float*)d_in[29];
  const float* pkw  = (const float*)d_in[30];
  const float* pkb  = (const float*)d_in[31];
  float* out = (float*)d_out;
  const int B = in_sizes[1];

  prep_frag<<<132, 256, 0, stream>>>(ne_w, m1w1, m1w2, m2w1, m2w2,
                                     wih, whh, pqw, opw, c1w, c2w, pkw,
                                     ne_b, m1b1, m1b2, n1g, n1b,
                                     m2b1, m2b2, n2g, n2b, bih, bhh,
                                     nnp, B);
  nn_scatter<<<(B + 255) / 256, 256, 0, stream>>>(nnp, B);
  msp<<<B / 16, 256, 0, stream>>>(nf, nnp, rnn, poh,
                                  opb, c1b, c2b,
                                  pqb, pkb, out, B);
}